// Round 1
// baseline (1502.855 us; speedup 1.0000x reference)
//
#include <hip/hip_runtime.h>
#include <math.h>

// Problem constants
#define B_ 4
#define S_ 1024
#define D_ 512
#define H_ 8
#define DH_ 64
#define I_ 2048
#define E_ 8
#define L_ 4
#define T_ 4096   // B*S

using bf16x8 = __attribute__((ext_vector_type(8))) __bf16;
using f32x4  = __attribute__((ext_vector_type(4))) float;

typedef __attribute__((address_space(1))) const void gvoid;
typedef __attribute__((address_space(3))) void lvoid;
__device__ __forceinline__ void gl_lds16(const void* g, void* l){
  __builtin_amdgcn_global_load_lds((gvoid*)g, (lvoid*)l, 16, 0, 0);
}

__device__ __forceinline__ float wred_sum(float v){
#pragma unroll
  for(int m=32;m>0;m>>=1) v += __shfl_xor(v, m, 64);
  return v;
}
__device__ __forceinline__ unsigned short f2bf(float f){
  unsigned x = __float_as_uint(f);
  unsigned r = (x + 0x7FFFu + ((x>>16)&1u)) >> 16;
  return (unsigned short)r;
}
__device__ __forceinline__ float bf2f(unsigned short u){
  return __uint_as_float(((unsigned)u)<<16);
}
__device__ __forceinline__ unsigned pk2(float a, float b){
  return (unsigned)f2bf(a) | ((unsigned)f2bf(b)<<16);
}

// ---------------------------------------------------------------------------
// bf16 MFMA GEMM. NT: C[m,n] = sum_k A[m,k]*B[n,k].
// BK=64: 2 MFMA k-substeps per barrier pair (double arithmetic density vs
// BK=32). global_load_lds width-16 staging, single LDS buffer.
// 4 waves in 2x2. BM in {64,128}, BN in {64,128}.
// MOE: block table btab[bx] = (e<<8)|mblk, -1 = dead. Optional row gather.
// ---------------------------------------------------------------------------
template<int BM, int BN, bool MOE, bool GATHER, bool OUT_BF16, int ACT, bool ADD_IN>
__global__ __launch_bounds__(256)
void gemm_k(const unsigned short* __restrict__ A, const unsigned short* __restrict__ Bv,
            void* Cp, const float* __restrict__ bias, const float* addin,
            int M, int N, int K, int lda, int ldb, int ldc,
            int hdiv, long sAb, long sAh, long sBb, long sBh, long sCb, long sCh,
            float scale,
            const int* __restrict__ moff, const int* __restrict__ mcnt,
            const int* __restrict__ rowtok, const int* __restrict__ btab,
            long sBe, int biasStride)
{
  constexpr int BK = 64;
  constexpr int WM = BM/2, WN = BN/2, FM = WM/16, FNN = WN/16;
  constexpr int RPC = 2048/BK;       // rows covered per block-wide gl_lds16 call
  constexpr int NA = BM/RPC, NB = BN/RPC;
  __shared__ unsigned short As[BM*BK];
  __shared__ unsigned short Bs[BN*BK];

  const int tid = threadIdx.x, wid = tid>>6, lane = tid&63;
  const int wy = wid>>1, wx = wid&1, ln16 = lane&15, q8 = (lane>>4)*8;
  int m0 = blockIdx.x*BM;
  const int n0 = blockIdx.y*BN;

  float* Cf = nullptr; unsigned short* Ch = nullptr;
  const float* biasp = bias;
  const unsigned short* Bp = Bv;
  int seg = 0, cnt = M;

  if constexpr (MOE){
    int tv = btab[blockIdx.x];
    if (tv < 0) return;
    int e = tv>>8;
    m0 = (tv&255)*BM;
    seg = moff[e]; cnt = mcnt[e];
    Bp = Bv + (long)e*sBe;
    if constexpr (OUT_BF16) Ch = (unsigned short*)Cp; else Cf = (float*)Cp;
    if (biasp) biasp += (long)e*biasStride;
  } else {
    int z = blockIdx.z, zb = z/hdiv, zh = z%hdiv;
    A  += (long)zb*sAb + (long)zh*sAh;
    Bp += (long)zb*sBb + (long)zh*sBh;
    long coff = (long)zb*sCb + (long)zh*sCh;
    if constexpr (OUT_BF16) Ch = (unsigned short*)Cp + coff; else Cf = ((float*)Cp) + coff;
    if constexpr (ADD_IN) addin += coff;
  }

  // staging geometry: call j covers rows j*RPC + tid/(BK/8), col (tid%(BK/8))*8
  const int srow = tid >> 3;          // BK/8 = 8 lanes per row
  const int scol = (tid & 7) * 8;
  long ga[NA], gb[NB];
#pragma unroll
  for (int j=0; j<NA; j++){
    int r = m0 + j*RPC + srow;
    if constexpr (MOE){
      r = min(r, cnt-1);
      long gr = GATHER ? (long)rowtok[seg+r] : (long)(seg+r);
      ga[j] = gr*lda + scol;
    } else {
      ga[j] = (long)min(r, M-1)*lda + scol;
    }
  }
#pragma unroll
  for (int j=0; j<NB; j++){
    int bn = min(n0 + j*RPC + srow, N-1);
    gb[j] = (long)bn*ldb + scol;
  }

  f32x4 acc[FM][FNN];
#pragma unroll
  for(int i=0;i<FM;i++)
#pragma unroll
    for(int j=0;j<FNN;j++){ f32x4 z = {0.f,0.f,0.f,0.f}; acc[i][j] = z; }

  for (int k0 = 0; k0 < K; k0 += BK){
    __syncthreads();
#pragma unroll
    for (int j=0; j<NA; j++) gl_lds16(A + ga[j] + k0, As + j*2048 + wid*512);
#pragma unroll
    for (int j=0; j<NB; j++) gl_lds16(Bp + gb[j] + k0, Bs + j*2048 + wid*512);
    __syncthreads();
#pragma unroll
    for (int kk=0; kk<2; kk++){
      bf16x8 fa[FM], fb[FNN];
#pragma unroll
      for(int i=0;i<FM;i++) fa[i] = *(const bf16x8*)&As[(wy*WM + i*16 + ln16)*BK + kk*32 + q8];
#pragma unroll
      for(int j=0;j<FNN;j++) fb[j] = *(const bf16x8*)&Bs[(wx*WN + j*16 + ln16)*BK + kk*32 + q8];
#pragma unroll
      for(int i=0;i<FM;i++)
#pragma unroll
        for(int j=0;j<FNN;j++)
          acc[i][j] = __builtin_amdgcn_mfma_f32_16x16x32_bf16(fa[i], fb[j], acc[i][j], 0, 0, 0);
    }
  }

  // epilogue: C[m = quad*4+r][n = lane&15]
#pragma unroll
  for(int i=0;i<FM;i++){
    int mbase = m0 + wy*WM + i*16 + (lane>>4)*4;
#pragma unroll
    for(int j=0;j<FNN;j++){
      int n = n0 + wx*WN + j*16 + ln16;
      float bv = biasp ? biasp[n] : 0.f;
      f32x4 v = acc[i][j];
#pragma unroll
      for(int r=0;r<4;r++){
        int m = mbase + r;
        if (m < cnt){
          float x = v[r]*scale + bv;
          if constexpr (ACT == 1) x = 0.5f*x*(1.f + erff(x*0.70710678118654752f));
          long ci = (long)(MOE ? seg + m : m)*ldc + n;
          if constexpr (ADD_IN) x += addin[ci];
          if constexpr (OUT_BF16) Ch[ci] = f2bf(x);
          else Cf[ci] = x;
        }
      }
    }
  }
}

// ---------------------------------------------------------------------------
// Fused flash attention. grid (S/64, B*H). 4 waves, each owns 16 Q-rows.
// ---------------------------------------------------------------------------
__global__ __launch_bounds__(256)
void flash_k(const unsigned short* __restrict__ qkvb, const unsigned short* __restrict__ Vt,
             unsigned short* __restrict__ ctx)
{
  __shared__ unsigned short Pl[4][16*72];
  const int qt = blockIdx.x, z = blockIdx.y, b = z>>3, h = z&7;
  const int wid = threadIdx.x>>6, lane = threadIdx.x&63;
  const int ln16 = lane&15, g = lane>>4;
  const int q0 = qt*64 + wid*16;
  unsigned short* Pw = &Pl[wid][0];

  const unsigned short* Qp = qkvb + (long)(b*1024 + q0 + ln16)*1536 + h*64 + g*8;
  bf16x8 qf0 = *(const bf16x8*)Qp;
  bf16x8 qf1 = *(const bf16x8*)(Qp + 32);
  const unsigned short* Kbase = qkvb + (long)b*1024*1536 + 512 + h*64 + g*8;
  const unsigned short* Vbase = Vt + (long)z*65536 + g*8;

  float m_s[4], l_s[4];
  f32x4 oacc[4];
#pragma unroll
  for(int r=0;r<4;r++){ m_s[r] = -1e30f; l_s[r] = 0.f; }
#pragma unroll
  for(int j=0;j<4;j++){ f32x4 zz = {0.f,0.f,0.f,0.f}; oacc[j] = zz; }

  for (int t = 0; t < 16; ++t){
    bf16x8 kf[4][2], vf[4][2];
#pragma unroll
    for(int j=0;j<4;j++){
      const unsigned short* kp = Kbase + (long)(t*64 + j*16 + ln16)*1536;
      kf[j][0] = *(const bf16x8*)kp;
      kf[j][1] = *(const bf16x8*)(kp + 32);
      const unsigned short* vp = Vbase + (long)(j*16 + ln16)*1024 + t*64;
      vf[j][0] = *(const bf16x8*)vp;
      vf[j][1] = *(const bf16x8*)(vp + 32);
    }
    f32x4 sacc[4];
#pragma unroll
    for(int j=0;j<4;j++){ f32x4 zz = {0.f,0.f,0.f,0.f}; sacc[j] = zz; }
#pragma unroll
    for(int j=0;j<4;j++){
      sacc[j] = __builtin_amdgcn_mfma_f32_16x16x32_bf16(qf0, kf[j][0], sacc[j], 0,0,0);
      sacc[j] = __builtin_amdgcn_mfma_f32_16x16x32_bf16(qf1, kf[j][1], sacc[j], 0,0,0);
    }
#pragma unroll
    for(int j=0;j<4;j++)
#pragma unroll
      for(int r=0;r<4;r++) sacc[j][r] *= 0.125f;
    float alpha[4];
#pragma unroll
    for(int r=0;r<4;r++){
      float mx = fmaxf(fmaxf(sacc[0][r], sacc[1][r]), fmaxf(sacc[2][r], sacc[3][r]));
#pragma unroll
      for(int m=1;m<16;m<<=1) mx = fmaxf(mx, __shfl_xor(mx, m, 64));
      float mn = fmaxf(m_s[r], mx);
      alpha[r] = __expf(m_s[r] - mn);
      m_s[r] = mn;
    }
#pragma unroll
    for(int j=0;j<4;j++)
#pragma unroll
      for(int r=0;r<4;r++) sacc[j][r] = __expf(sacc[j][r] - m_s[r]);
#pragma unroll
    for(int r=0;r<4;r++){
      float rs = sacc[0][r]+sacc[1][r]+sacc[2][r]+sacc[3][r];
#pragma unroll
      for(int m=1;m<16;m<<=1) rs += __shfl_xor(rs, m, 64);
      l_s[r] = l_s[r]*alpha[r] + rs;
    }
#pragma unroll
    for(int j=0;j<4;j++)
#pragma unroll
      for(int r=0;r<4;r++) oacc[j][r] *= alpha[r];
#pragma unroll
    for(int j=0;j<4;j++)
#pragma unroll
      for(int r=0;r<4;r++)
        Pw[(g*4+r)*72 + j*16 + ln16] = f2bf(sacc[j][r]);
    bf16x8 pf0 = *(const bf16x8*)&Pw[ln16*72 + g*8];
    bf16x8 pf1 = *(const bf16x8*)&Pw[ln16*72 + 32 + g*8];
#pragma unroll
    for(int j=0;j<4;j++){
      oacc[j] = __builtin_amdgcn_mfma_f32_16x16x32_bf16(pf0, vf[j][0], oacc[j], 0,0,0);
      oacc[j] = __builtin_amdgcn_mfma_f32_16x16x32_bf16(pf1, vf[j][1], oacc[j], 0,0,0);
    }
  }
#pragma unroll
  for(int r=0;r<4;r++){
    float inv = 1.f/l_s[r];
    long row = (long)(b*1024 + q0 + g*4 + r)*512 + h*64;
#pragma unroll
    for(int j=0;j<4;j++)
      ctx[row + j*16 + ln16] = f2bf(oacc[j][r]*inv);
  }
}

// ---------------------------------------------------------------------------
// Wave-per-row LayerNorm (D=512): 4 rows/block, no barriers.
// ---------------------------------------------------------------------------
template<bool OUT_BF16>
__global__ __launch_bounds__(256)
void ln_w_k(const float* __restrict__ in, const float* __restrict__ w,
            const float* __restrict__ bb, void* __restrict__ outp)
{
  int row = blockIdx.x*4 + (threadIdx.x>>6), lane = threadIdx.x&63;
  const float4* p = (const float4*)(in + (long)row*512 + lane*8);
  float4 a = p[0], c = p[1];
  float s = a.x+a.y+a.z+a.w + c.x+c.y+c.z+c.w;
  float q = a.x*a.x+a.y*a.y+a.z*a.z+a.w*a.w + c.x*c.x+c.y*c.y+c.z*c.z+c.w*c.w;
  s = wred_sum(s); q = wred_sum(q);
  float mean = s*(1.f/512.f);
  float var  = q*(1.f/512.f) - mean*mean;
  float inv  = rsqrtf(var + 1e-5f);
  const float4* wp = (const float4*)(w + lane*8);
  const float4* bp = (const float4*)(bb + lane*8);
  float4 w0 = wp[0], w1 = wp[1], b0 = bp[0], b1 = bp[1];
  float o0 = (a.x-mean)*inv*w0.x + b0.x, o1 = (a.y-mean)*inv*w0.y + b0.y;
  float o2 = (a.z-mean)*inv*w0.z + b0.z, o3 = (a.w-mean)*inv*w0.w + b0.w;
  float o4 = (c.x-mean)*inv*w1.x + b1.x, o5 = (c.y-mean)*inv*w1.y + b1.y;
  float o6 = (c.z-mean)*inv*w1.z + b1.z, o7 = (c.w-mean)*inv*w1.w + b1.w;
  if constexpr (OUT_BF16){
    *(uint4*)((unsigned short*)outp + (long)row*512 + lane*8) =
      make_uint4(pk2(o0,o1), pk2(o2,o3), pk2(o4,o5), pk2(o6,o7));
  } else {
    float4* op = (float4*)((float*)outp + (long)row*512 + lane*8);
    op[0] = make_float4(o0,o1,o2,o3);
    op[1] = make_float4(o4,o5,o6,o7);
  }
}

// LN2 + router fused: h2 = LN(x) (bf16 out) then top-2 gate; NO global atomics.
__global__ __launch_bounds__(256)
void ln2route_k(const float* __restrict__ in, const float* __restrict__ w,
                const float* __restrict__ bb, unsigned short* __restrict__ h2,
                const float* __restrict__ gw,
                int* __restrict__ tok_e, float* __restrict__ tok_w)
{
  int tok = blockIdx.x*4 + (threadIdx.x>>6), lane = threadIdx.x&63;
  const float4* p = (const float4*)(in + (long)tok*512 + lane*8);
  float4 a = p[0], c = p[1];
  float s = a.x+a.y+a.z+a.w + c.x+c.y+c.z+c.w;
  float q = a.x*a.x+a.y*a.y+a.z*a.z+a.w*a.w + c.x*c.x+c.y*c.y+c.z*c.z+c.w*c.w;
  s = wred_sum(s); q = wred_sum(q);
  float mean = s*(1.f/512.f);
  float var  = q*(1.f/512.f) - mean*mean;
  float inv  = rsqrtf(var + 1e-5f);
  const float4* wp = (const float4*)(w + lane*8);
  const float4* bp = (const float4*)(bb + lane*8);
  float4 w0 = wp[0], w1 = wp[1], b0 = bp[0], b1 = bp[1];
  float o[8];
  o[0] = (a.x-mean)*inv*w0.x + b0.x; o[1] = (a.y-mean)*inv*w0.y + b0.y;
  o[2] = (a.z-mean)*inv*w0.z + b0.z; o[3] = (a.w-mean)*inv*w0.w + b0.w;
  o[4] = (c.x-mean)*inv*w1.x + b1.x; o[5] = (c.y-mean)*inv*w1.y + b1.y;
  o[6] = (c.z-mean)*inv*w1.z + b1.z; o[7] = (c.w-mean)*inv*w1.w + b1.w;
  *(uint4*)(h2 + (long)tok*512 + lane*8) =
    make_uint4(pk2(o[0],o[1]), pk2(o[2],o[3]), pk2(o[4],o[5]), pk2(o[6],o[7]));
  float lg[8];
#pragma unroll
  for(int e=0;e<8;e++){
    const float4* gr = (const float4*)(gw + e*512 + lane*8);
    float4 g0 = gr[0], g1 = gr[1];
    float d = o[0]*g0.x + o[1]*g0.y + o[2]*g0.z + o[3]*g0.w
            + o[4]*g1.x + o[5]*g1.y + o[6]*g1.z + o[7]*g1.w;
    lg[e] = wred_sum(d);
  }
  if (lane == 0){
    float mx = lg[0];
#pragma unroll
    for(int e=1;e<8;e++) mx = fmaxf(mx, lg[e]);
    float pr[8];
#pragma unroll
    for(int e=0;e<8;e++) pr[e] = expf(lg[e]-mx);
    int e0 = 0; float p0 = pr[0];
#pragma unroll
    for(int e=1;e<8;e++) if (pr[e] > p0){ p0 = pr[e]; e0 = e; }
    int e1 = -1; float p1 = -1.f;
#pragma unroll
    for(int e=0;e<8;e++) if (e != e0 && pr[e] > p1){ p1 = pr[e]; e1 = e; }
    float invp = 1.f/(p0+p1);
    tok_e[2*tok] = e0; tok_e[2*tok+1] = e1;
    tok_w[2*tok] = p0*invp; tok_w[2*tok+1] = p1*invp;
  }
}

// ---------------------------------------------------------------------------
// Single-block planner + scatter: LDS-atomic histogram, offsets, two block
// tables (BM=128 for FFN1, BM=64 for FFN2), aux, and compaction scatter.
// ---------------------------------------------------------------------------
__global__ __launch_bounds__(1024)
void plan_scatter_k(const int* __restrict__ tok_e, const float* __restrict__ tok_w,
                    int* __restrict__ offs, int* __restrict__ cnts, float* __restrict__ aux,
                    int* __restrict__ btab, int* __restrict__ btab64,
                    int* __restrict__ rowtok, float* __restrict__ roww, int* __restrict__ rowof)
{
  __shared__ int hist[8];
  __shared__ int offsS[8];
  __shared__ int base[8];
  const int t = threadIdx.x;
  if (t < 8) hist[t] = 0;
  __syncthreads();
  int e[8]; float w[8];
#pragma unroll
  for (int i=0;i<8;i++){
    e[i] = tok_e[t + i*1024];
    w[i] = tok_w[t + i*1024];
    atomicAdd(&hist[e[i]], 1);
  }
  __syncthreads();
  if (t == 0){
    int o = 0, idx = 0, idx2 = 0; float a = 0.f;
    for (int ee=0; ee<8; ee++){
      offsS[ee] = o;
      int c = hist[ee];
      o += c;
      float u = (float)c*(1.f/4096.f) - 0.125f;
      a += u*u;
      int nb = (c + 127) >> 7;
      for (int j=0;j<nb;j++) btab[idx++] = (ee<<8)|j;
      int nb2 = (c + 63) >> 6;
      for (int j=0;j<nb2;j++) btab64[idx2++] = (ee<<8)|j;
    }
    while (idx < 80) btab[idx++] = -1;
    while (idx2 < 144) btab64[idx2++] = -1;
    *aux += a*(1.f/8.f);
  }
  __syncthreads();
  if (t < 8){
    cnts[t] = hist[t];
    offs[t] = offsS[t];
    base[t] = offsS[t];
  }
  __syncthreads();
#pragma unroll
  for (int i=0;i<8;i++){
    int pos = atomicAdd(&base[e[i]], 1);   // LDS atomic
    int gi = t + i*1024;
    rowtok[pos] = gi>>1;
    roww[pos] = w[i];
    rowof[gi] = pos;
  }
}

// Fused MoE combine + LN, wave per token
__global__ __launch_bounds__(256)
void ln_moe_k(const float* __restrict__ eout, const int* __restrict__ rowof,
              const float* __restrict__ roww, const float* __restrict__ mask,
              const unsigned short* __restrict__ h2,
              const float* __restrict__ w, const float* __restrict__ bb,
              float* __restrict__ outp)
{
  int tok = blockIdx.x*4 + (threadIdx.x>>6), lane = threadIdx.x&63;
  int r0 = rowof[2*tok], r1 = rowof[2*tok+1];
  float w0w = roww[r0], w1w = roww[r1], mk = mask[tok];
  const float4* ap = (const float4*)(eout + (long)r0*512 + lane*8);
  const float4* bp2 = (const float4*)(eout + (long)r1*512 + lane*8);
  float4 a0 = ap[0], a1 = ap[1], c0 = bp2[0], c1 = bp2[1];
  uint4 hu = *(const uint4*)(h2 + (long)tok*512 + lane*8);
  const unsigned short* hh = (const unsigned short*)&hu;
  float v[8];
  v[0] = bf2f(hh[0]) + (a0.x*w0w + c0.x*w1w)*mk;
  v[1] = bf2f(hh[1]) + (a0.y*w0w + c0.y*w1w)*mk;
  v[2] = bf2f(hh[2]) + (a0.z*w0w + c0.z*w1w)*mk;
  v[3] = bf2f(hh[3]) + (a0.w*w0w + c0.w*w1w)*mk;
  v[4] = bf2f(hh[4]) + (a1.x*w0w + c1.x*w1w)*mk;
  v[5] = bf2f(hh[5]) + (a1.y*w0w + c1.y*w1w)*mk;
  v[6] = bf2f(hh[6]) + (a1.z*w0w + c1.z*w1w)*mk;
  v[7] = bf2f(hh[7]) + (a1.w*w0w + c1.w*w1w)*mk;
  float s = 0.f, q = 0.f;
#pragma unroll
  for(int i=0;i<8;i++){ s += v[i]; q += v[i]*v[i]; }
  s = wred_sum(s); q = wred_sum(q);
  float mean = s*(1.f/512.f);
  float var  = q*(1.f/512.f) - mean*mean;
  float inv  = rsqrtf(var + 1e-5f);
  const float4* wp = (const float4*)(w + lane*8);
  const float4* bpp = (const float4*)(bb + lane*8);
  float4 w0 = wp[0], w1 = wp[1], b0 = bpp[0], b1 = bpp[1];
  float wv[8] = {w0.x,w0.y,w0.z,w0.w,w1.x,w1.y,w1.z,w1.w};
  float bv[8] = {b0.x,b0.y,b0.z,b0.w,b1.x,b1.y,b1.z,b1.w};
  float4* op = (float4*)(outp + (long)tok*512 + lane*8);
  op[0] = make_float4((v[0]-mean)*inv*wv[0]+bv[0], (v[1]-mean)*inv*wv[1]+bv[1],
                      (v[2]-mean)*inv*wv[2]+bv[2], (v[3]-mean)*inv*wv[3]+bv[3]);
  op[1] = make_float4((v[4]-mean)*inv*wv[4]+bv[4], (v[5]-mean)*inv*wv[5]+bv[5],
                      (v[6]-mean)*inv*wv[6]+bv[6], (v[7]-mean)*inv*wv[7]+bv[7]);
}

// Build Vt[bh][d][k] bf16 from qkv V slice; grid (4,32), 4 chunks per block
__global__ __launch_bounds__(256)
void vt_k(const unsigned short* __restrict__ qkvb, unsigned short* __restrict__ Vt)
{
  __shared__ unsigned short tile[64][80];
  int z = blockIdx.y, b = z>>3, h = z&7;
  int t = threadIdx.x;
  int kk = t>>2, dd = (t&3)*16;
  int dd2 = t>>2, kk2 = (t&3)*16;
  for (int c = 0; c < 4; ++c){
    int k0 = (blockIdx.x*4 + c)*64;
    const unsigned short* p = qkvb + ((long)(b*1024 + k0 + kk))*1536 + 1024 + h*64 + dd;
    uint4 u0 = *(const uint4*)p, u1 = *(const uint4*)(p+8);
    __syncthreads();
    *(uint4*)&tile[kk][dd] = u0;
    *(uint4*)&tile[kk][dd+8] = u1;
    __syncthreads();
    uint4 o0, o1;
    unsigned short* s0 = (unsigned short*)&o0;
    unsigned short* s1 = (unsigned short*)&o1;
#pragma unroll
    for(int j=0;j<8;j++){ s0[j] = tile[kk2+j][dd2]; s1[j] = tile[kk2+8+j][dd2]; }
    unsigned short* o = Vt + (long)z*65536 + (long)dd2*1024 + k0 + kk2;
    *(uint4*)o = o0; *(uint4*)(o+8) = o1;
  }
}

// fp32 (R,C) -> bf16 (C,R), z-loop of ZL
__global__ __launch_bounds__(256)
void transpose_cast_k(const float* __restrict__ in, unsigned short* __restrict__ outp,
                      int R, int C, int ZL)
{
  __shared__ float tile[64][65];
  int t = threadIdx.x;
  int rr = t>>2, cc = (t&3)*16;
  int cc2 = t>>2, rr2 = (t&3)*16;
  int c0 = blockIdx.x*64, r0 = blockIdx.y*64;
  for (int zi = 0; zi < ZL; ++zi){
    long zoff = (long)(blockIdx.z*ZL + zi) * R * C;
    const float* pin = in + zoff + (long)(r0+rr)*C + c0 + cc;
    float4 v0=*(const float4*)pin, v1=*(const float4*)(pin+4), v2=*(const float4*)(pin+8), v3=*(const float4*)(pin+12);
    __syncthreads();
    tile[rr][cc+0]=v0.x; tile[rr][cc+1]=v0.y; tile[rr][cc+2]=v0.z; tile[rr][cc+3]=v0.w;
    tile[rr][cc+4]=v1.x; tile[rr][cc+5]=v1.y; tile[rr][cc+6]=v1.z; tile[rr][cc+7]=v1.w;
    tile[rr][cc+8]=v2.x; tile[rr][cc+9]=v2.y; tile[rr][cc+10]=v2.z; tile[rr][cc+11]=v2.w;
    tile[rr][cc+12]=v3.x; tile[rr][cc+13]=v3.y; tile[rr][cc+14]=v3.z; tile[rr][cc+15]=v3.w;
    __syncthreads();
    unsigned tmp[8];
#pragma unroll
    for(int jj=0;jj<8;jj++)
      tmp[jj] = pk2(tile[rr2+2*jj][cc2], tile[rr2+2*jj+1][cc2]);
    uint4* dst = (uint4*)(outp + zoff + (long)(c0+cc2)*R + r0 + rr2);
    dst[0] = make_uint4(tmp[0],tmp[1],tmp[2],tmp[3]);
    dst[1] = make_uint4(tmp[4],tmp[5],tmp[6],tmp[7]);
  }
}

// fp32 -> bf16, grid-stride
__global__ __launch_bounds__(256)
void cast_bf16_k(const float* __restrict__ in, unsigned short* __restrict__ outp, int n8)
{
  for (int i = blockIdx.x*256 + threadIdx.x; i < n8; i += gridDim.x*256){
    const float4* p = (const float4*)(in + (long)i*8);
    float4 a = p[0], b = p[1];
    *(uint4*)(outp + (long)i*8) = make_uint4(pk2(a.x,a.y), pk2(a.z,a.w), pk2(b.x,b.y), pk2(b.z,b.w));
  }
}

// masked-sum partial pooling, NO atomics: grid (4,8) -> 8 partials per batch
__global__ __launch_bounds__(256)
void pool2_k(const float* __restrict__ h, const float* __restrict__ mask, float* __restrict__ pooled)
{
  int b = blockIdx.x, sc = blockIdx.y, t = threadIdx.x;
  float a0 = 0.f, a1 = 0.f;
  const float* mb = mask + b*1024 + sc*128;
  const float* hbase = h + ((long)b*1024 + sc*128)*512;
  for (int s = 0; s < 128; ++s){
    float mk = mb[s];
    const float* r = hbase + (long)s*512;
    a0 += r[t]*mk; a1 += r[t+256]*mk;
  }
  pooled[((b*8 + sc)*512) + t] = a0;
  pooled[((b*8 + sc)*512) + t + 256] = a1;
}

__global__ __launch_bounds__(256)
void head_final_k(const float* __restrict__ pooled, const float* __restrict__ mask,
                  const float* __restrict__ pool_w, const float* __restrict__ pool_b,
                  const float* __restrict__ cls_w, const float* __restrict__ cls_b,
                  const float* __restrict__ cf_w1, const float* __restrict__ cf_b1,
                  const float* __restrict__ cf_w2, const float* __restrict__ cf_b2,
                  const float* __restrict__ aux, float* __restrict__ out)
{
  int b = blockIdx.x, t = threadIdx.x, wid = t>>6, lane = t&63;
  __shared__ __align__(16) float pld[512];
  __shared__ __align__(16) float p2[512];
  __shared__ float red[4];
  float ds = 0.f;
  for(int s=t; s<1024; s+=256) ds += mask[b*1024 + s];
  ds = wred_sum(ds);
  if (lane==0) red[wid] = ds;
  __syncthreads();
  float denom = fmaxf(red[0]+red[1]+red[2]+red[3], 1e-9f);
  float s0 = 0.f, s1 = 0.f;
#pragma unroll
  for(int sc=0;sc<8;sc++){
    s0 += pooled[((b*8+sc)*512) + t];
    s1 += pooled[((b*8+sc)*512) + t + 256];
  }
  pld[t]     = s0/denom;
  pld[t+256] = s1/denom;
  __syncthreads();
#pragma unroll
  for(int jj=0;jj<2;jj++){
    int j = t + jj*256;
    const float4* wr = (const float4*)(pool_w + (long)j*512);
    float acc = 0.f;
    for(int i=0;i<128;i++){
      float4 w4 = wr[i]; float4 x4 = ((const float4*)pld)[i];
      acc += w4.x*x4.x + w4.y*x4.y + w4.z*x4.z + w4.w*x4.w;
    }
    p2[j] = tanhf(acc + pool_b[j]);
  }
  __syncthreads();
  if (t < 4){
    const float4* wr = (const float4*)(cls_w + (long)t*512);
    float acc = 0.f;
    for(int i=0;i<128;i++){
      float4 w4 = wr[i]; float4 x4 = ((const float4*)p2)[i];
      acc += w4.x*x4.x + w4.y*x4.y + w4.z*x4.z + w4.w*x4.w;
    }
    out[b*4 + t] = acc + cls_b[t];
  }
  {
    const float4* wr = (const float4*)(cf_w1 + (long)t*512);
    float acc = 0.f;
    for(int i=0;i<128;i++){
      float4 w4 = wr[i]; float4 x4 = ((const float4*)p2)[i];
      acc += w4.x*x4.x + w4.y*x4.y + w4.z*x4.z + w4.w*x4.w;
    }
    acc = fmaxf(acc + cf_b1[t], 0.f) * cf_w2[t];
    acc = wred_sum(acc);
    __syncthreads();
    if (lane==0) red[wid] = acc;
    __syncthreads();
    if (t == 0){
      float sum = red[0]+red[1]+red[2]+red[3];
      out[17 + b] = 1.f/(1.f + expf(-(sum + cf_b2[0])));
    }
  }
  if (b == 0 && t == 0) out[16] = aux[0]*0.25f;
}

// ---------------------------------------------------------------------------
extern "C" void kernel_launch(void* const* d_in, const int* in_sizes, int n_in,
                              void* d_out, int out_size, void* d_ws, size_t ws_size,
                              hipStream_t stream)
{
  (void)in_sizes; (void)n_in; (void)out_size;
  const float* emb    = (const float*)d_in[0];
  const float* mask   = (const float*)d_in[1];
  const float* in_w   = (const float*)d_in[2];
  const float* in_b   = (const float*)d_in[3];
  const float* out_w  = (const float*)d_in[4];
  const float* out_b  = (const float*)d_in[5];
  const float* ln1_w  = (const float*)d_in[6];
  const float* ln1_b  = (const float*)d_in[7];
  const float* ln2_w  = (const float*)d_in[8];
  const float* ln2_b  = (const float*)d_in[9];
  const float* gate_w = (const float*)d_in[10];
  const float* e_w1   = (const float*)d_in[11];
  const float* e_b1   = (const float*)d_in[12];
  const float* e_w2   = (const float*)d_in[13];
  const float* e_b2   = (const float*)d_in[14];
  const float* mln_w  = (const float*)d_in[15];
  const float* mln_b  = (const float*)d_in[16];
  const float* fln_w  = (const float*)d_in[17];
  const float* fln_b  = (const float*)d_in[18];
  const float* pool_w = (const float*)d_in[19];
  const float* pool_b = (const float*)d_in[20];
  const float* cls_w  = (const float*)d_in[21];
  const float* cls_b  = (const float*)d_in[22];
  const float* cf_w1  = (const float*)d_in[23];
  const float* cf_b1  = (const float*)d_in[24];
  const float* cf_w2  = (const float*)d_in[25];
  const float* cf_b2  = (const float*)d_in[26];
  float* out = (float*)d_out;
  char* ws = (char*)d_ws;

  const size_t MiB = 1024*1024;
  if (ws_size < 218*MiB) return;

  // Workspace layout
  float*          x     = (float*)(ws + 0*MiB);             // 8 MiB fp32
  unsigned short* hb    = (unsigned short*)(ws + 8*MiB);    // 4 MiB bf16
  unsigned short* qkvb  = (unsigned short*)(ws + 12*MiB);   // 12 MiB bf16
  unsigned short* ctx   = (unsigned short*)(ws + 24*MiB);   // 4 MiB bf16
  unsigned short* Vt    = (unsigned short*)(ws + 28*MiB);   // 4 MiB bf16
  unsigned short* mid   = (unsigned short*)(ws + 32*MiB);   // 32 MiB bf16
  float*          eout  = (float*)(ws + 64*MiB);            // 16 MiB fp32
  float*          fout  = (float*)(ws + 64*MiB);            //   (reuse, head)
  unsigned short* w1t   = (unsigned short*)(ws + 80*MiB);   // 64 MiB bf16
  unsigned short* w2t   = (unsigned short*)(ws + 144*MiB);  // 64 MiB bf16
  unsigned short* inwb  = (unsigned short*)(ws + 208*MiB);  // 6 MiB bf16
  unsigned short* outwb = (unsigned short*)(ws + 214*MiB);  // 2 MiB bf16
  char* misc = ws + 216*MiB;
  int*   counts  = (int*)(misc + 0);
  int*   offs    = (int*)(misc + 64);
  float* aux     = (float*)(misc + 128);
  int*   btab    = (int*)(misc + 256);       // 80 ints
  int*   btab64  = (int*)(misc + 1024);      // 144 ints
  float* pooled  = (float*)(misc + 4096);    // 64 KiB
  int*   tok_e   = (int*)(misc + 81920);
  float* tok_w   = (float*)(misc + 114688);
  int*   rowtok  = (int*)(misc + 147456);
  float* roww    = (float*)(misc + 180224);
  int*   rowof   = (int*)(misc + 212992);

  hipMemcpyAsync(x, emb, (size_t)T_*D_*4, hipMemcpyDeviceToDevice, stream);
  hipMemsetAsync(aux, 0, 4, stream);
  // weight prep
  cast_bf16_k<<<512, 256, 0, stream>>>(in_w, inwb, L_*3*D_*D_/8);
  cast_bf16_k<<<256, 256, 0, stream>>>(out_w, outwb, L_*D_*D_/8);
  transpose_cast_k<<<dim3(I_/64, D_/64, 4), 256, 0, stream>>>(e_w1, w1t, D_, I_, 8);
  transpose_cast_k<<<dim3(D_/64, I_/64, 4), 256, 0, stream>>>(e_w2, w2t, I_, D_, 8);

  for (int l=0; l<L_; l++){
    const float* inbl  = in_b  + (size_t)l*3*D_;
    const float* outbl = out_b + (size_t)l*D_;
    const float* gwl   = gate_w + (size_t)l*E_*D_;
    const float* eb1l  = e_b1 + (size_t)l*E_*I_;
    const float* eb2l  = e_b2 + (size_t)l*E_*D_;
    const unsigned short* inwbl  = inwb + (size_t)l*3*D_*D_;
    const unsigned short* outwbl = outwb + (size_t)l*D_*D_;
    const unsigned short* w1tl = w1t + (size_t)l*E_*I_*D_;
    const unsigned short* w2tl = w2t + (size_t)l*E_*D_*I_;

    // h = LN1(x) -> bf16
    ln_w_k<true><<<T_/4, 256, 0, stream>>>(x, ln1_w + (size_t)l*D_, ln1_b + (size_t)l*D_, hb);
    // qkv = h @ in_w^T + in_b -> bf16   (BM=64: 768 blocks)
    gemm_k<64,128,false,false,true,0,false><<<dim3(64,12,1), 256, 0, stream>>>(
      hb, inwbl, qkvb, inbl, nullptr, T_, 3*D_, D_, D_, D_, 3*D_,
      1, 0,0,0,0,0,0, 1.f, nullptr, nullptr, nullptr, nullptr, 0, 0);
    vt_k<<<dim3(4,32), 256, 0, stream>>>(qkvb, Vt);
    // fused attention -> ctx (B,S,512) bf16
    flash_k<<<dim3(16,32), 256, 0, stream>>>(qkvb, Vt, ctx);
    // x = x + ctx @ out_w^T + out_b  (fp32)   (64x64: 512 blocks)
    gemm_k<64,64,false,false,false,0,true><<<dim3(64,8,1), 256, 0, stream>>>(
      ctx, outwbl, x, outbl, x, T_, D_, D_, D_, D_, D_,
      1, 0,0,0,0,0,0, 1.f, nullptr, nullptr, nullptr, nullptr, 0, 0);
    // h2 = LN2(x) -> bf16, + routing (no atomics)
    ln2route_k<<<T_/4, 256, 0, stream>>>(x, ln2_w + (size_t)l*D_, ln2_b + (size_t)l*D_,
                                         hb, gwl, tok_e, tok_w);
    // plan + scatter, single block, LDS atomics only
    plan_scatter_k<<<1, 1024, 0, stream>>>(tok_e, tok_w, offs, counts, aux, btab, btab64,
                                           rowtok, roww, rowof);
    // FFN1: mid = gelu(gather(h2) @ w1^T + b1) -> bf16   (BM=128)
    gemm_k<128,128,true,true,true,1,false><<<dim3(71,16,1), 256, 0, stream>>>(
      hb, w1tl, mid, eb1l, nullptr, 2*T_, I_, D_, D_, D_, I_,
      1, 0,0,0,0,0,0, 1.f, offs, counts, rowtok, btab, (long)I_*D_, I_);
    // FFN2: eout = mid @ w2^T + b2 -> fp32   (BM=64: ~535 live blocks)
    gemm_k<64,128,true,false,false,0,false><<<dim3(136,4,1), 256, 0, stream>>>(
      mid, w2tl, eout, eb2l, nullptr, 2*T_, D_, I_, I_, I_, D_,
      1, 0,0,0,0,0,0, 1.f, offs, counts, nullptr, btab64, (long)D_*I_, D_);
    // x = LN(h2 + combine(eout))
    ln_moe_k<<<T_/4, 256, 0, stream>>>(eout, rowof, roww, mask, hb,
                                       mln_w + (size_t)l*D_, mln_b + (size_t)l*D_, x);
  }
  // head
  ln_w_k<false><<<T_/4, 256, 0, stream>>>(x, fln_w, fln_b, fout);
  pool2_k<<<dim3(4,8), 256, 0, stream>>>(fout, mask, pooled);
  head_final_k<<<4, 256, 0, stream>>>(pooled, mask, pool_w, pool_b, cls_w, cls_b,
                                      cf_w1, cf_b1, cf_w2, cf_b2, aux, out);
}

// Round 3
// 1490.122 us; speedup vs baseline: 1.0085x; 1.0085x over previous
//
#include <hip/hip_runtime.h>
#include <math.h>

// Problem constants
#define B_ 4
#define S_ 1024
#define D_ 512
#define H_ 8
#define DH_ 64
#define I_ 2048
#define E_ 8
#define L_ 4
#define T_ 4096   // B*S

using bf16x8 = __attribute__((ext_vector_type(8))) __bf16;
using f32x4  = __attribute__((ext_vector_type(4))) float;

typedef __attribute__((address_space(1))) const void gvoid;
typedef __attribute__((address_space(3))) void lvoid;
__device__ __forceinline__ void gl_lds16(const void* g, void* l){
  __builtin_amdgcn_global_load_lds((gvoid*)g, (lvoid*)l, 16, 0, 0);
}

__device__ __forceinline__ float wred_sum(float v){
#pragma unroll
  for(int m=32;m>0;m>>=1) v += __shfl_xor(v, m, 64);
  return v;
}
__device__ __forceinline__ unsigned short f2bf(float f){
  unsigned x = __float_as_uint(f);
  unsigned r = (x + 0x7FFFu + ((x>>16)&1u)) >> 16;
  return (unsigned short)r;
}
__device__ __forceinline__ float bf2f(unsigned short u){
  return __uint_as_float(((unsigned)u)<<16);
}
__device__ __forceinline__ unsigned pk2(float a, float b){
  return (unsigned)f2bf(a) | ((unsigned)f2bf(b)<<16);
}

// ---------------------------------------------------------------------------
// bf16 MFMA GEMM. NT: C[m,n] = sum_k A[m,k]*B[n,k].
// BK=64, double-buffered LDS with async prefetch: stage(t+1) issued before
// compute(t); counted s_waitcnt vmcnt(NLD) + raw s_barrier (NOT __syncthreads,
// which would force vmcnt(0) drain). 1-D grid with XCD-chunked bijective
// swizzle (gridDim.x % 8 == 0 required), n-blocks innermost for A/L2 reuse.
// 4 waves in 2x2. BM in {64,128}, BN in {64,128}.
// MOE: block table btab[bx] = (e<<8)|mblk, -1 = dead. Optional row gather.
// ---------------------------------------------------------------------------
template<int BM, int BN, bool MOE, bool GATHER, bool OUT_BF16, int ACT, bool ADD_IN>
__global__ __launch_bounds__(256)
void gemm_k(const unsigned short* __restrict__ A, const unsigned short* __restrict__ Bv,
            void* Cp, const float* __restrict__ bias, const float* addin,
            int M, int N, int K, int lda, int ldb, int ldc,
            int hdiv, long sAb, long sAh, long sBb, long sBh, long sCb, long sCh,
            float scale,
            const int* __restrict__ moff, const int* __restrict__ mcnt,
            const int* __restrict__ rowtok, const int* __restrict__ btab,
            long sBe, int biasStride, int nby)
{
  constexpr int BK = 64;
  constexpr int WM = BM/2, WN = BN/2, FM = WM/16, FNN = WN/16;
  constexpr int RPC = 2048/BK;       // rows covered per block-wide gl_lds16 call
  constexpr int NA = BM/RPC, NB = BN/RPC;
  constexpr int NLD = NA + NB;       // gl_lds issued per wave per K-step
  __shared__ unsigned short As[2*BM*BK];
  __shared__ unsigned short Bs[2*BN*BK];

  const int tid = threadIdx.x, wid = tid>>6, lane = tid&63;
  const int wy = wid>>1, wx = wid&1, ln16 = lane&15, q8 = (lane>>4)*8;

  // XCD-chunked bijective swizzle: consecutive hw ids round-robin XCDs;
  // remap so each XCD owns a contiguous chunk of (bx,by) space, by innermost.
  const int nwg = gridDim.x, cpx = nwg >> 3;
  const int lin = blockIdx.x;
  const int wg  = (lin & 7)*cpx + (lin >> 3);
  const int bxi = wg / nby, byi = wg % nby;

  int m0 = bxi*BM;
  const int n0 = byi*BN;

  float* Cf = nullptr; unsigned short* Ch = nullptr;
  const float* biasp = bias;
  const unsigned short* Bp = Bv;
  int seg = 0, cnt = M;

  if constexpr (MOE){
    int tv = btab[bxi];
    if (tv < 0) return;
    int e = tv>>8;
    m0 = (tv&255)*BM;
    seg = moff[e]; cnt = mcnt[e];
    Bp = Bv + (long)e*sBe;
    if constexpr (OUT_BF16) Ch = (unsigned short*)Cp; else Cf = (float*)Cp;
    if (biasp) biasp += (long)e*biasStride;
  } else {
    int z = blockIdx.z, zb = z/hdiv, zh = z%hdiv;
    A  += (long)zb*sAb + (long)zh*sAh;
    Bp += (long)zb*sBb + (long)zh*sBh;
    long coff = (long)zb*sCb + (long)zh*sCh;
    if constexpr (OUT_BF16) Ch = (unsigned short*)Cp + coff; else Cf = ((float*)Cp) + coff;
    if constexpr (ADD_IN) addin += coff;
  }

  // staging geometry: call j covers rows j*RPC + tid/(BK/8), col (tid%(BK/8))*8
  const int srow = tid >> 3;          // BK/8 = 8 lanes per row
  const int scol = (tid & 7) * 8;
  long ga[NA], gb[NB];
#pragma unroll
  for (int j=0; j<NA; j++){
    int r = m0 + j*RPC + srow;
    if constexpr (MOE){
      r = min(r, cnt-1);
      long gr = GATHER ? (long)rowtok[seg+r] : (long)(seg+r);
      ga[j] = gr*lda + scol;
    } else {
      ga[j] = (long)min(r, M-1)*lda + scol;
    }
  }
#pragma unroll
  for (int j=0; j<NB; j++){
    int bn = min(n0 + j*RPC + srow, N-1);
    gb[j] = (long)bn*ldb + scol;
  }

  f32x4 acc[FM][FNN];
#pragma unroll
  for(int i=0;i<FM;i++)
#pragma unroll
    for(int j=0;j<FNN;j++){ f32x4 z = {0.f,0.f,0.f,0.f}; acc[i][j] = z; }

  const int nt = K/BK;
  int cur = 0;
  // prologue: stage tile 0 into buffer 0
#pragma unroll
  for (int j=0; j<NA; j++) gl_lds16(A + ga[j], As + j*2048 + wid*512);
#pragma unroll
  for (int j=0; j<NB; j++) gl_lds16(Bp + gb[j], Bs + j*2048 + wid*512);

  for (int t = 0; t < nt; ++t){
    const int cb = cur;
    if (t+1 < nt){
      const int nb2 = cur^1;
      const int k0 = (t+1)*BK;
#pragma unroll
      for (int j=0; j<NA; j++) gl_lds16(A + ga[j] + k0, As + nb2*BM*BK + j*2048 + wid*512);
#pragma unroll
      for (int j=0; j<NB; j++) gl_lds16(Bp + gb[j] + k0, Bs + nb2*BN*BK + j*2048 + wid*512);
      asm volatile("s_waitcnt vmcnt(%0)" :: "n"(NLD) : "memory");  // cur's loads done; next's in flight
    } else {
      asm volatile("s_waitcnt vmcnt(0)" ::: "memory");
    }
    __builtin_amdgcn_s_barrier();          // all waves' cur-tile loads landed
    __builtin_amdgcn_sched_barrier(0);     // pin: no ds_read hoists above barrier
#pragma unroll
    for (int kk=0; kk<2; kk++){
      bf16x8 fa[FM], fb[FNN];
#pragma unroll
      for(int i=0;i<FM;i++) fa[i] = *(const bf16x8*)&As[cb*BM*BK + (wy*WM + i*16 + ln16)*BK + kk*32 + q8];
#pragma unroll
      for(int j=0;j<FNN;j++) fb[j] = *(const bf16x8*)&Bs[cb*BN*BK + (wx*WN + j*16 + ln16)*BK + kk*32 + q8];
#pragma unroll
      for(int i=0;i<FM;i++)
#pragma unroll
        for(int j=0;j<FNN;j++)
          acc[i][j] = __builtin_amdgcn_mfma_f32_16x16x32_bf16(fa[i], fb[j], acc[i][j], 0, 0, 0);
    }
    __builtin_amdgcn_sched_barrier(0);     // pin: no ds_read sinks below barrier
    __builtin_amdgcn_s_barrier();          // buf[cur] reads done before t+2 overwrites it
    cur ^= 1;
  }

  // epilogue: C[m = quad*4+r][n = lane&15]
#pragma unroll
  for(int i=0;i<FM;i++){
    int mbase = m0 + wy*WM + i*16 + (lane>>4)*4;
#pragma unroll
    for(int j=0;j<FNN;j++){
      int n = n0 + wx*WN + j*16 + ln16;
      float bv = biasp ? biasp[n] : 0.f;
      f32x4 v = acc[i][j];
#pragma unroll
      for(int r=0;r<4;r++){
        int m = mbase + r;
        if (m < cnt){
          float x = v[r]*scale + bv;
          if constexpr (ACT == 1) x = 0.5f*x*(1.f + erff(x*0.70710678118654752f));
          long ci = (long)(MOE ? seg + m : m)*ldc + n;
          if constexpr (ADD_IN) x += addin[ci];
          if constexpr (OUT_BF16) Ch[ci] = f2bf(x);
          else Cf[ci] = x;
        }
      }
    }
  }
}

// ---------------------------------------------------------------------------
// Fused flash attention. grid (S/64, B*H). 4 waves, each owns 16 Q-rows.
// ---------------------------------------------------------------------------
__global__ __launch_bounds__(256)
void flash_k(const unsigned short* __restrict__ qkvb, const unsigned short* __restrict__ Vt,
             unsigned short* __restrict__ ctx)
{
  __shared__ unsigned short Pl[4][16*72];
  const int qt = blockIdx.x, z = blockIdx.y, b = z>>3, h = z&7;
  const int wid = threadIdx.x>>6, lane = threadIdx.x&63;
  const int ln16 = lane&15, g = lane>>4;
  const int q0 = qt*64 + wid*16;
  unsigned short* Pw = &Pl[wid][0];

  const unsigned short* Qp = qkvb + (long)(b*1024 + q0 + ln16)*1536 + h*64 + g*8;
  bf16x8 qf0 = *(const bf16x8*)Qp;
  bf16x8 qf1 = *(const bf16x8*)(Qp + 32);
  const unsigned short* Kbase = qkvb + (long)b*1024*1536 + 512 + h*64 + g*8;
  const unsigned short* Vbase = Vt + (long)z*65536 + g*8;

  float m_s[4], l_s[4];
  f32x4 oacc[4];
#pragma unroll
  for(int r=0;r<4;r++){ m_s[r] = -1e30f; l_s[r] = 0.f; }
#pragma unroll
  for(int j=0;j<4;j++){ f32x4 zz = {0.f,0.f,0.f,0.f}; oacc[j] = zz; }

  for (int t = 0; t < 16; ++t){
    bf16x8 kf[4][2], vf[4][2];
#pragma unroll
    for(int j=0;j<4;j++){
      const unsigned short* kp = Kbase + (long)(t*64 + j*16 + ln16)*1536;
      kf[j][0] = *(const bf16x8*)kp;
      kf[j][1] = *(const bf16x8*)(kp + 32);
      const unsigned short* vp = Vbase + (long)(j*16 + ln16)*1024 + t*64;
      vf[j][0] = *(const bf16x8*)vp;
      vf[j][1] = *(const bf16x8*)(vp + 32);
    }
    f32x4 sacc[4];
#pragma unroll
    for(int j=0;j<4;j++){ f32x4 zz = {0.f,0.f,0.f,0.f}; sacc[j] = zz; }
#pragma unroll
    for(int j=0;j<4;j++){
      sacc[j] = __builtin_amdgcn_mfma_f32_16x16x32_bf16(qf0, kf[j][0], sacc[j], 0,0,0);
      sacc[j] = __builtin_amdgcn_mfma_f32_16x16x32_bf16(qf1, kf[j][1], sacc[j], 0,0,0);
    }
#pragma unroll
    for(int j=0;j<4;j++)
#pragma unroll
      for(int r=0;r<4;r++) sacc[j][r] *= 0.125f;
    float alpha[4];
#pragma unroll
    for(int r=0;r<4;r++){
      float mx = fmaxf(fmaxf(sacc[0][r], sacc[1][r]), fmaxf(sacc[2][r], sacc[3][r]));
#pragma unroll
      for(int m=1;m<16;m<<=1) mx = fmaxf(mx, __shfl_xor(mx, m, 64));
      float mn = fmaxf(m_s[r], mx);
      alpha[r] = __expf(m_s[r] - mn);
      m_s[r] = mn;
    }
#pragma unroll
    for(int j=0;j<4;j++)
#pragma unroll
      for(int r=0;r<4;r++) sacc[j][r] = __expf(sacc[j][r] - m_s[r]);
#pragma unroll
    for(int r=0;r<4;r++){
      float rs = sacc[0][r]+sacc[1][r]+sacc[2][r]+sacc[3][r];
#pragma unroll
      for(int m=1;m<16;m<<=1) rs += __shfl_xor(rs, m, 64);
      l_s[r] = l_s[r]*alpha[r] + rs;
    }
#pragma unroll
    for(int j=0;j<4;j++)
#pragma unroll
      for(int r=0;r<4;r++) oacc[j][r] *= alpha[r];
#pragma unroll
    for(int j=0;j<4;j++)
#pragma unroll
      for(int r=0;r<4;r++)
        Pw[(g*4+r)*72 + j*16 + ln16] = f2bf(sacc[j][r]);
    bf16x8 pf0 = *(const bf16x8*)&Pw[ln16*72 + g*8];
    bf16x8 pf1 = *(const bf16x8*)&Pw[ln16*72 + 32 + g*8];
#pragma unroll
    for(int j=0;j<4;j++){
      oacc[j] = __builtin_amdgcn_mfma_f32_16x16x32_bf16(pf0, vf[j][0], oacc[j], 0,0,0);
      oacc[j] = __builtin_amdgcn_mfma_f32_16x16x32_bf16(pf1, vf[j][1], oacc[j], 0,0,0);
    }
  }
#pragma unroll
  for(int r=0;r<4;r++){
    float inv = 1.f/l_s[r];
    long row = (long)(b*1024 + q0 + g*4 + r)*512 + h*64;
#pragma unroll
    for(int j=0;j<4;j++)
      ctx[row + j*16 + ln16] = f2bf(oacc[j][r]*inv);
  }
}

// ---------------------------------------------------------------------------
// Wave-per-row LayerNorm (D=512): 4 rows/block, no barriers.
// ---------------------------------------------------------------------------
template<bool OUT_BF16>
__global__ __launch_bounds__(256)
void ln_w_k(const float* __restrict__ in, const float* __restrict__ w,
            const float* __restrict__ bb, void* __restrict__ outp)
{
  int row = blockIdx.x*4 + (threadIdx.x>>6), lane = threadIdx.x&63;
  const float4* p = (const float4*)(in + (long)row*512 + lane*8);
  float4 a = p[0], c = p[1];
  float s = a.x+a.y+a.z+a.w + c.x+c.y+c.z+c.w;
  float q = a.x*a.x+a.y*a.y+a.z*a.z+a.w*a.w + c.x*c.x+c.y*c.y+c.z*c.z+c.w*c.w;
  s = wred_sum(s); q = wred_sum(q);
  float mean = s*(1.f/512.f);
  float var  = q*(1.f/512.f) - mean*mean;
  float inv  = rsqrtf(var + 1e-5f);
  const float4* wp = (const float4*)(w + lane*8);
  const float4* bp = (const float4*)(bb + lane*8);
  float4 w0 = wp[0], w1 = wp[1], b0 = bp[0], b1 = bp[1];
  float o0 = (a.x-mean)*inv*w0.x + b0.x, o1 = (a.y-mean)*inv*w0.y + b0.y;
  float o2 = (a.z-mean)*inv*w0.z + b0.z, o3 = (a.w-mean)*inv*w0.w + b0.w;
  float o4 = (c.x-mean)*inv*w1.x + b1.x, o5 = (c.y-mean)*inv*w1.y + b1.y;
  float o6 = (c.z-mean)*inv*w1.z + b1.z, o7 = (c.w-mean)*inv*w1.w + b1.w;
  if constexpr (OUT_BF16){
    *(uint4*)((unsigned short*)outp + (long)row*512 + lane*8) =
      make_uint4(pk2(o0,o1), pk2(o2,o3), pk2(o4,o5), pk2(o6,o7));
  } else {
    float4* op = (float4*)((float*)outp + (long)row*512 + lane*8);
    op[0] = make_float4(o0,o1,o2,o3);
    op[1] = make_float4(o4,o5,o6,o7);
  }
}

// LN2 + router fused: h2 = LN(x) (bf16 out) then top-2 gate; NO global atomics.
__global__ __launch_bounds__(256)
void ln2route_k(const float* __restrict__ in, const float* __restrict__ w,
                const float* __restrict__ bb, unsigned short* __restrict__ h2,
                const float* __restrict__ gw,
                int* __restrict__ tok_e, float* __restrict__ tok_w)
{
  int tok = blockIdx.x*4 + (threadIdx.x>>6), lane = threadIdx.x&63;
  const float4* p = (const float4*)(in + (long)tok*512 + lane*8);
  float4 a = p[0], c = p[1];
  float s = a.x+a.y+a.z+a.w + c.x+c.y+c.z+c.w;
  float q = a.x*a.x+a.y*a.y+a.z*a.z+a.w*a.w + c.x*c.x+c.y*c.y+c.z*c.z+c.w*c.w;
  s = wred_sum(s); q = wred_sum(q);
  float mean = s*(1.f/512.f);
  float var  = q*(1.f/512.f) - mean*mean;
  float inv  = rsqrtf(var + 1e-5f);
  const float4* wp = (const float4*)(w + lane*8);
  const float4* bp = (const float4*)(bb + lane*8);
  float4 w0 = wp[0], w1 = wp[1], b0 = bp[0], b1 = bp[1];
  float o[8];
  o[0] = (a.x-mean)*inv*w0.x + b0.x; o[1] = (a.y-mean)*inv*w0.y + b0.y;
  o[2] = (a.z-mean)*inv*w0.z + b0.z; o[3] = (a.w-mean)*inv*w0.w + b0.w;
  o[4] = (c.x-mean)*inv*w1.x + b1.x; o[5] = (c.y-mean)*inv*w1.y + b1.y;
  o[6] = (c.z-mean)*inv*w1.z + b1.z; o[7] = (c.w-mean)*inv*w1.w + b1.w;
  *(uint4*)(h2 + (long)tok*512 + lane*8) =
    make_uint4(pk2(o[0],o[1]), pk2(o[2],o[3]), pk2(o[4],o[5]), pk2(o[6],o[7]));
  float lg[8];
#pragma unroll
  for(int e=0;e<8;e++){
    const float4* gr = (const float4*)(gw + e*512 + lane*8);
    float4 g0 = gr[0], g1 = gr[1];
    float d = o[0]*g0.x + o[1]*g0.y + o[2]*g0.z + o[3]*g0.w
            + o[4]*g1.x + o[5]*g1.y + o[6]*g1.z + o[7]*g1.w;
    lg[e] = wred_sum(d);
  }
  if (lane == 0){
    float mx = lg[0];
#pragma unroll
    for(int e=1;e<8;e++) mx = fmaxf(mx, lg[e]);
    float pr[8];
#pragma unroll
    for(int e=0;e<8;e++) pr[e] = expf(lg[e]-mx);
    int e0 = 0; float p0 = pr[0];
#pragma unroll
    for(int e=1;e<8;e++) if (pr[e] > p0){ p0 = pr[e]; e0 = e; }
    int e1 = -1; float p1 = -1.f;
#pragma unroll
    for(int e=0;e<8;e++) if (e != e0 && pr[e] > p1){ p1 = pr[e]; e1 = e; }
    float invp = 1.f/(p0+p1);
    tok_e[2*tok] = e0; tok_e[2*tok+1] = e1;
    tok_w[2*tok] = p0*invp; tok_w[2*tok+1] = p1*invp;
  }
}

// ---------------------------------------------------------------------------
// Single-block planner + scatter: LDS-atomic histogram, offsets, two block
// tables (BM=128 for FFN1, BM=64 for FFN2), aux, and compaction scatter.
// ---------------------------------------------------------------------------
__global__ __launch_bounds__(1024)
void plan_scatter_k(const int* __restrict__ tok_e, const float* __restrict__ tok_w,
                    int* __restrict__ offs, int* __restrict__ cnts, float* __restrict__ aux,
                    int* __restrict__ btab, int* __restrict__ btab64,
                    int* __restrict__ rowtok, float* __restrict__ roww, int* __restrict__ rowof)
{
  __shared__ int hist[8];
  __shared__ int offsS[8];
  __shared__ int base[8];
  const int t = threadIdx.x;
  if (t < 8) hist[t] = 0;
  __syncthreads();
  int e[8]; float w[8];
#pragma unroll
  for (int i=0;i<8;i++){
    e[i] = tok_e[t + i*1024];
    w[i] = tok_w[t + i*1024];
    atomicAdd(&hist[e[i]], 1);
  }
  __syncthreads();
  if (t == 0){
    int o = 0, idx = 0, idx2 = 0; float a = 0.f;
    for (int ee=0; ee<8; ee++){
      offsS[ee] = o;
      int c = hist[ee];
      o += c;
      float u = (float)c*(1.f/4096.f) - 0.125f;
      a += u*u;
      int nb = (c + 127) >> 7;
      for (int j=0;j<nb;j++) btab[idx++] = (ee<<8)|j;
      int nb2 = (c + 63) >> 6;
      for (int j=0;j<nb2;j++) btab64[idx2++] = (ee<<8)|j;
    }
    while (idx < 80) btab[idx++] = -1;
    while (idx2 < 144) btab64[idx2++] = -1;
    *aux += a*(1.f/8.f);
  }
  __syncthreads();
  if (t < 8){
    cnts[t] = hist[t];
    offs[t] = offsS[t];
    base[t] = offsS[t];
  }
  __syncthreads();
#pragma unroll
  for (int i=0;i<8;i++){
    int pos = atomicAdd(&base[e[i]], 1);   // LDS atomic
    int gi = t + i*1024;
    rowtok[pos] = gi>>1;
    roww[pos] = w[i];
    rowof[gi] = pos;
  }
}

// Fused MoE combine + LN, wave per token
__global__ __launch_bounds__(256)
void ln_moe_k(const float* __restrict__ eout, const int* __restrict__ rowof,
              const float* __restrict__ roww, const float* __restrict__ mask,
              const unsigned short* __restrict__ h2,
              const float* __restrict__ w, const float* __restrict__ bb,
              float* __restrict__ outp)
{
  int tok = blockIdx.x*4 + (threadIdx.x>>6), lane = threadIdx.x&63;
  int r0 = rowof[2*tok], r1 = rowof[2*tok+1];
  float w0w = roww[r0], w1w = roww[r1], mk = mask[tok];
  const float4* ap = (const float4*)(eout + (long)r0*512 + lane*8);
  const float4* bp2 = (const float4*)(eout + (long)r1*512 + lane*8);
  float4 a0 = ap[0], a1 = ap[1], c0 = bp2[0], c1 = bp2[1];
  uint4 hu = *(const uint4*)(h2 + (long)tok*512 + lane*8);
  const unsigned short* hh = (const unsigned short*)&hu;
  float v[8];
  v[0] = bf2f(hh[0]) + (a0.x*w0w + c0.x*w1w)*mk;
  v[1] = bf2f(hh[1]) + (a0.y*w0w + c0.y*w1w)*mk;
  v[2] = bf2f(hh[2]) + (a0.z*w0w + c0.z*w1w)*mk;
  v[3] = bf2f(hh[3]) + (a0.w*w0w + c0.w*w1w)*mk;
  v[4] = bf2f(hh[4]) + (a1.x*w0w + c1.x*w1w)*mk;
  v[5] = bf2f(hh[5]) + (a1.y*w0w + c1.y*w1w)*mk;
  v[6] = bf2f(hh[6]) + (a1.z*w0w + c1.z*w1w)*mk;
  v[7] = bf2f(hh[7]) + (a1.w*w0w + c1.w*w1w)*mk;
  float s = 0.f, q = 0.f;
#pragma unroll
  for(int i=0;i<8;i++){ s += v[i]; q += v[i]*v[i]; }
  s = wred_sum(s); q = wred_sum(q);
  float mean = s*(1.f/512.f);
  float var  = q*(1.f/512.f) - mean*mean;
  float inv  = rsqrtf(var + 1e-5f);
  const float4* wp = (const float4*)(w + lane*8);
  const float4* bpp = (const float4*)(bb + lane*8);
  float4 w0 = wp[0], w1 = wp[1], b0 = bpp[0], b1 = bpp[1];
  float wv[8] = {w0.x,w0.y,w0.z,w0.w,w1.x,w1.y,w1.z,w1.w};
  float bv[8] = {b0.x,b0.y,b0.z,b0.w,b1.x,b1.y,b1.z,b1.w};
  float4* op = (float4*)(outp + (long)tok*512 + lane*8);
  op[0] = make_float4((v[0]-mean)*inv*wv[0]+bv[0], (v[1]-mean)*inv*wv[1]+bv[1],
                      (v[2]-mean)*inv*wv[2]+bv[2], (v[3]-mean)*inv*wv[3]+bv[3]);
  op[1] = make_float4((v[4]-mean)*inv*wv[4]+bv[4], (v[5]-mean)*inv*wv[5]+bv[5],
                      (v[6]-mean)*inv*wv[6]+bv[6], (v[7]-mean)*inv*wv[7]+bv[7]);
}

// Build Vt[bh][d][k] bf16 from qkv V slice; grid (4,32), 4 chunks per block
__global__ __launch_bounds__(256)
void vt_k(const unsigned short* __restrict__ qkvb, unsigned short* __restrict__ Vt)
{
  __shared__ unsigned short tile[64][80];
  int z = blockIdx.y, b = z>>3, h = z&7;
  int t = threadIdx.x;
  int kk = t>>2, dd = (t&3)*16;
  int dd2 = t>>2, kk2 = (t&3)*16;
  for (int c = 0; c < 4; ++c){
    int k0 = (blockIdx.x*4 + c)*64;
    const unsigned short* p = qkvb + ((long)(b*1024 + k0 + kk))*1536 + 1024 + h*64 + dd;
    uint4 u0 = *(const uint4*)p, u1 = *(const uint4*)(p+8);
    __syncthreads();
    *(uint4*)&tile[kk][dd] = u0;
    *(uint4*)&tile[kk][dd+8] = u1;
    __syncthreads();
    uint4 o0, o1;
    unsigned short* s0 = (unsigned short*)&o0;
    unsigned short* s1 = (unsigned short*)&o1;
#pragma unroll
    for(int j=0;j<8;j++){ s0[j] = tile[kk2+j][dd2]; s1[j] = tile[kk2+8+j][dd2]; }
    unsigned short* o = Vt + (long)z*65536 + (long)dd2*1024 + k0 + kk2;
    *(uint4*)o = o0; *(uint4*)(o+8) = o1;
  }
}

// fp32 (R,C) -> bf16 (C,R), z-loop of ZL
__global__ __launch_bounds__(256)
void transpose_cast_k(const float* __restrict__ in, unsigned short* __restrict__ outp,
                      int R, int C, int ZL)
{
  __shared__ float tile[64][65];
  int t = threadIdx.x;
  int rr = t>>2, cc = (t&3)*16;
  int cc2 = t>>2, rr2 = (t&3)*16;
  int c0 = blockIdx.x*64, r0 = blockIdx.y*64;
  for (int zi = 0; zi < ZL; ++zi){
    long zoff = (long)(blockIdx.z*ZL + zi) * R * C;
    const float* pin = in + zoff + (long)(r0+rr)*C + c0 + cc;
    float4 v0=*(const float4*)pin, v1=*(const float4*)(pin+4), v2=*(const float4*)(pin+8), v3=*(const float4*)(pin+12);
    __syncthreads();
    tile[rr][cc+0]=v0.x; tile[rr][cc+1]=v0.y; tile[rr][cc+2]=v0.z; tile[rr][cc+3]=v0.w;
    tile[rr][cc+4]=v1.x; tile[rr][cc+5]=v1.y; tile[rr][cc+6]=v1.z; tile[rr][cc+7]=v1.w;
    tile[rr][cc+8]=v2.x; tile[rr][cc+9]=v2.y; tile[rr][cc+10]=v2.z; tile[rr][cc+11]=v2.w;
    tile[rr][cc+12]=v3.x; tile[rr][cc+13]=v3.y; tile[rr][cc+14]=v3.z; tile[rr][cc+15]=v3.w;
    __syncthreads();
    unsigned tmp[8];
#pragma unroll
    for(int jj=0;jj<8;jj++)
      tmp[jj] = pk2(tile[rr2+2*jj][cc2], tile[rr2+2*jj+1][cc2]);
    uint4* dst = (uint4*)(outp + zoff + (long)(c0+cc2)*R + r0 + rr2);
    dst[0] = make_uint4(tmp[0],tmp[1],tmp[2],tmp[3]);
    dst[1] = make_uint4(tmp[4],tmp[5],tmp[6],tmp[7]);
  }
}

// fp32 -> bf16, grid-stride
__global__ __launch_bounds__(256)
void cast_bf16_k(const float* __restrict__ in, unsigned short* __restrict__ outp, int n8)
{
  for (int i = blockIdx.x*256 + threadIdx.x; i < n8; i += gridDim.x*256){
    const float4* p = (const float4*)(in + (long)i*8);
    float4 a = p[0], b = p[1];
    *(uint4*)(outp + (long)i*8) = make_uint4(pk2(a.x,a.y), pk2(a.z,a.w), pk2(b.x,b.y), pk2(b.z,b.w));
  }
}

// masked-sum partial pooling, NO atomics: grid (4,8) -> 8 partials per batch
__global__ __launch_bounds__(256)
void pool2_k(const float* __restrict__ h, const float* __restrict__ mask, float* __restrict__ pooled)
{
  int b = blockIdx.x, sc = blockIdx.y, t = threadIdx.x;
  float a0 = 0.f, a1 = 0.f;
  const float* mb = mask + b*1024 + sc*128;
  const float* hbase = h + ((long)b*1024 + sc*128)*512;
  for (int s = 0; s < 128; ++s){
    float mk = mb[s];
    const float* r = hbase + (long)s*512;
    a0 += r[t]*mk; a1 += r[t+256]*mk;
  }
  pooled[((b*8 + sc)*512) + t] = a0;
  pooled[((b*8 + sc)*512) + t + 256] = a1;
}

__global__ __launch_bounds__(256)
void head_final_k(const float* __restrict__ pooled, const float* __restrict__ mask,
                  const float* __restrict__ pool_w, const float* __restrict__ pool_b,
                  const float* __restrict__ cls_w, const float* __restrict__ cls_b,
                  const float* __restrict__ cf_w1, const float* __restrict__ cf_b1,
                  const float* __restrict__ cf_w2, const float* __restrict__ cf_b2,
                  const float* __restrict__ aux, float* __restrict__ out)
{
  int b = blockIdx.x, t = threadIdx.x, wid = t>>6, lane = t&63;
  __shared__ __align__(16) float pld[512];
  __shared__ __align__(16) float p2[512];
  __shared__ float red[4];
  float ds = 0.f;
  for(int s=t; s<1024; s+=256) ds += mask[b*1024 + s];
  ds = wred_sum(ds);
  if (lane==0) red[wid] = ds;
  __syncthreads();
  float denom = fmaxf(red[0]+red[1]+red[2]+red[3], 1e-9f);
  float s0 = 0.f, s1 = 0.f;
#pragma unroll
  for(int sc=0;sc<8;sc++){
    s0 += pooled[((b*8+sc)*512) + t];
    s1 += pooled[((b*8+sc)*512) + t + 256];
  }
  pld[t]     = s0/denom;
  pld[t+256] = s1/denom;
  __syncthreads();
#pragma unroll
  for(int jj=0;jj<2;jj++){
    int j = t + jj*256;
    const float4* wr = (const float4*)(pool_w + (long)j*512);
    float acc = 0.f;
    for(int i=0;i<128;i++){
      float4 w4 = wr[i]; float4 x4 = ((const float4*)pld)[i];
      acc += w4.x*x4.x + w4.y*x4.y + w4.z*x4.z + w4.w*x4.w;
    }
    p2[j] = tanhf(acc + pool_b[j]);
  }
  __syncthreads();
  if (t < 4){
    const float4* wr = (const float4*)(cls_w + (long)t*512);
    float acc = 0.f;
    for(int i=0;i<128;i++){
      float4 w4 = wr[i]; float4 x4 = ((const float4*)p2)[i];
      acc += w4.x*x4.x + w4.y*x4.y + w4.z*x4.z + w4.w*x4.w;
    }
    out[b*4 + t] = acc + cls_b[t];
  }
  {
    const float4* wr = (const float4*)(cf_w1 + (long)t*512);
    float acc = 0.f;
    for(int i=0;i<128;i++){
      float4 w4 = wr[i]; float4 x4 = ((const float4*)p2)[i];
      acc += w4.x*x4.x + w4.y*x4.y + w4.z*x4.z + w4.w*x4.w;
    }
    acc = fmaxf(acc + cf_b1[t], 0.f) * cf_w2[t];
    acc = wred_sum(acc);
    __syncthreads();
    if (lane==0) red[wid] = acc;
    __syncthreads();
    if (t == 0){
      float sum = red[0]+red[1]+red[2]+red[3];
      out[17 + b] = 1.f/(1.f + expf(-(sum + cf_b2[0])));
    }
  }
  if (b == 0 && t == 0) out[16] = aux[0]*0.25f;
}

// ---------------------------------------------------------------------------
extern "C" void kernel_launch(void* const* d_in, const int* in_sizes, int n_in,
                              void* d_out, int out_size, void* d_ws, size_t ws_size,
                              hipStream_t stream)
{
  (void)in_sizes; (void)n_in; (void)out_size;
  const float* emb    = (const float*)d_in[0];
  const float* mask   = (const float*)d_in[1];
  const float* in_w   = (const float*)d_in[2];
  const float* in_b   = (const float*)d_in[3];
  const float* out_w  = (const float*)d_in[4];
  const float* out_b  = (const float*)d_in[5];
  const float* ln1_w  = (const float*)d_in[6];
  const float* ln1_b  = (const float*)d_in[7];
  const float* ln2_w  = (const float*)d_in[8];
  const float* ln2_b  = (const float*)d_in[9];
  const float* gate_w = (const float*)d_in[10];
  const float* e_w1   = (const float*)d_in[11];
  const float* e_b1   = (const float*)d_in[12];
  const float* e_w2   = (const float*)d_in[13];
  const float* e_b2   = (const float*)d_in[14];
  const float* mln_w  = (const float*)d_in[15];
  const float* mln_b  = (const float*)d_in[16];
  const float* fln_w  = (const float*)d_in[17];
  const float* fln_b  = (const float*)d_in[18];
  const float* pool_w = (const float*)d_in[19];
  const float* pool_b = (const float*)d_in[20];
  const float* cls_w  = (const float*)d_in[21];
  const float* cls_b  = (const float*)d_in[22];
  const float* cf_w1  = (const float*)d_in[23];
  const float* cf_b1  = (const float*)d_in[24];
  const float* cf_w2  = (const float*)d_in[25];
  const float* cf_b2  = (const float*)d_in[26];
  float* out = (float*)d_out;
  char* ws = (char*)d_ws;

  const size_t MiB = 1024*1024;
  if (ws_size < 218*MiB) return;

  // Workspace layout
  float*          x     = (float*)(ws + 0*MiB);             // 8 MiB fp32
  unsigned short* hb    = (unsigned short*)(ws + 8*MiB);    // 4 MiB bf16
  unsigned short* qkvb  = (unsigned short*)(ws + 12*MiB);   // 12 MiB bf16
  unsigned short* ctx   = (unsigned short*)(ws + 24*MiB);   // 4 MiB bf16
  unsigned short* Vt    = (unsigned short*)(ws + 28*MiB);   // 4 MiB bf16
  unsigned short* mid   = (unsigned short*)(ws + 32*MiB);   // 32 MiB bf16
  float*          eout  = (float*)(ws + 64*MiB);            // 16 MiB fp32
  float*          fout  = (float*)(ws + 64*MiB);            //   (reuse, head)
  unsigned short* w1t   = (unsigned short*)(ws + 80*MiB);   // 64 MiB bf16
  unsigned short* w2t   = (unsigned short*)(ws + 144*MiB);  // 64 MiB bf16
  unsigned short* inwb  = (unsigned short*)(ws + 208*MiB);  // 6 MiB bf16
  unsigned short* outwb = (unsigned short*)(ws + 214*MiB);  // 2 MiB bf16
  char* misc = ws + 216*MiB;
  int*   counts  = (int*)(misc + 0);
  int*   offs    = (int*)(misc + 64);
  float* aux     = (float*)(misc + 128);
  int*   btab    = (int*)(misc + 256);       // 80 ints
  int*   btab64  = (int*)(misc + 1024);      // 144 ints
  float* pooled  = (float*)(misc + 4096);    // 64 KiB
  int*   tok_e   = (int*)(misc + 81920);
  float* tok_w   = (float*)(misc + 114688);
  int*   rowtok  = (int*)(misc + 147456);
  float* roww    = (float*)(misc + 180224);
  int*   rowof   = (int*)(misc + 212992);

  hipMemcpyAsync(x, emb, (size_t)T_*D_*4, hipMemcpyDeviceToDevice, stream);
  hipMemsetAsync(aux, 0, 4, stream);
  // weight prep
  cast_bf16_k<<<512, 256, 0, stream>>>(in_w, inwb, L_*3*D_*D_/8);
  cast_bf16_k<<<256, 256, 0, stream>>>(out_w, outwb, L_*D_*D_/8);
  transpose_cast_k<<<dim3(I_/64, D_/64, 4), 256, 0, stream>>>(e_w1, w1t, D_, I_, 8);
  transpose_cast_k<<<dim3(D_/64, I_/64, 4), 256, 0, stream>>>(e_w2, w2t, I_, D_, 8);

  for (int l=0; l<L_; l++){
    const float* inbl  = in_b  + (size_t)l*3*D_;
    const float* outbl = out_b + (size_t)l*D_;
    const float* gwl   = gate_w + (size_t)l*E_*D_;
    const float* eb1l  = e_b1 + (size_t)l*E_*I_;
    const float* eb2l  = e_b2 + (size_t)l*E_*D_;
    const unsigned short* inwbl  = inwb + (size_t)l*3*D_*D_;
    const unsigned short* outwbl = outwb + (size_t)l*D_*D_;
    const unsigned short* w1tl = w1t + (size_t)l*E_*I_*D_;
    const unsigned short* w2tl = w2t + (size_t)l*E_*D_*I_;

    // h = LN1(x) -> bf16
    ln_w_k<true><<<T_/4, 256, 0, stream>>>(x, ln1_w + (size_t)l*D_, ln1_b + (size_t)l*D_, hb);
    // qkv = h @ in_w^T + in_b -> bf16   (64x128: 768 blocks, nby=12)
    gemm_k<64,128,false,false,true,0,false><<<dim3(768,1,1), 256, 0, stream>>>(
      hb, inwbl, qkvb, inbl, nullptr, T_, 3*D_, D_, D_, D_, 3*D_,
      1, 0,0,0,0,0,0, 1.f, nullptr, nullptr, nullptr, nullptr, 0, 0, 12);
    vt_k<<<dim3(4,32), 256, 0, stream>>>(qkvb, Vt);
    // fused attention -> ctx (B,S,512) bf16
    flash_k<<<dim3(16,32), 256, 0, stream>>>(qkvb, Vt, ctx);
    // x = x + ctx @ out_w^T + out_b  (fp32)   (64x64: 512 blocks, nby=8)
    gemm_k<64,64,false,false,false,0,true><<<dim3(512,1,1), 256, 0, stream>>>(
      ctx, outwbl, x, outbl, x, T_, D_, D_, D_, D_, D_,
      1, 0,0,0,0,0,0, 1.f, nullptr, nullptr, nullptr, nullptr, 0, 0, 8);
    // h2 = LN2(x) -> bf16, + routing (no atomics)
    ln2route_k<<<T_/4, 256, 0, stream>>>(x, ln2_w + (size_t)l*D_, ln2_b + (size_t)l*D_,
                                         hb, gwl, tok_e, tok_w);
    // plan + scatter, single block, LDS atomics only
    plan_scatter_k<<<1, 1024, 0, stream>>>(tok_e, tok_w, offs, counts, aux, btab, btab64,
                                           rowtok, roww, rowof);
    // FFN1: mid = gelu(gather(h2) @ w1^T + b1) -> bf16   (BM=128, 1136 blocks, nby=16)
    gemm_k<128,128,true,true,true,1,false><<<dim3(1136,1,1), 256, 0, stream>>>(
      hb, w1tl, mid, eb1l, nullptr, 2*T_, I_, D_, D_, D_, I_,
      1, 0,0,0,0,0,0, 1.f, offs, counts, rowtok, btab, (long)I_*D_, I_, 16);
    // FFN2: eout = mid @ w2^T + b2 -> fp32   (BM=64, 544 blocks, nby=4)
    gemm_k<64,128,true,false,false,0,false><<<dim3(544,1,1), 256, 0, stream>>>(
      mid, w2tl, eout, eb2l, nullptr, 2*T_, D_, I_, I_, I_, D_,
      1, 0,0,0,0,0,0, 1.f, offs, counts, nullptr, btab64, (long)D_*I_, D_, 4);
    // x = LN(h2 + combine(eout))
    ln_moe_k<<<T_/4, 256, 0, stream>>>(eout, rowof, roww, mask, hb,
                                       mln_w + (size_t)l*D_, mln_b + (size_t)l*D_, x);
  }
  // head
  ln_w_k<false><<<T_/4, 256, 0, stream>>>(x, fln_w, fln_b, fout);
  pool2_k<<<dim3(4,8), 256, 0, stream>>>(fout, mask, pooled);
  head_final_k<<<4, 256, 0, stream>>>(pooled, mask, pool_w, pool_b, cls_w, cls_b,
                                      cf_w1, cf_b1, cf_w2, cf_b2, aux, out);
}

// Round 4
// 1456.159 us; speedup vs baseline: 1.0321x; 1.0233x over previous
//
#include <hip/hip_runtime.h>
#include <math.h>

// Problem constants
#define B_ 4
#define S_ 1024
#define D_ 512
#define H_ 8
#define DH_ 64
#define I_ 2048
#define E_ 8
#define L_ 4
#define T_ 4096   // B*S

using bf16x8 = __attribute__((ext_vector_type(8))) __bf16;
using f32x4  = __attribute__((ext_vector_type(4))) float;

typedef __attribute__((address_space(1))) const void gvoid;
typedef __attribute__((address_space(3))) void lvoid;
__device__ __forceinline__ void gl_lds16(const void* g, void* l){
  __builtin_amdgcn_global_load_lds((gvoid*)g, (lvoid*)l, 16, 0, 0);
}

__device__ __forceinline__ float wred_sum(float v){
#pragma unroll
  for(int m=32;m>0;m>>=1) v += __shfl_xor(v, m, 64);
  return v;
}
__device__ __forceinline__ unsigned short f2bf(float f){
  unsigned x = __float_as_uint(f);
  unsigned r = (x + 0x7FFFu + ((x>>16)&1u)) >> 16;
  return (unsigned short)r;
}
__device__ __forceinline__ float bf2f(unsigned short u){
  return __uint_as_float(((unsigned)u)<<16);
}
__device__ __forceinline__ unsigned pk2(float a, float b){
  return (unsigned)f2bf(a) | ((unsigned)f2bf(b)<<16);
}

// ---------------------------------------------------------------------------
// bf16 MFMA GEMM. NT: C[m,n] = sum_k A[m,k]*B[n,k].
// BK=64, double-buffered LDS, phase-interleaved schedule:
//   per K-step: [vmcnt(0); s_barrier] then
//     phase0: issue stage A(t+1) | ds_read kk0 | setprio(1) MFMA kk0
//     phase1: issue stage B(t+1) | ds_read kk1 | setprio(1) MFMA kk1
// ONE barrier per K-step (top barrier protects both buffers: a wave passing
// it implies all waves consumed their previous-step ds_reads).
// T2 bank-conflict fix (rule #21 both-sides): LDS dest linear, global SOURCE
// col unit ^= (row&7); fragment reads XOR the same involution.
// 1-D grid with XCD-chunked bijective swizzle (gridDim.x % 8 == 0).
// MOE: block table btab[bx] = (e<<8)|mblk, -1 = dead. Optional row gather.
// ---------------------------------------------------------------------------
template<int BM, int BN, bool MOE, bool GATHER, bool OUT_BF16, int ACT, bool ADD_IN>
__global__ __launch_bounds__(256)
void gemm_k(const unsigned short* __restrict__ A, const unsigned short* __restrict__ Bv,
            void* Cp, const float* __restrict__ bias, const float* addin,
            int M, int N, int K, int lda, int ldb, int ldc,
            int hdiv, long sAb, long sAh, long sBb, long sBh, long sCb, long sCh,
            float scale,
            const int* __restrict__ moff, const int* __restrict__ mcnt,
            const int* __restrict__ rowtok, const int* __restrict__ btab,
            long sBe, int biasStride, int nby)
{
  constexpr int BK = 64;
  constexpr int WM = BM/2, WN = BN/2, FM = WM/16, FNN = WN/16;
  constexpr int RPC = 2048/BK;       // 32 rows covered per block-wide gl_lds16 call
  constexpr int NA = BM/RPC, NB = BN/RPC;
  __shared__ unsigned short As[2*BM*BK];
  __shared__ unsigned short Bs[2*BN*BK];

  const int tid = threadIdx.x, wid = tid>>6, lane = tid&63;
  const int wy = wid>>1, wx = wid&1, ln16 = lane&15;

  // XCD-chunked bijective swizzle: consecutive hw ids round-robin XCDs;
  // remap so each XCD owns a contiguous chunk of (bx,by) space, by innermost.
  const int nwg = gridDim.x, cpx = nwg >> 3;
  const int lin = blockIdx.x;
  const int wg  = (lin & 7)*cpx + (lin >> 3);
  const int bxi = wg / nby, byi = wg % nby;

  int m0 = bxi*BM;
  const int n0 = byi*BN;

  float* Cf = nullptr; unsigned short* Ch = nullptr;
  const float* biasp = bias;
  const unsigned short* Bp = Bv;
  int seg = 0, cnt = M;

  if constexpr (MOE){
    int tv = btab[bxi];
    if (tv < 0) return;
    int e = tv>>8;
    m0 = (tv&255)*BM;
    seg = moff[e]; cnt = mcnt[e];
    Bp = Bv + (long)e*sBe;
    if constexpr (OUT_BF16) Ch = (unsigned short*)Cp; else Cf = (float*)Cp;
    if (biasp) biasp += (long)e*biasStride;
  } else {
    int z = blockIdx.z, zb = z/hdiv, zh = z%hdiv;
    A  += (long)zb*sAb + (long)zh*sAh;
    Bp += (long)zb*sBb + (long)zh*sBh;
    long coff = (long)zb*sCb + (long)zh*sCh;
    if constexpr (OUT_BF16) Ch = (unsigned short*)Cp + coff; else Cf = ((float*)Cp) + coff;
    if constexpr (ADD_IN) addin += coff;
  }

  // staging geometry: call j covers rows j*RPC + tid/8, col-unit (tid&7) of 8x16B.
  // SOURCE-side XOR swizzle (T2): unit ^= (row&7); LDS dest stays linear so
  // gl_lds is legal; reads undo the same involution.
  const int srow = tid >> 3;          // 8 lanes per row
  const int scol = ((tid & 7) ^ (srow & 7)) * 8;
  long ga[NA], gb[NB];
#pragma unroll
  for (int j=0; j<NA; j++){
    int r = m0 + j*RPC + srow;
    if constexpr (MOE){
      r = min(r, cnt-1);
      long gr = GATHER ? (long)rowtok[seg+r] : (long)(seg+r);
      ga[j] = gr*lda + scol;
    } else {
      ga[j] = (long)min(r, M-1)*lda + scol;
    }
  }
#pragma unroll
  for (int j=0; j<NB; j++){
    int bn = min(n0 + j*RPC + srow, N-1);
    gb[j] = (long)bn*ldb + scol;
  }

  f32x4 acc[FM][FNN];
#pragma unroll
  for(int i=0;i<FM;i++)
#pragma unroll
    for(int j=0;j<FNN;j++){ f32x4 z = {0.f,0.f,0.f,0.f}; acc[i][j] = z; }

  const int nt = K/BK;
  // read-side swizzle: row&7 == ln16&7 for all fragment rows (WM,WN mult of 8)
  const int rsw = ln16 & 7;
  const int u0 = ((lane>>4)     ^ rsw) * 8;   // kk=0 unit offset (elements)
  const int u1 = ((4+(lane>>4)) ^ rsw) * 8;   // kk=1 unit offset

  // prologue: stage tile 0 into buffer 0
#pragma unroll
  for (int j=0; j<NA; j++) gl_lds16(A + ga[j], As + j*2048 + wid*512);
#pragma unroll
  for (int j=0; j<NB; j++) gl_lds16(Bp + gb[j], Bs + j*2048 + wid*512);

  for (int t = 0; t < nt; ++t){
    const int cb = t & 1;
    const unsigned short* Ab = As + cb*BM*BK;
    const unsigned short* Bb = Bs + cb*BN*BK;
    unsigned short* An = As + (cb^1)*BM*BK;
    unsigned short* Bn = Bs + (cb^1)*BN*BK;
    const bool pf = (t+1 < nt);
    const long k0n = (long)(t+1)*BK;

    asm volatile("s_waitcnt vmcnt(0)" ::: "memory");  // this tile's loads (all waves will have drained theirs)
    __builtin_amdgcn_s_barrier();                     // tile t ready; prev-tile reads done by all waves
    __builtin_amdgcn_sched_barrier(0);                // no ds_read/gl_lds hoists above

    // ---- phase 0: stage A(t+1) | ds_read kk0 | MFMA kk0
    if (pf){
#pragma unroll
      for (int j=0; j<NA; j++) gl_lds16(A + ga[j] + k0n, An + j*2048 + wid*512);
    }
    {
      bf16x8 fa[FM], fb[FNN];
#pragma unroll
      for(int i=0;i<FM;i++) fa[i] = *(const bf16x8*)&Ab[(wy*WM + i*16 + ln16)*BK + u0];
#pragma unroll
      for(int j=0;j<FNN;j++) fb[j] = *(const bf16x8*)&Bb[(wx*WN + j*16 + ln16)*BK + u0];
      __builtin_amdgcn_s_setprio(1);
#pragma unroll
      for(int i=0;i<FM;i++)
#pragma unroll
        for(int j=0;j<FNN;j++)
          acc[i][j] = __builtin_amdgcn_mfma_f32_16x16x32_bf16(fa[i], fb[j], acc[i][j], 0, 0, 0);
      __builtin_amdgcn_s_setprio(0);
    }
    // ---- phase 1: stage B(t+1) | ds_read kk1 | MFMA kk1
    if (pf){
#pragma unroll
      for (int j=0; j<NB; j++) gl_lds16(Bp + gb[j] + k0n, Bn + j*2048 + wid*512);
    }
    {
      bf16x8 fa[FM], fb[FNN];
#pragma unroll
      for(int i=0;i<FM;i++) fa[i] = *(const bf16x8*)&Ab[(wy*WM + i*16 + ln16)*BK + u1];
#pragma unroll
      for(int j=0;j<FNN;j++) fb[j] = *(const bf16x8*)&Bb[(wx*WN + j*16 + ln16)*BK + u1];
      __builtin_amdgcn_s_setprio(1);
#pragma unroll
      for(int i=0;i<FM;i++)
#pragma unroll
        for(int j=0;j<FNN;j++)
          acc[i][j] = __builtin_amdgcn_mfma_f32_16x16x32_bf16(fa[i], fb[j], acc[i][j], 0, 0, 0);
      __builtin_amdgcn_s_setprio(0);
    }
  }

  // epilogue: C[m = quad*4+r][n = lane&15]
#pragma unroll
  for(int i=0;i<FM;i++){
    int mbase = m0 + wy*WM + i*16 + (lane>>4)*4;
#pragma unroll
    for(int j=0;j<FNN;j++){
      int n = n0 + wx*WN + j*16 + ln16;
      float bv = biasp ? biasp[n] : 0.f;
      f32x4 v = acc[i][j];
#pragma unroll
      for(int r=0;r<4;r++){
        int m = mbase + r;
        if (m < cnt){
          float x = v[r]*scale + bv;
          if constexpr (ACT == 1) x = 0.5f*x*(1.f + erff(x*0.70710678118654752f));
          long ci = (long)(MOE ? seg + m : m)*ldc + n;
          if constexpr (ADD_IN) x += addin[ci];
          if constexpr (OUT_BF16) Ch[ci] = f2bf(x);
          else Cf[ci] = x;
        }
      }
    }
  }
}

// ---------------------------------------------------------------------------
// Fused flash attention. grid (S/64, B*H). 4 waves, each owns 16 Q-rows.
// ---------------------------------------------------------------------------
__global__ __launch_bounds__(256)
void flash_k(const unsigned short* __restrict__ qkvb, const unsigned short* __restrict__ Vt,
             unsigned short* __restrict__ ctx)
{
  __shared__ unsigned short Pl[4][16*72];
  const int qt = blockIdx.x, z = blockIdx.y, b = z>>3, h = z&7;
  const int wid = threadIdx.x>>6, lane = threadIdx.x&63;
  const int ln16 = lane&15, g = lane>>4;
  const int q0 = qt*64 + wid*16;
  unsigned short* Pw = &Pl[wid][0];

  const unsigned short* Qp = qkvb + (long)(b*1024 + q0 + ln16)*1536 + h*64 + g*8;
  bf16x8 qf0 = *(const bf16x8*)Qp;
  bf16x8 qf1 = *(const bf16x8*)(Qp + 32);
  const unsigned short* Kbase = qkvb + (long)b*1024*1536 + 512 + h*64 + g*8;
  const unsigned short* Vbase = Vt + (long)z*65536 + g*8;

  float m_s[4], l_s[4];
  f32x4 oacc[4];
#pragma unroll
  for(int r=0;r<4;r++){ m_s[r] = -1e30f; l_s[r] = 0.f; }
#pragma unroll
  for(int j=0;j<4;j++){ f32x4 zz = {0.f,0.f,0.f,0.f}; oacc[j] = zz; }

  for (int t = 0; t < 16; ++t){
    bf16x8 kf[4][2], vf[4][2];
#pragma unroll
    for(int j=0;j<4;j++){
      const unsigned short* kp = Kbase + (long)(t*64 + j*16 + ln16)*1536;
      kf[j][0] = *(const bf16x8*)kp;
      kf[j][1] = *(const bf16x8*)(kp + 32);
      const unsigned short* vp = Vbase + (long)(j*16 + ln16)*1024 + t*64;
      vf[j][0] = *(const bf16x8*)vp;
      vf[j][1] = *(const bf16x8*)(vp + 32);
    }
    f32x4 sacc[4];
#pragma unroll
    for(int j=0;j<4;j++){ f32x4 zz = {0.f,0.f,0.f,0.f}; sacc[j] = zz; }
#pragma unroll
    for(int j=0;j<4;j++){
      sacc[j] = __builtin_amdgcn_mfma_f32_16x16x32_bf16(qf0, kf[j][0], sacc[j], 0,0,0);
      sacc[j] = __builtin_amdgcn_mfma_f32_16x16x32_bf16(qf1, kf[j][1], sacc[j], 0,0,0);
    }
#pragma unroll
    for(int j=0;j<4;j++)
#pragma unroll
      for(int r=0;r<4;r++) sacc[j][r] *= 0.125f;
    float alpha[4];
#pragma unroll
    for(int r=0;r<4;r++){
      float mx = fmaxf(fmaxf(sacc[0][r], sacc[1][r]), fmaxf(sacc[2][r], sacc[3][r]));
#pragma unroll
      for(int m=1;m<16;m<<=1) mx = fmaxf(mx, __shfl_xor(mx, m, 64));
      float mn = fmaxf(m_s[r], mx);
      alpha[r] = __expf(m_s[r] - mn);
      m_s[r] = mn;
    }
#pragma unroll
    for(int j=0;j<4;j++)
#pragma unroll
      for(int r=0;r<4;r++) sacc[j][r] = __expf(sacc[j][r] - m_s[r]);
#pragma unroll
    for(int r=0;r<4;r++){
      float rs = sacc[0][r]+sacc[1][r]+sacc[2][r]+sacc[3][r];
#pragma unroll
      for(int m=1;m<16;m<<=1) rs += __shfl_xor(rs, m, 64);
      l_s[r] = l_s[r]*alpha[r] + rs;
    }
#pragma unroll
    for(int j=0;j<4;j++)
#pragma unroll
      for(int r=0;r<4;r++) oacc[j][r] *= alpha[r];
#pragma unroll
    for(int j=0;j<4;j++)
#pragma unroll
      for(int r=0;r<4;r++)
        Pw[(g*4+r)*72 + j*16 + ln16] = f2bf(sacc[j][r]);
    bf16x8 pf0 = *(const bf16x8*)&Pw[ln16*72 + g*8];
    bf16x8 pf1 = *(const bf16x8*)&Pw[ln16*72 + 32 + g*8];
#pragma unroll
    for(int j=0;j<4;j++){
      oacc[j] = __builtin_amdgcn_mfma_f32_16x16x32_bf16(pf0, vf[j][0], oacc[j], 0,0,0);
      oacc[j] = __builtin_amdgcn_mfma_f32_16x16x32_bf16(pf1, vf[j][1], oacc[j], 0,0,0);
    }
  }
#pragma unroll
  for(int r=0;r<4;r++){
    float inv = 1.f/l_s[r];
    long row = (long)(b*1024 + q0 + g*4 + r)*512 + h*64;
#pragma unroll
    for(int j=0;j<4;j++)
      ctx[row + j*16 + ln16] = f2bf(oacc[j][r]*inv);
  }
}

// ---------------------------------------------------------------------------
// Wave-per-row LayerNorm (D=512): 4 rows/block, no barriers.
// ---------------------------------------------------------------------------
template<bool OUT_BF16>
__global__ __launch_bounds__(256)
void ln_w_k(const float* __restrict__ in, const float* __restrict__ w,
            const float* __restrict__ bb, void* __restrict__ outp)
{
  int row = blockIdx.x*4 + (threadIdx.x>>6), lane = threadIdx.x&63;
  const float4* p = (const float4*)(in + (long)row*512 + lane*8);
  float4 a = p[0], c = p[1];
  float s = a.x+a.y+a.z+a.w + c.x+c.y+c.z+c.w;
  float q = a.x*a.x+a.y*a.y+a.z*a.z+a.w*a.w + c.x*c.x+c.y*c.y+c.z*c.z+c.w*c.w;
  s = wred_sum(s); q = wred_sum(q);
  float mean = s*(1.f/512.f);
  float var  = q*(1.f/512.f) - mean*mean;
  float inv  = rsqrtf(var + 1e-5f);
  const float4* wp = (const float4*)(w + lane*8);
  const float4* bp = (const float4*)(bb + lane*8);
  float4 w0 = wp[0], w1 = wp[1], b0 = bp[0], b1 = bp[1];
  float o0 = (a.x-mean)*inv*w0.x + b0.x, o1 = (a.y-mean)*inv*w0.y + b0.y;
  float o2 = (a.z-mean)*inv*w0.z + b0.z, o3 = (a.w-mean)*inv*w0.w + b0.w;
  float o4 = (c.x-mean)*inv*w1.x + b1.x, o5 = (c.y-mean)*inv*w1.y + b1.y;
  float o6 = (c.z-mean)*inv*w1.z + b1.z, o7 = (c.w-mean)*inv*w1.w + b1.w;
  if constexpr (OUT_BF16){
    *(uint4*)((unsigned short*)outp + (long)row*512 + lane*8) =
      make_uint4(pk2(o0,o1), pk2(o2,o3), pk2(o4,o5), pk2(o6,o7));
  } else {
    float4* op = (float4*)((float*)outp + (long)row*512 + lane*8);
    op[0] = make_float4(o0,o1,o2,o3);
    op[1] = make_float4(o4,o5,o6,o7);
  }
}

// LN2 + router fused: h2 = LN(x) (bf16 out) then top-2 gate; NO global atomics.
__global__ __launch_bounds__(256)
void ln2route_k(const float* __restrict__ in, const float* __restrict__ w,
                const float* __restrict__ bb, unsigned short* __restrict__ h2,
                const float* __restrict__ gw,
                int* __restrict__ tok_e, float* __restrict__ tok_w)
{
  int tok = blockIdx.x*4 + (threadIdx.x>>6), lane = threadIdx.x&63;
  const float4* p = (const float4*)(in + (long)tok*512 + lane*8);
  float4 a = p[0], c = p[1];
  float s = a.x+a.y+a.z+a.w + c.x+c.y+c.z+c.w;
  float q = a.x*a.x+a.y*a.y+a.z*a.z+a.w*a.w + c.x*c.x+c.y*c.y+c.z*c.z+c.w*c.w;
  s = wred_sum(s); q = wred_sum(q);
  float mean = s*(1.f/512.f);
  float var  = q*(1.f/512.f) - mean*mean;
  float inv  = rsqrtf(var + 1e-5f);
  const float4* wp = (const float4*)(w + lane*8);
  const float4* bp = (const float4*)(bb + lane*8);
  float4 w0 = wp[0], w1 = wp[1], b0 = bp[0], b1 = bp[1];
  float o[8];
  o[0] = (a.x-mean)*inv*w0.x + b0.x; o[1] = (a.y-mean)*inv*w0.y + b0.y;
  o[2] = (a.z-mean)*inv*w0.z + b0.z; o[3] = (a.w-mean)*inv*w0.w + b0.w;
  o[4] = (c.x-mean)*inv*w1.x + b1.x; o[5] = (c.y-mean)*inv*w1.y + b1.y;
  o[6] = (c.z-mean)*inv*w1.z + b1.z; o[7] = (c.w-mean)*inv*w1.w + b1.w;
  *(uint4*)(h2 + (long)tok*512 + lane*8) =
    make_uint4(pk2(o[0],o[1]), pk2(o[2],o[3]), pk2(o[4],o[5]), pk2(o[6],o[7]));
  float lg[8];
#pragma unroll
  for(int e=0;e<8;e++){
    const float4* gr = (const float4*)(gw + e*512 + lane*8);
    float4 g0 = gr[0], g1 = gr[1];
    float d = o[0]*g0.x + o[1]*g0.y + o[2]*g0.z + o[3]*g0.w
            + o[4]*g1.x + o[5]*g1.y + o[6]*g1.z + o[7]*g1.w;
    lg[e] = wred_sum(d);
  }
  if (lane == 0){
    float mx = lg[0];
#pragma unroll
    for(int e=1;e<8;e++) mx = fmaxf(mx, lg[e]);
    float pr[8];
#pragma unroll
    for(int e=0;e<8;e++) pr[e] = expf(lg[e]-mx);
    int e0 = 0; float p0 = pr[0];
#pragma unroll
    for(int e=1;e<8;e++) if (pr[e] > p0){ p0 = pr[e]; e0 = e; }
    int e1 = -1; float p1 = -1.f;
#pragma unroll
    for(int e=0;e<8;e++) if (e != e0 && pr[e] > p1){ p1 = pr[e]; e1 = e; }
    float invp = 1.f/(p0+p1);
    tok_e[2*tok] = e0; tok_e[2*tok+1] = e1;
    tok_w[2*tok] = p0*invp; tok_w[2*tok+1] = p1*invp;
  }
}

// ---------------------------------------------------------------------------
// Single-block planner + scatter: LDS-atomic histogram, offsets, two block
// tables (BM=128 for FFN1, BM=64 for FFN2), aux, and compaction scatter.
// ---------------------------------------------------------------------------
__global__ __launch_bounds__(1024)
void plan_scatter_k(const int* __restrict__ tok_e, const float* __restrict__ tok_w,
                    int* __restrict__ offs, int* __restrict__ cnts, float* __restrict__ aux,
                    int* __restrict__ btab, int* __restrict__ btab64,
                    int* __restrict__ rowtok, float* __restrict__ roww, int* __restrict__ rowof)
{
  __shared__ int hist[8];
  __shared__ int offsS[8];
  __shared__ int base[8];
  const int t = threadIdx.x;
  if (t < 8) hist[t] = 0;
  __syncthreads();
  int e[8]; float w[8];
#pragma unroll
  for (int i=0;i<8;i++){
    e[i] = tok_e[t + i*1024];
    w[i] = tok_w[t + i*1024];
    atomicAdd(&hist[e[i]], 1);
  }
  __syncthreads();
  if (t == 0){
    int o = 0, idx = 0, idx2 = 0; float a = 0.f;
    for (int ee=0; ee<8; ee++){
      offsS[ee] = o;
      int c = hist[ee];
      o += c;
      float u = (float)c*(1.f/4096.f) - 0.125f;
      a += u*u;
      int nb = (c + 127) >> 7;
      for (int j=0;j<nb;j++) btab[idx++] = (ee<<8)|j;
      int nb2 = (c + 63) >> 6;
      for (int j=0;j<nb2;j++) btab64[idx2++] = (ee<<8)|j;
    }
    while (idx < 80) btab[idx++] = -1;
    while (idx2 < 144) btab64[idx2++] = -1;
    *aux += a*(1.f/8.f);
  }
  __syncthreads();
  if (t < 8){
    cnts[t] = hist[t];
    offs[t] = offsS[t];
    base[t] = offsS[t];
  }
  __syncthreads();
#pragma unroll
  for (int i=0;i<8;i++){
    int pos = atomicAdd(&base[e[i]], 1);   // LDS atomic
    int gi = t + i*1024;
    rowtok[pos] = gi>>1;
    roww[pos] = w[i];
    rowof[gi] = pos;
  }
}

// Fused MoE combine + LN, wave per token
__global__ __launch_bounds__(256)
void ln_moe_k(const float* __restrict__ eout, const int* __restrict__ rowof,
              const float* __restrict__ roww, const float* __restrict__ mask,
              const unsigned short* __restrict__ h2,
              const float* __restrict__ w, const float* __restrict__ bb,
              float* __restrict__ outp)
{
  int tok = blockIdx.x*4 + (threadIdx.x>>6), lane = threadIdx.x&63;
  int r0 = rowof[2*tok], r1 = rowof[2*tok+1];
  float w0w = roww[r0], w1w = roww[r1], mk = mask[tok];
  const float4* ap = (const float4*)(eout + (long)r0*512 + lane*8);
  const float4* bp2 = (const float4*)(eout + (long)r1*512 + lane*8);
  float4 a0 = ap[0], a1 = ap[1], c0 = bp2[0], c1 = bp2[1];
  uint4 hu = *(const uint4*)(h2 + (long)tok*512 + lane*8);
  const unsigned short* hh = (const unsigned short*)&hu;
  float v[8];
  v[0] = bf2f(hh[0]) + (a0.x*w0w + c0.x*w1w)*mk;
  v[1] = bf2f(hh[1]) + (a0.y*w0w + c0.y*w1w)*mk;
  v[2] = bf2f(hh[2]) + (a0.z*w0w + c0.z*w1w)*mk;
  v[3] = bf2f(hh[3]) + (a0.w*w0w + c0.w*w1w)*mk;
  v[4] = bf2f(hh[4]) + (a1.x*w0w + c1.x*w1w)*mk;
  v[5] = bf2f(hh[5]) + (a1.y*w0w + c1.y*w1w)*mk;
  v[6] = bf2f(hh[6]) + (a1.z*w0w + c1.z*w1w)*mk;
  v[7] = bf2f(hh[7]) + (a1.w*w0w + c1.w*w1w)*mk;
  float s = 0.f, q = 0.f;
#pragma unroll
  for(int i=0;i<8;i++){ s += v[i]; q += v[i]*v[i]; }
  s = wred_sum(s); q = wred_sum(q);
  float mean = s*(1.f/512.f);
  float var  = q*(1.f/512.f) - mean*mean;
  float inv  = rsqrtf(var + 1e-5f);
  const float4* wp = (const float4*)(w + lane*8);
  const float4* bpp = (const float4*)(bb + lane*8);
  float4 w0 = wp[0], w1 = wp[1], b0 = bpp[0], b1 = bpp[1];
  float wv[8] = {w0.x,w0.y,w0.z,w0.w,w1.x,w1.y,w1.z,w1.w};
  float bv[8] = {b0.x,b0.y,b0.z,b0.w,b1.x,b1.y,b1.z,b1.w};
  float4* op = (float4*)(outp + (long)tok*512 + lane*8);
  op[0] = make_float4((v[0]-mean)*inv*wv[0]+bv[0], (v[1]-mean)*inv*wv[1]+bv[1],
                      (v[2]-mean)*inv*wv[2]+bv[2], (v[3]-mean)*inv*wv[3]+bv[3]);
  op[1] = make_float4((v[4]-mean)*inv*wv[4]+bv[4], (v[5]-mean)*inv*wv[5]+bv[5],
                      (v[6]-mean)*inv*wv[6]+bv[6], (v[7]-mean)*inv*wv[7]+bv[7]);
}

// Build Vt[bh][d][k] bf16 from qkv V slice; grid (4,32), 4 chunks per block
__global__ __launch_bounds__(256)
void vt_k(const unsigned short* __restrict__ qkvb, unsigned short* __restrict__ Vt)
{
  __shared__ unsigned short tile[64][80];
  int z = blockIdx.y, b = z>>3, h = z&7;
  int t = threadIdx.x;
  int kk = t>>2, dd = (t&3)*16;
  int dd2 = t>>2, kk2 = (t&3)*16;
  for (int c = 0; c < 4; ++c){
    int k0 = (blockIdx.x*4 + c)*64;
    const unsigned short* p = qkvb + ((long)(b*1024 + k0 + kk))*1536 + 1024 + h*64 + dd;
    uint4 u0 = *(const uint4*)p, u1 = *(const uint4*)(p+8);
    __syncthreads();
    *(uint4*)&tile[kk][dd] = u0;
    *(uint4*)&tile[kk][dd+8] = u1;
    __syncthreads();
    uint4 o0, o1;
    unsigned short* s0 = (unsigned short*)&o0;
    unsigned short* s1 = (unsigned short*)&o1;
#pragma unroll
    for(int j=0;j<8;j++){ s0[j] = tile[kk2+j][dd2]; s1[j] = tile[kk2+8+j][dd2]; }
    unsigned short* o = Vt + (long)z*65536 + (long)dd2*1024 + k0 + kk2;
    *(uint4*)o = o0; *(uint4*)(o+8) = o1;
  }
}

// fp32 (R,C) -> bf16 (C,R), z-loop of ZL
__global__ __launch_bounds__(256)
void transpose_cast_k(const float* __restrict__ in, unsigned short* __restrict__ outp,
                      int R, int C, int ZL)
{
  __shared__ float tile[64][65];
  int t = threadIdx.x;
  int rr = t>>2, cc = (t&3)*16;
  int cc2 = t>>2, rr2 = (t&3)*16;
  int c0 = blockIdx.x*64, r0 = blockIdx.y*64;
  for (int zi = 0; zi < ZL; ++zi){
    long zoff = (long)(blockIdx.z*ZL + zi) * R * C;
    const float* pin = in + zoff + (long)(r0+rr)*C + c0 + cc;
    float4 v0=*(const float4*)pin, v1=*(const float4*)(pin+4), v2=*(const float4*)(pin+8), v3=*(const float4*)(pin+12);
    __syncthreads();
    tile[rr][cc+0]=v0.x; tile[rr][cc+1]=v0.y; tile[rr][cc+2]=v0.z; tile[rr][cc+3]=v0.w;
    tile[rr][cc+4]=v1.x; tile[rr][cc+5]=v1.y; tile[rr][cc+6]=v1.z; tile[rr][cc+7]=v1.w;
    tile[rr][cc+8]=v2.x; tile[rr][cc+9]=v2.y; tile[rr][cc+10]=v2.z; tile[rr][cc+11]=v2.w;
    tile[rr][cc+12]=v3.x; tile[rr][cc+13]=v3.y; tile[rr][cc+14]=v3.z; tile[rr][cc+15]=v3.w;
    __syncthreads();
    unsigned tmp[8];
#pragma unroll
    for(int jj=0;jj<8;jj++)
      tmp[jj] = pk2(tile[rr2+2*jj][cc2], tile[rr2+2*jj+1][cc2]);
    uint4* dst = (uint4*)(outp + zoff + (long)(c0+cc2)*R + r0 + rr2);
    dst[0] = make_uint4(tmp[0],tmp[1],tmp[2],tmp[3]);
    dst[1] = make_uint4(tmp[4],tmp[5],tmp[6],tmp[7]);
  }
}

// fp32 -> bf16, grid-stride
__global__ __launch_bounds__(256)
void cast_bf16_k(const float* __restrict__ in, unsigned short* __restrict__ outp, int n8)
{
  for (int i = blockIdx.x*256 + threadIdx.x; i < n8; i += gridDim.x*256){
    const float4* p = (const float4*)(in + (long)i*8);
    float4 a = p[0], b = p[1];
    *(uint4*)(outp + (long)i*8) = make_uint4(pk2(a.x,a.y), pk2(a.z,a.w), pk2(b.x,b.y), pk2(b.z,b.w));
  }
}

// masked-sum partial pooling, NO atomics: grid (4,8) -> 8 partials per batch
__global__ __launch_bounds__(256)
void pool2_k(const float* __restrict__ h, const float* __restrict__ mask, float* __restrict__ pooled)
{
  int b = blockIdx.x, sc = blockIdx.y, t = threadIdx.x;
  float a0 = 0.f, a1 = 0.f;
  const float* mb = mask + b*1024 + sc*128;
  const float* hbase = h + ((long)b*1024 + sc*128)*512;
  for (int s = 0; s < 128; ++s){
    float mk = mb[s];
    const float* r = hbase + (long)s*512;
    a0 += r[t]*mk; a1 += r[t+256]*mk;
  }
  pooled[((b*8 + sc)*512) + t] = a0;
  pooled[((b*8 + sc)*512) + t + 256] = a1;
}

__global__ __launch_bounds__(256)
void head_final_k(const float* __restrict__ pooled, const float* __restrict__ mask,
                  const float* __restrict__ pool_w, const float* __restrict__ pool_b,
                  const float* __restrict__ cls_w, const float* __restrict__ cls_b,
                  const float* __restrict__ cf_w1, const float* __restrict__ cf_b1,
                  const float* __restrict__ cf_w2, const float* __restrict__ cf_b2,
                  const float* __restrict__ aux, float* __restrict__ out)
{
  int b = blockIdx.x, t = threadIdx.x, wid = t>>6, lane = t&63;
  __shared__ __align__(16) float pld[512];
  __shared__ __align__(16) float p2[512];
  __shared__ float red[4];
  float ds = 0.f;
  for(int s=t; s<1024; s+=256) ds += mask[b*1024 + s];
  ds = wred_sum(ds);
  if (lane==0) red[wid] = ds;
  __syncthreads();
  float denom = fmaxf(red[0]+red[1]+red[2]+red[3], 1e-9f);
  float s0 = 0.f, s1 = 0.f;
#pragma unroll
  for(int sc=0;sc<8;sc++){
    s0 += pooled[((b*8+sc)*512) + t];
    s1 += pooled[((b*8+sc)*512) + t + 256];
  }
  pld[t]     = s0/denom;
  pld[t+256] = s1/denom;
  __syncthreads();
#pragma unroll
  for(int jj=0;jj<2;jj++){
    int j = t + jj*256;
    const float4* wr = (const float4*)(pool_w + (long)j*512);
    float acc = 0.f;
    for(int i=0;i<128;i++){
      float4 w4 = wr[i]; float4 x4 = ((const float4*)pld)[i];
      acc += w4.x*x4.x + w4.y*x4.y + w4.z*x4.z + w4.w*x4.w;
    }
    p2[j] = tanhf(acc + pool_b[j]);
  }
  __syncthreads();
  if (t < 4){
    const float4* wr = (const float4*)(cls_w + (long)t*512);
    float acc = 0.f;
    for(int i=0;i<128;i++){
      float4 w4 = wr[i]; float4 x4 = ((const float4*)p2)[i];
      acc += w4.x*x4.x + w4.y*x4.y + w4.z*x4.z + w4.w*x4.w;
    }
    out[b*4 + t] = acc + cls_b[t];
  }
  {
    const float4* wr = (const float4*)(cf_w1 + (long)t*512);
    float acc = 0.f;
    for(int i=0;i<128;i++){
      float4 w4 = wr[i]; float4 x4 = ((const float4*)p2)[i];
      acc += w4.x*x4.x + w4.y*x4.y + w4.z*x4.z + w4.w*x4.w;
    }
    acc = fmaxf(acc + cf_b1[t], 0.f) * cf_w2[t];
    acc = wred_sum(acc);
    __syncthreads();
    if (lane==0) red[wid] = acc;
    __syncthreads();
    if (t == 0){
      float sum = red[0]+red[1]+red[2]+red[3];
      out[17 + b] = 1.f/(1.f + expf(-(sum + cf_b2[0])));
    }
  }
  if (b == 0 && t == 0) out[16] = aux[0]*0.25f;
}

// ---------------------------------------------------------------------------
extern "C" void kernel_launch(void* const* d_in, const int* in_sizes, int n_in,
                              void* d_out, int out_size, void* d_ws, size_t ws_size,
                              hipStream_t stream)
{
  (void)in_sizes; (void)n_in; (void)out_size;
  const float* emb    = (const float*)d_in[0];
  const float* mask   = (const float*)d_in[1];
  const float* in_w   = (const float*)d_in[2];
  const float* in_b   = (const float*)d_in[3];
  const float* out_w  = (const float*)d_in[4];
  const float* out_b  = (const float*)d_in[5];
  const float* ln1_w  = (const float*)d_in[6];
  const float* ln1_b  = (const float*)d_in[7];
  const float* ln2_w  = (const float*)d_in[8];
  const float* ln2_b  = (const float*)d_in[9];
  const float* gate_w = (const float*)d_in[10];
  const float* e_w1   = (const float*)d_in[11];
  const float* e_b1   = (const float*)d_in[12];
  const float* e_w2   = (const float*)d_in[13];
  const float* e_b2   = (const float*)d_in[14];
  const float* mln_w  = (const float*)d_in[15];
  const float* mln_b  = (const float*)d_in[16];
  const float* fln_w  = (const float*)d_in[17];
  const float* fln_b  = (const float*)d_in[18];
  const float* pool_w = (const float*)d_in[19];
  const float* pool_b = (const float*)d_in[20];
  const float* cls_w  = (const float*)d_in[21];
  const float* cls_b  = (const float*)d_in[22];
  const float* cf_w1  = (const float*)d_in[23];
  const float* cf_b1  = (const float*)d_in[24];
  const float* cf_w2  = (const float*)d_in[25];
  const float* cf_b2  = (const float*)d_in[26];
  float* out = (float*)d_out;
  char* ws = (char*)d_ws;

  const size_t MiB = 1024*1024;
  if (ws_size < 218*MiB) return;

  // Workspace layout
  float*          x     = (float*)(ws + 0*MiB);             // 8 MiB fp32
  unsigned short* hb    = (unsigned short*)(ws + 8*MiB);    // 4 MiB bf16
  unsigned short* qkvb  = (unsigned short*)(ws + 12*MiB);   // 12 MiB bf16
  unsigned short* ctx   = (unsigned short*)(ws + 24*MiB);   // 4 MiB bf16
  unsigned short* Vt    = (unsigned short*)(ws + 28*MiB);   // 4 MiB bf16
  unsigned short* mid   = (unsigned short*)(ws + 32*MiB);   // 32 MiB bf16
  float*          eout  = (float*)(ws + 64*MiB);            // 16 MiB fp32
  float*          fout  = (float*)(ws + 64*MiB);            //   (reuse, head)
  unsigned short* w1t   = (unsigned short*)(ws + 80*MiB);   // 64 MiB bf16
  unsigned short* w2t   = (unsigned short*)(ws + 144*MiB);  // 64 MiB bf16
  unsigned short* inwb  = (unsigned short*)(ws + 208*MiB);  // 6 MiB bf16
  unsigned short* outwb = (unsigned short*)(ws + 214*MiB);  // 2 MiB bf16
  char* misc = ws + 216*MiB;
  int*   counts  = (int*)(misc + 0);
  int*   offs    = (int*)(misc + 64);
  float* aux     = (float*)(misc + 128);
  int*   btab    = (int*)(misc + 256);       // 80 ints
  int*   btab64  = (int*)(misc + 1024);      // 144 ints
  float* pooled  = (float*)(misc + 4096);    // 64 KiB
  int*   tok_e   = (int*)(misc + 81920);
  float* tok_w   = (float*)(misc + 114688);
  int*   rowtok  = (int*)(misc + 147456);
  float* roww    = (float*)(misc + 180224);
  int*   rowof   = (int*)(misc + 212992);

  hipMemcpyAsync(x, emb, (size_t)T_*D_*4, hipMemcpyDeviceToDevice, stream);
  hipMemsetAsync(aux, 0, 4, stream);
  // weight prep
  cast_bf16_k<<<512, 256, 0, stream>>>(in_w, inwb, L_*3*D_*D_/8);
  cast_bf16_k<<<256, 256, 0, stream>>>(out_w, outwb, L_*D_*D_/8);
  transpose_cast_k<<<dim3(I_/64, D_/64, 4), 256, 0, stream>>>(e_w1, w1t, D_, I_, 8);
  transpose_cast_k<<<dim3(D_/64, I_/64, 4), 256, 0, stream>>>(e_w2, w2t, I_, D_, 8);

  for (int l=0; l<L_; l++){
    const float* inbl  = in_b  + (size_t)l*3*D_;
    const float* outbl = out_b + (size_t)l*D_;
    const float* gwl   = gate_w + (size_t)l*E_*D_;
    const float* eb1l  = e_b1 + (size_t)l*E_*I_;
    const float* eb2l  = e_b2 + (size_t)l*E_*D_;
    const unsigned short* inwbl  = inwb + (size_t)l*3*D_*D_;
    const unsigned short* outwbl = outwb + (size_t)l*D_*D_;
    const unsigned short* w1tl = w1t + (size_t)l*E_*I_*D_;
    const unsigned short* w2tl = w2t + (size_t)l*E_*D_*I_;

    // h = LN1(x) -> bf16
    ln_w_k<true><<<T_/4, 256, 0, stream>>>(x, ln1_w + (size_t)l*D_, ln1_b + (size_t)l*D_, hb);
    // qkv = h @ in_w^T + in_b -> bf16   (64x128: 768 blocks, nby=12)
    gemm_k<64,128,false,false,true,0,false><<<dim3(768,1,1), 256, 0, stream>>>(
      hb, inwbl, qkvb, inbl, nullptr, T_, 3*D_, D_, D_, D_, 3*D_,
      1, 0,0,0,0,0,0, 1.f, nullptr, nullptr, nullptr, nullptr, 0, 0, 12);
    vt_k<<<dim3(4,32), 256, 0, stream>>>(qkvb, Vt);
    // fused attention -> ctx (B,S,512) bf16
    flash_k<<<dim3(16,32), 256, 0, stream>>>(qkvb, Vt, ctx);
    // x = x + ctx @ out_w^T + out_b  (fp32)   (64x64: 512 blocks, nby=8)
    gemm_k<64,64,false,false,false,0,true><<<dim3(512,1,1), 256, 0, stream>>>(
      ctx, outwbl, x, outbl, x, T_, D_, D_, D_, D_, D_,
      1, 0,0,0,0,0,0, 1.f, nullptr, nullptr, nullptr, nullptr, 0, 0, 8);
    // h2 = LN2(x) -> bf16, + routing (no atomics)
    ln2route_k<<<T_/4, 256, 0, stream>>>(x, ln2_w + (size_t)l*D_, ln2_b + (size_t)l*D_,
                                         hb, gwl, tok_e, tok_w);
    // plan + scatter, single block, LDS atomics only
    plan_scatter_k<<<1, 1024, 0, stream>>>(tok_e, tok_w, offs, counts, aux, btab, btab64,
                                           rowtok, roww, rowof);
    // FFN1: mid = gelu(gather(h2) @ w1^T + b1) -> bf16   (BM=128, 1136 blocks, nby=16)
    gemm_k<128,128,true,true,true,1,false><<<dim3(1136,1,1), 256, 0, stream>>>(
      hb, w1tl, mid, eb1l, nullptr, 2*T_, I_, D_, D_, D_, I_,
      1, 0,0,0,0,0,0, 1.f, offs, counts, rowtok, btab, (long)I_*D_, I_, 16);
    // FFN2: eout = mid @ w2^T + b2 -> fp32   (BM=64, 544 blocks, nby=4)
    gemm_k<64,128,true,false,false,0,false><<<dim3(544,1,1), 256, 0, stream>>>(
      mid, w2tl, eout, eb2l, nullptr, 2*T_, D_, I_, I_, I_, D_,
      1, 0,0,0,0,0,0, 1.f, offs, counts, nullptr, btab64, (long)D_*I_, D_, 4);
    // x = LN(h2 + combine(eout))
    ln_moe_k<<<T_/4, 256, 0, stream>>>(eout, rowof, roww, mask, hb,
                                       mln_w + (size_t)l*D_, mln_b + (size_t)l*D_, x);
  }
  // head
  ln_w_k<false><<<T_/4, 256, 0, stream>>>(x, fln_w, fln_b, fout);
  pool2_k<<<dim3(4,8), 256, 0, stream>>>(fout, mask, pooled);
  head_final_k<<<4, 256, 0, stream>>>(pooled, mask, pool_w, pool_b, cls_w, cls_b,
                                      cf_w1, cf_b1, cf_w2, cf_b2, aux, out);
}

// Round 5
// 1326.462 us; speedup vs baseline: 1.1330x; 1.0978x over previous
//
#include <hip/hip_runtime.h>
#include <math.h>

// Problem constants
#define B_ 4
#define S_ 1024
#define D_ 512
#define H_ 8
#define DH_ 64
#define I_ 2048
#define E_ 8
#define L_ 4
#define T_ 4096   // B*S

using bf16x8 = __attribute__((ext_vector_type(8))) __bf16;
using f32x4  = __attribute__((ext_vector_type(4))) float;

typedef __attribute__((address_space(1))) const void gvoid;
typedef __attribute__((address_space(3))) void lvoid;
__device__ __forceinline__ void gl_lds16(const void* g, void* l){
  __builtin_amdgcn_global_load_lds((gvoid*)g, (lvoid*)l, 16, 0, 0);
}

__device__ __forceinline__ float wred_sum(float v){
#pragma unroll
  for(int m=32;m>0;m>>=1) v += __shfl_xor(v, m, 64);
  return v;
}
__device__ __forceinline__ unsigned short f2bf(float f){
  unsigned x = __float_as_uint(f);
  unsigned r = (x + 0x7FFFu + ((x>>16)&1u)) >> 16;
  return (unsigned short)r;
}
__device__ __forceinline__ float bf2f(unsigned short u){
  return __uint_as_float(((unsigned)u)<<16);
}
__device__ __forceinline__ unsigned pk2(float a, float b){
  return (unsigned)f2bf(a) | ((unsigned)f2bf(b)<<16);
}

// ---------------------------------------------------------------------------
// bf16 MFMA GEMM. NT: C[m,n] = sum_k A[m,k]*B[n,k].
// 512 threads = 8 waves in 2x4 (wy=wid>>2, wx=wid&3): per-wave tile WM=BM/2,
// WN=BN/4 -> half the per-wave work of the 4-wave layout, 2x the waves/CU
// (occupancy was the Round-4 limiter: 15% occ, >70% stall, MfmaUtil 8.6%).
// BK=64, double-buffered LDS, phase-interleaved schedule:
//   per K-step: [vmcnt(0); s_barrier] then
//     phase0: issue stage A(t+1) | ds_read kk0 | setprio(1) MFMA kk0
//     phase1: issue stage B(t+1) | ds_read kk1 | setprio(1) MFMA kk1
// ONE barrier per K-step (top barrier protects both buffers).
// T2 bank-conflict fix (both-sides, verified 6.78M->0): LDS dest linear,
// global SOURCE col unit ^= (row&7); fragment reads XOR the same involution.
// 1-D grid with XCD-chunked bijective swizzle (gridDim.x % 8 == 0).
// MOE: block table btab[bx] = (e<<8)|mblk, -1 = dead. Optional row gather.
// ---------------------------------------------------------------------------
template<int BM, int BN, bool MOE, bool GATHER, bool OUT_BF16, int ACT, bool ADD_IN>
__global__ __launch_bounds__(512)
void gemm_k(const unsigned short* __restrict__ A, const unsigned short* __restrict__ Bv,
            void* Cp, const float* __restrict__ bias, const float* addin,
            int M, int N, int K, int lda, int ldb, int ldc,
            int hdiv, long sAb, long sAh, long sBb, long sBh, long sCb, long sCh,
            float scale,
            const int* __restrict__ moff, const int* __restrict__ mcnt,
            const int* __restrict__ rowtok, const int* __restrict__ btab,
            long sBe, int biasStride, int nby)
{
  constexpr int BK = 64;
  constexpr int WM = BM/2, WN = BN/4, FM = WM/16, FNN = WN/16;
  constexpr int RPC = 64;            // rows covered per block-wide gl_lds16 call (512 thr / 8 per row)
  constexpr int SHPC = 4096;         // shorts per call (512 thr * 8)
  constexpr int NA = BM/RPC, NB = BN/RPC;
  __shared__ unsigned short As[2*BM*BK];
  __shared__ unsigned short Bs[2*BN*BK];

  const int tid = threadIdx.x, wid = tid>>6, lane = tid&63;
  const int wy = wid>>2, wx = wid&3, ln16 = lane&15;

  // XCD-chunked bijective swizzle: consecutive hw ids round-robin XCDs;
  // remap so each XCD owns a contiguous chunk of (bx,by) space, by innermost.
  const int nwg = gridDim.x, cpx = nwg >> 3;
  const int lin = blockIdx.x;
  const int wg  = (lin & 7)*cpx + (lin >> 3);
  const int bxi = wg / nby, byi = wg % nby;

  int m0 = bxi*BM;
  const int n0 = byi*BN;

  float* Cf = nullptr; unsigned short* Ch = nullptr;
  const float* biasp = bias;
  const unsigned short* Bp = Bv;
  int seg = 0, cnt = M;

  if constexpr (MOE){
    int tv = btab[bxi];
    if (tv < 0) return;
    int e = tv>>8;
    m0 = (tv&255)*BM;
    seg = moff[e]; cnt = mcnt[e];
    Bp = Bv + (long)e*sBe;
    if constexpr (OUT_BF16) Ch = (unsigned short*)Cp; else Cf = (float*)Cp;
    if (biasp) biasp += (long)e*biasStride;
  } else {
    int z = blockIdx.z, zb = z/hdiv, zh = z%hdiv;
    A  += (long)zb*sAb + (long)zh*sAh;
    Bp += (long)zb*sBb + (long)zh*sBh;
    long coff = (long)zb*sCb + (long)zh*sCh;
    if constexpr (OUT_BF16) Ch = (unsigned short*)Cp + coff; else Cf = ((float*)Cp) + coff;
    if constexpr (ADD_IN) addin += coff;
  }

  // staging geometry: call j covers rows j*RPC + tid/8, col-unit (tid&7) of 8x16B.
  // SOURCE-side XOR swizzle (T2): unit ^= (row&7); LDS dest stays linear so
  // gl_lds is legal; reads undo the same involution.
  const int srow = tid >> 3;          // 8 lanes per row
  const int scol = ((tid & 7) ^ (srow & 7)) * 8;
  long ga[NA], gb[NB];
#pragma unroll
  for (int j=0; j<NA; j++){
    int r = m0 + j*RPC + srow;
    if constexpr (MOE){
      r = min(r, cnt-1);
      long gr = GATHER ? (long)rowtok[seg+r] : (long)(seg+r);
      ga[j] = gr*lda + scol;
    } else {
      ga[j] = (long)min(r, M-1)*lda + scol;
    }
  }
#pragma unroll
  for (int j=0; j<NB; j++){
    int bn = min(n0 + j*RPC + srow, N-1);
    gb[j] = (long)bn*ldb + scol;
  }

  f32x4 acc[FM][FNN];
#pragma unroll
  for(int i=0;i<FM;i++)
#pragma unroll
    for(int j=0;j<FNN;j++){ f32x4 z = {0.f,0.f,0.f,0.f}; acc[i][j] = z; }

  const int nt = K/BK;
  // read-side swizzle: row&7 == ln16&7 for all fragment rows (WM,WN mult of 8/16)
  const int rsw = ln16 & 7;
  const int u0 = ((lane>>4)     ^ rsw) * 8;   // kk=0 unit offset (elements)
  const int u1 = ((4+(lane>>4)) ^ rsw) * 8;   // kk=1 unit offset

  // prologue: stage tile 0 into buffer 0
#pragma unroll
  for (int j=0; j<NA; j++) gl_lds16(A + ga[j], As + j*SHPC + wid*512);
#pragma unroll
  for (int j=0; j<NB; j++) gl_lds16(Bp + gb[j], Bs + j*SHPC + wid*512);

  for (int t = 0; t < nt; ++t){
    const int cb = t & 1;
    const unsigned short* Ab = As + cb*BM*BK;
    const unsigned short* Bb = Bs + cb*BN*BK;
    unsigned short* An = As + (cb^1)*BM*BK;
    unsigned short* Bn = Bs + (cb^1)*BN*BK;
    const bool pf = (t+1 < nt);
    const long k0n = (long)(t+1)*BK;

    asm volatile("s_waitcnt vmcnt(0)" ::: "memory");  // this tile's loads landed
    __builtin_amdgcn_s_barrier();                     // tile t ready; prev-tile reads done by all waves
    __builtin_amdgcn_sched_barrier(0);                // no ds_read/gl_lds hoists above

    // ---- phase 0: stage A(t+1) | ds_read kk0 | MFMA kk0
    if (pf){
#pragma unroll
      for (int j=0; j<NA; j++) gl_lds16(A + ga[j] + k0n, An + j*SHPC + wid*512);
    }
    {
      bf16x8 fa[FM], fb[FNN];
#pragma unroll
      for(int i=0;i<FM;i++) fa[i] = *(const bf16x8*)&Ab[(wy*WM + i*16 + ln16)*BK + u0];
#pragma unroll
      for(int j=0;j<FNN;j++) fb[j] = *(const bf16x8*)&Bb[(wx*WN + j*16 + ln16)*BK + u0];
      __builtin_amdgcn_s_setprio(1);
#pragma unroll
      for(int i=0;i<FM;i++)
#pragma unroll
        for(int j=0;j<FNN;j++)
          acc[i][j] = __builtin_amdgcn_mfma_f32_16x16x32_bf16(fa[i], fb[j], acc[i][j], 0, 0, 0);
      __builtin_amdgcn_s_setprio(0);
    }
    // ---- phase 1: stage B(t+1) | ds_read kk1 | MFMA kk1
    if (pf){
#pragma unroll
      for (int j=0; j<NB; j++) gl_lds16(Bp + gb[j] + k0n, Bn + j*SHPC + wid*512);
    }
    {
      bf16x8 fa[FM], fb[FNN];
#pragma unroll
      for(int i=0;i<FM;i++) fa[i] = *(const bf16x8*)&Ab[(wy*WM + i*16 + ln16)*BK + u1];
#pragma unroll
      for(int j=0;j<FNN;j++) fb[j] = *(const bf16x8*)&Bb[(wx*WN + j*16 + ln16)*BK + u1];
      __builtin_amdgcn_s_setprio(1);
#pragma unroll
      for(int i=0;i<FM;i++)
#pragma unroll
        for(int j=0;j<FNN;j++)
          acc[i][j] = __builtin_amdgcn_mfma_f32_16x16x32_bf16(fa[i], fb[j], acc[i][j], 0, 0, 0);
      __builtin_amdgcn_s_setprio(0);
    }
  }

  // epilogue: C[m = quad*4+r][n = lane&15]
#pragma unroll
  for(int i=0;i<FM;i++){
    int mbase = m0 + wy*WM + i*16 + (lane>>4)*4;
#pragma unroll
    for(int j=0;j<FNN;j++){
      int n = n0 + wx*WN + j*16 + ln16;
      float bv = biasp ? biasp[n] : 0.f;
      f32x4 v = acc[i][j];
#pragma unroll
      for(int r=0;r<4;r++){
        int m = mbase + r;
        if (m < cnt){
          float x = v[r]*scale + bv;
          if constexpr (ACT == 1) x = 0.5f*x*(1.f + erff(x*0.70710678118654752f));
          long ci = (long)(MOE ? seg + m : m)*ldc + n;
          if constexpr (ADD_IN) x += addin[ci];
          if constexpr (OUT_BF16) Ch[ci] = f2bf(x);
          else Cf[ci] = x;
        }
      }
    }
  }
}

// ---------------------------------------------------------------------------
// Fused flash attention. grid (S/64, B*H). 4 waves, each owns 16 Q-rows.
// ---------------------------------------------------------------------------
__global__ __launch_bounds__(256)
void flash_k(const unsigned short* __restrict__ qkvb, const unsigned short* __restrict__ Vt,
             unsigned short* __restrict__ ctx)
{
  __shared__ unsigned short Pl[4][16*72];
  const int qt = blockIdx.x, z = blockIdx.y, b = z>>3, h = z&7;
  const int wid = threadIdx.x>>6, lane = threadIdx.x&63;
  const int ln16 = lane&15, g = lane>>4;
  const int q0 = qt*64 + wid*16;
  unsigned short* Pw = &Pl[wid][0];

  const unsigned short* Qp = qkvb + (long)(b*1024 + q0 + ln16)*1536 + h*64 + g*8;
  bf16x8 qf0 = *(const bf16x8*)Qp;
  bf16x8 qf1 = *(const bf16x8*)(Qp + 32);
  const unsigned short* Kbase = qkvb + (long)b*1024*1536 + 512 + h*64 + g*8;
  const unsigned short* Vbase = Vt + (long)z*65536 + g*8;

  float m_s[4], l_s[4];
  f32x4 oacc[4];
#pragma unroll
  for(int r=0;r<4;r++){ m_s[r] = -1e30f; l_s[r] = 0.f; }
#pragma unroll
  for(int j=0;j<4;j++){ f32x4 zz = {0.f,0.f,0.f,0.f}; oacc[j] = zz; }

  for (int t = 0; t < 16; ++t){
    bf16x8 kf[4][2], vf[4][2];
#pragma unroll
    for(int j=0;j<4;j++){
      const unsigned short* kp = Kbase + (long)(t*64 + j*16 + ln16)*1536;
      kf[j][0] = *(const bf16x8*)kp;
      kf[j][1] = *(const bf16x8*)(kp + 32);
      const unsigned short* vp = Vbase + (long)(j*16 + ln16)*1024 + t*64;
      vf[j][0] = *(const bf16x8*)vp;
      vf[j][1] = *(const bf16x8*)(vp + 32);
    }
    f32x4 sacc[4];
#pragma unroll
    for(int j=0;j<4;j++){ f32x4 zz = {0.f,0.f,0.f,0.f}; sacc[j] = zz; }
#pragma unroll
    for(int j=0;j<4;j++){
      sacc[j] = __builtin_amdgcn_mfma_f32_16x16x32_bf16(qf0, kf[j][0], sacc[j], 0,0,0);
      sacc[j] = __builtin_amdgcn_mfma_f32_16x16x32_bf16(qf1, kf[j][1], sacc[j], 0,0,0);
    }
#pragma unroll
    for(int j=0;j<4;j++)
#pragma unroll
      for(int r=0;r<4;r++) sacc[j][r] *= 0.125f;
    float alpha[4];
#pragma unroll
    for(int r=0;r<4;r++){
      float mx = fmaxf(fmaxf(sacc[0][r], sacc[1][r]), fmaxf(sacc[2][r], sacc[3][r]));
#pragma unroll
      for(int m=1;m<16;m<<=1) mx = fmaxf(mx, __shfl_xor(mx, m, 64));
      float mn = fmaxf(m_s[r], mx);
      alpha[r] = __expf(m_s[r] - mn);
      m_s[r] = mn;
    }
#pragma unroll
    for(int j=0;j<4;j++)
#pragma unroll
      for(int r=0;r<4;r++) sacc[j][r] = __expf(sacc[j][r] - m_s[r]);
#pragma unroll
    for(int r=0;r<4;r++){
      float rs = sacc[0][r]+sacc[1][r]+sacc[2][r]+sacc[3][r];
#pragma unroll
      for(int m=1;m<16;m<<=1) rs += __shfl_xor(rs, m, 64);
      l_s[r] = l_s[r]*alpha[r] + rs;
    }
#pragma unroll
    for(int j=0;j<4;j++)
#pragma unroll
      for(int r=0;r<4;r++) oacc[j][r] *= alpha[r];
#pragma unroll
    for(int j=0;j<4;j++)
#pragma unroll
      for(int r=0;r<4;r++)
        Pw[(g*4+r)*72 + j*16 + ln16] = f2bf(sacc[j][r]);
    bf16x8 pf0 = *(const bf16x8*)&Pw[ln16*72 + g*8];
    bf16x8 pf1 = *(const bf16x8*)&Pw[ln16*72 + 32 + g*8];
#pragma unroll
    for(int j=0;j<4;j++){
      oacc[j] = __builtin_amdgcn_mfma_f32_16x16x32_bf16(pf0, vf[j][0], oacc[j], 0,0,0);
      oacc[j] = __builtin_amdgcn_mfma_f32_16x16x32_bf16(pf1, vf[j][1], oacc[j], 0,0,0);
    }
  }
#pragma unroll
  for(int r=0;r<4;r++){
    float inv = 1.f/l_s[r];
    long row = (long)(b*1024 + q0 + g*4 + r)*512 + h*64;
#pragma unroll
    for(int j=0;j<4;j++)
      ctx[row + j*16 + ln16] = f2bf(oacc[j][r]*inv);
  }
}

// ---------------------------------------------------------------------------
// Wave-per-row LayerNorm (D=512): 4 rows/block, no barriers.
// ---------------------------------------------------------------------------
template<bool OUT_BF16>
__global__ __launch_bounds__(256)
void ln_w_k(const float* __restrict__ in, const float* __restrict__ w,
            const float* __restrict__ bb, void* __restrict__ outp)
{
  int row = blockIdx.x*4 + (threadIdx.x>>6), lane = threadIdx.x&63;
  const float4* p = (const float4*)(in + (long)row*512 + lane*8);
  float4 a = p[0], c = p[1];
  float s = a.x+a.y+a.z+a.w + c.x+c.y+c.z+c.w;
  float q = a.x*a.x+a.y*a.y+a.z*a.z+a.w*a.w + c.x*c.x+c.y*c.y+c.z*c.z+c.w*c.w;
  s = wred_sum(s); q = wred_sum(q);
  float mean = s*(1.f/512.f);
  float var  = q*(1.f/512.f) - mean*mean;
  float inv  = rsqrtf(var + 1e-5f);
  const float4* wp = (const float4*)(w + lane*8);
  const float4* bp = (const float4*)(bb + lane*8);
  float4 w0 = wp[0], w1 = wp[1], b0 = bp[0], b1 = bp[1];
  float o0 = (a.x-mean)*inv*w0.x + b0.x, o1 = (a.y-mean)*inv*w0.y + b0.y;
  float o2 = (a.z-mean)*inv*w0.z + b0.z, o3 = (a.w-mean)*inv*w0.w + b0.w;
  float o4 = (c.x-mean)*inv*w1.x + b1.x, o5 = (c.y-mean)*inv*w1.y + b1.y;
  float o6 = (c.z-mean)*inv*w1.z + b1.z, o7 = (c.w-mean)*inv*w1.w + b1.w;
  if constexpr (OUT_BF16){
    *(uint4*)((unsigned short*)outp + (long)row*512 + lane*8) =
      make_uint4(pk2(o0,o1), pk2(o2,o3), pk2(o4,o5), pk2(o6,o7));
  } else {
    float4* op = (float4*)((float*)outp + (long)row*512 + lane*8);
    op[0] = make_float4(o0,o1,o2,o3);
    op[1] = make_float4(o4,o5,o6,o7);
  }
}

// LN2 + router fused: h2 = LN(x) (bf16 out) then top-2 gate; NO global atomics.
__global__ __launch_bounds__(256)
void ln2route_k(const float* __restrict__ in, const float* __restrict__ w,
                const float* __restrict__ bb, unsigned short* __restrict__ h2,
                const float* __restrict__ gw,
                int* __restrict__ tok_e, float* __restrict__ tok_w)
{
  int tok = blockIdx.x*4 + (threadIdx.x>>6), lane = threadIdx.x&63;
  const float4* p = (const float4*)(in + (long)tok*512 + lane*8);
  float4 a = p[0], c = p[1];
  float s = a.x+a.y+a.z+a.w + c.x+c.y+c.z+c.w;
  float q = a.x*a.x+a.y*a.y+a.z*a.z+a.w*a.w + c.x*c.x+c.y*c.y+c.z*c.z+c.w*c.w;
  s = wred_sum(s); q = wred_sum(q);
  float mean = s*(1.f/512.f);
  float var  = q*(1.f/512.f) - mean*mean;
  float inv  = rsqrtf(var + 1e-5f);
  const float4* wp = (const float4*)(w + lane*8);
  const float4* bp = (const float4*)(bb + lane*8);
  float4 w0 = wp[0], w1 = wp[1], b0 = bp[0], b1 = bp[1];
  float o[8];
  o[0] = (a.x-mean)*inv*w0.x + b0.x; o[1] = (a.y-mean)*inv*w0.y + b0.y;
  o[2] = (a.z-mean)*inv*w0.z + b0.z; o[3] = (a.w-mean)*inv*w0.w + b0.w;
  o[4] = (c.x-mean)*inv*w1.x + b1.x; o[5] = (c.y-mean)*inv*w1.y + b1.y;
  o[6] = (c.z-mean)*inv*w1.z + b1.z; o[7] = (c.w-mean)*inv*w1.w + b1.w;
  *(uint4*)(h2 + (long)tok*512 + lane*8) =
    make_uint4(pk2(o[0],o[1]), pk2(o[2],o[3]), pk2(o[4],o[5]), pk2(o[6],o[7]));
  float lg[8];
#pragma unroll
  for(int e=0;e<8;e++){
    const float4* gr = (const float4*)(gw + e*512 + lane*8);
    float4 g0 = gr[0], g1 = gr[1];
    float d = o[0]*g0.x + o[1]*g0.y + o[2]*g0.z + o[3]*g0.w
            + o[4]*g1.x + o[5]*g1.y + o[6]*g1.z + o[7]*g1.w;
    lg[e] = wred_sum(d);
  }
  if (lane == 0){
    float mx = lg[0];
#pragma unroll
    for(int e=1;e<8;e++) mx = fmaxf(mx, lg[e]);
    float pr[8];
#pragma unroll
    for(int e=0;e<8;e++) pr[e] = expf(lg[e]-mx);
    int e0 = 0; float p0 = pr[0];
#pragma unroll
    for(int e=1;e<8;e++) if (pr[e] > p0){ p0 = pr[e]; e0 = e; }
    int e1 = -1; float p1 = -1.f;
#pragma unroll
    for(int e=0;e<8;e++) if (e != e0 && pr[e] > p1){ p1 = pr[e]; e1 = e; }
    float invp = 1.f/(p0+p1);
    tok_e[2*tok] = e0; tok_e[2*tok+1] = e1;
    tok_w[2*tok] = p0*invp; tok_w[2*tok+1] = p1*invp;
  }
}

// ---------------------------------------------------------------------------
// Single-block planner + scatter: LDS-atomic histogram, offsets, two block
// tables (BM=128 for FFN1, BM=64 for FFN2), aux, and compaction scatter.
// ---------------------------------------------------------------------------
__global__ __launch_bounds__(1024)
void plan_scatter_k(const int* __restrict__ tok_e, const float* __restrict__ tok_w,
                    int* __restrict__ offs, int* __restrict__ cnts, float* __restrict__ aux,
                    int* __restrict__ btab, int* __restrict__ btab64,
                    int* __restrict__ rowtok, float* __restrict__ roww, int* __restrict__ rowof)
{
  __shared__ int hist[8];
  __shared__ int offsS[8];
  __shared__ int base[8];
  const int t = threadIdx.x;
  if (t < 8) hist[t] = 0;
  __syncthreads();
  int e[8]; float w[8];
#pragma unroll
  for (int i=0;i<8;i++){
    e[i] = tok_e[t + i*1024];
    w[i] = tok_w[t + i*1024];
    atomicAdd(&hist[e[i]], 1);
  }
  __syncthreads();
  if (t == 0){
    int o = 0, idx = 0, idx2 = 0; float a = 0.f;
    for (int ee=0; ee<8; ee++){
      offsS[ee] = o;
      int c = hist[ee];
      o += c;
      float u = (float)c*(1.f/4096.f) - 0.125f;
      a += u*u;
      int nb = (c + 127) >> 7;
      for (int j=0;j<nb;j++) btab[idx++] = (ee<<8)|j;
      int nb2 = (c + 63) >> 6;
      for (int j=0;j<nb2;j++) btab64[idx2++] = (ee<<8)|j;
    }
    while (idx < 80) btab[idx++] = -1;
    while (idx2 < 144) btab64[idx2++] = -1;
    *aux += a*(1.f/8.f);
  }
  __syncthreads();
  if (t < 8){
    cnts[t] = hist[t];
    offs[t] = offsS[t];
    base[t] = offsS[t];
  }
  __syncthreads();
#pragma unroll
  for (int i=0;i<8;i++){
    int pos = atomicAdd(&base[e[i]], 1);   // LDS atomic
    int gi = t + i*1024;
    rowtok[pos] = gi>>1;
    roww[pos] = w[i];
    rowof[gi] = pos;
  }
}

// Fused MoE combine + LN, wave per token
__global__ __launch_bounds__(256)
void ln_moe_k(const float* __restrict__ eout, const int* __restrict__ rowof,
              const float* __restrict__ roww, const float* __restrict__ mask,
              const unsigned short* __restrict__ h2,
              const float* __restrict__ w, const float* __restrict__ bb,
              float* __restrict__ outp)
{
  int tok = blockIdx.x*4 + (threadIdx.x>>6), lane = threadIdx.x&63;
  int r0 = rowof[2*tok], r1 = rowof[2*tok+1];
  float w0w = roww[r0], w1w = roww[r1], mk = mask[tok];
  const float4* ap = (const float4*)(eout + (long)r0*512 + lane*8);
  const float4* bp2 = (const float4*)(eout + (long)r1*512 + lane*8);
  float4 a0 = ap[0], a1 = ap[1], c0 = bp2[0], c1 = bp2[1];
  uint4 hu = *(const uint4*)(h2 + (long)tok*512 + lane*8);
  const unsigned short* hh = (const unsigned short*)&hu;
  float v[8];
  v[0] = bf2f(hh[0]) + (a0.x*w0w + c0.x*w1w)*mk;
  v[1] = bf2f(hh[1]) + (a0.y*w0w + c0.y*w1w)*mk;
  v[2] = bf2f(hh[2]) + (a0.z*w0w + c0.z*w1w)*mk;
  v[3] = bf2f(hh[3]) + (a0.w*w0w + c0.w*w1w)*mk;
  v[4] = bf2f(hh[4]) + (a1.x*w0w + c1.x*w1w)*mk;
  v[5] = bf2f(hh[5]) + (a1.y*w0w + c1.y*w1w)*mk;
  v[6] = bf2f(hh[6]) + (a1.z*w0w + c1.z*w1w)*mk;
  v[7] = bf2f(hh[7]) + (a1.w*w0w + c1.w*w1w)*mk;
  float s = 0.f, q = 0.f;
#pragma unroll
  for(int i=0;i<8;i++){ s += v[i]; q += v[i]*v[i]; }
  s = wred_sum(s); q = wred_sum(q);
  float mean = s*(1.f/512.f);
  float var  = q*(1.f/512.f) - mean*mean;
  float inv  = rsqrtf(var + 1e-5f);
  const float4* wp = (const float4*)(w + lane*8);
  const float4* bpp = (const float4*)(bb + lane*8);
  float4 w0 = wp[0], w1 = wp[1], b0 = bpp[0], b1 = bpp[1];
  float wv[8] = {w0.x,w0.y,w0.z,w0.w,w1.x,w1.y,w1.z,w1.w};
  float bv[8] = {b0.x,b0.y,b0.z,b0.w,b1.x,b1.y,b1.z,b1.w};
  float4* op = (float4*)(outp + (long)tok*512 + lane*8);
  op[0] = make_float4((v[0]-mean)*inv*wv[0]+bv[0], (v[1]-mean)*inv*wv[1]+bv[1],
                      (v[2]-mean)*inv*wv[2]+bv[2], (v[3]-mean)*inv*wv[3]+bv[3]);
  op[1] = make_float4((v[4]-mean)*inv*wv[4]+bv[4], (v[5]-mean)*inv*wv[5]+bv[5],
                      (v[6]-mean)*inv*wv[6]+bv[6], (v[7]-mean)*inv*wv[7]+bv[7]);
}

// Build Vt[bh][d][k] bf16 from qkv V slice; grid (4,32), 4 chunks per block
__global__ __launch_bounds__(256)
void vt_k(const unsigned short* __restrict__ qkvb, unsigned short* __restrict__ Vt)
{
  __shared__ unsigned short tile[64][80];
  int z = blockIdx.y, b = z>>3, h = z&7;
  int t = threadIdx.x;
  int kk = t>>2, dd = (t&3)*16;
  int dd2 = t>>2, kk2 = (t&3)*16;
  for (int c = 0; c < 4; ++c){
    int k0 = (blockIdx.x*4 + c)*64;
    const unsigned short* p = qkvb + ((long)(b*1024 + k0 + kk))*1536 + 1024 + h*64 + dd;
    uint4 u0 = *(const uint4*)p, u1 = *(const uint4*)(p+8);
    __syncthreads();
    *(uint4*)&tile[kk][dd] = u0;
    *(uint4*)&tile[kk][dd+8] = u1;
    __syncthreads();
    uint4 o0, o1;
    unsigned short* s0 = (unsigned short*)&o0;
    unsigned short* s1 = (unsigned short*)&o1;
#pragma unroll
    for(int j=0;j<8;j++){ s0[j] = tile[kk2+j][dd2]; s1[j] = tile[kk2+8+j][dd2]; }
    unsigned short* o = Vt + (long)z*65536 + (long)dd2*1024 + k0 + kk2;
    *(uint4*)o = o0; *(uint4*)(o+8) = o1;
  }
}

// fp32 (R,C) -> bf16 (C,R), z-loop of ZL
__global__ __launch_bounds__(256)
void transpose_cast_k(const float* __restrict__ in, unsigned short* __restrict__ outp,
                      int R, int C, int ZL)
{
  __shared__ float tile[64][65];
  int t = threadIdx.x;
  int rr = t>>2, cc = (t&3)*16;
  int cc2 = t>>2, rr2 = (t&3)*16;
  int c0 = blockIdx.x*64, r0 = blockIdx.y*64;
  for (int zi = 0; zi < ZL; ++zi){
    long zoff = (long)(blockIdx.z*ZL + zi) * R * C;
    const float* pin = in + zoff + (long)(r0+rr)*C + c0 + cc;
    float4 v0=*(const float4*)pin, v1=*(const float4*)(pin+4), v2=*(const float4*)(pin+8), v3=*(const float4*)(pin+12);
    __syncthreads();
    tile[rr][cc+0]=v0.x; tile[rr][cc+1]=v0.y; tile[rr][cc+2]=v0.z; tile[rr][cc+3]=v0.w;
    tile[rr][cc+4]=v1.x; tile[rr][cc+5]=v1.y; tile[rr][cc+6]=v1.z; tile[rr][cc+7]=v1.w;
    tile[rr][cc+8]=v2.x; tile[rr][cc+9]=v2.y; tile[rr][cc+10]=v2.z; tile[rr][cc+11]=v2.w;
    tile[rr][cc+12]=v3.x; tile[rr][cc+13]=v3.y; tile[rr][cc+14]=v3.z; tile[rr][cc+15]=v3.w;
    __syncthreads();
    unsigned tmp[8];
#pragma unroll
    for(int jj=0;jj<8;jj++)
      tmp[jj] = pk2(tile[rr2+2*jj][cc2], tile[rr2+2*jj+1][cc2]);
    uint4* dst = (uint4*)(outp + zoff + (long)(c0+cc2)*R + r0 + rr2);
    dst[0] = make_uint4(tmp[0],tmp[1],tmp[2],tmp[3]);
    dst[1] = make_uint4(tmp[4],tmp[5],tmp[6],tmp[7]);
  }
}

// fp32 -> bf16, grid-stride
__global__ __launch_bounds__(256)
void cast_bf16_k(const float* __restrict__ in, unsigned short* __restrict__ outp, int n8)
{
  for (int i = blockIdx.x*256 + threadIdx.x; i < n8; i += gridDim.x*256){
    const float4* p = (const float4*)(in + (long)i*8);
    float4 a = p[0], b = p[1];
    *(uint4*)(outp + (long)i*8) = make_uint4(pk2(a.x,a.y), pk2(a.z,a.w), pk2(b.x,b.y), pk2(b.z,b.w));
  }
}

// masked-sum partial pooling, NO atomics: grid (4,8) -> 8 partials per batch
__global__ __launch_bounds__(256)
void pool2_k(const float* __restrict__ h, const float* __restrict__ mask, float* __restrict__ pooled)
{
  int b = blockIdx.x, sc = blockIdx.y, t = threadIdx.x;
  float a0 = 0.f, a1 = 0.f;
  const float* mb = mask + b*1024 + sc*128;
  const float* hbase = h + ((long)b*1024 + sc*128)*512;
  for (int s = 0; s < 128; ++s){
    float mk = mb[s];
    const float* r = hbase + (long)s*512;
    a0 += r[t]*mk; a1 += r[t+256]*mk;
  }
  pooled[((b*8 + sc)*512) + t] = a0;
  pooled[((b*8 + sc)*512) + t + 256] = a1;
}

__global__ __launch_bounds__(256)
void head_final_k(const float* __restrict__ pooled, const float* __restrict__ mask,
                  const float* __restrict__ pool_w, const float* __restrict__ pool_b,
                  const float* __restrict__ cls_w, const float* __restrict__ cls_b,
                  const float* __restrict__ cf_w1, const float* __restrict__ cf_b1,
                  const float* __restrict__ cf_w2, const float* __restrict__ cf_b2,
                  const float* __restrict__ aux, float* __restrict__ out)
{
  int b = blockIdx.x, t = threadIdx.x, wid = t>>6, lane = t&63;
  __shared__ __align__(16) float pld[512];
  __shared__ __align__(16) float p2[512];
  __shared__ float red[4];
  float ds = 0.f;
  for(int s=t; s<1024; s+=256) ds += mask[b*1024 + s];
  ds = wred_sum(ds);
  if (lane==0) red[wid] = ds;
  __syncthreads();
  float denom = fmaxf(red[0]+red[1]+red[2]+red[3], 1e-9f);
  float s0 = 0.f, s1 = 0.f;
#pragma unroll
  for(int sc=0;sc<8;sc++){
    s0 += pooled[((b*8+sc)*512) + t];
    s1 += pooled[((b*8+sc)*512) + t + 256];
  }
  pld[t]     = s0/denom;
  pld[t+256] = s1/denom;
  __syncthreads();
#pragma unroll
  for(int jj=0;jj<2;jj++){
    int j = t + jj*256;
    const float4* wr = (const float4*)(pool_w + (long)j*512);
    float acc = 0.f;
    for(int i=0;i<128;i++){
      float4 w4 = wr[i]; float4 x4 = ((const float4*)pld)[i];
      acc += w4.x*x4.x + w4.y*x4.y + w4.z*x4.z + w4.w*x4.w;
    }
    p2[j] = tanhf(acc + pool_b[j]);
  }
  __syncthreads();
  if (t < 4){
    const float4* wr = (const float4*)(cls_w + (long)t*512);
    float acc = 0.f;
    for(int i=0;i<128;i++){
      float4 w4 = wr[i]; float4 x4 = ((const float4*)p2)[i];
      acc += w4.x*x4.x + w4.y*x4.y + w4.z*x4.z + w4.w*x4.w;
    }
    out[b*4 + t] = acc + cls_b[t];
  }
  {
    const float4* wr = (const float4*)(cf_w1 + (long)t*512);
    float acc = 0.f;
    for(int i=0;i<128;i++){
      float4 w4 = wr[i]; float4 x4 = ((const float4*)p2)[i];
      acc += w4.x*x4.x + w4.y*x4.y + w4.z*x4.z + w4.w*x4.w;
    }
    acc = fmaxf(acc + cf_b1[t], 0.f) * cf_w2[t];
    acc = wred_sum(acc);
    __syncthreads();
    if (lane==0) red[wid] = acc;
    __syncthreads();
    if (t == 0){
      float sum = red[0]+red[1]+red[2]+red[3];
      out[17 + b] = 1.f/(1.f + expf(-(sum + cf_b2[0])));
    }
  }
  if (b == 0 && t == 0) out[16] = aux[0]*0.25f;
}

// ---------------------------------------------------------------------------
extern "C" void kernel_launch(void* const* d_in, const int* in_sizes, int n_in,
                              void* d_out, int out_size, void* d_ws, size_t ws_size,
                              hipStream_t stream)
{
  (void)in_sizes; (void)n_in; (void)out_size;
  const float* emb    = (const float*)d_in[0];
  const float* mask   = (const float*)d_in[1];
  const float* in_w   = (const float*)d_in[2];
  const float* in_b   = (const float*)d_in[3];
  const float* out_w  = (const float*)d_in[4];
  const float* out_b  = (const float*)d_in[5];
  const float* ln1_w  = (const float*)d_in[6];
  const float* ln1_b  = (const float*)d_in[7];
  const float* ln2_w  = (const float*)d_in[8];
  const float* ln2_b  = (const float*)d_in[9];
  const float* gate_w = (const float*)d_in[10];
  const float* e_w1   = (const float*)d_in[11];
  const float* e_b1   = (const float*)d_in[12];
  const float* e_w2   = (const float*)d_in[13];
  const float* e_b2   = (const float*)d_in[14];
  const float* mln_w  = (const float*)d_in[15];
  const float* mln_b  = (const float*)d_in[16];
  const float* fln_w  = (const float*)d_in[17];
  const float* fln_b  = (const float*)d_in[18];
  const float* pool_w = (const float*)d_in[19];
  const float* pool_b = (const float*)d_in[20];
  const float* cls_w  = (const float*)d_in[21];
  const float* cls_b  = (const float*)d_in[22];
  const float* cf_w1  = (const float*)d_in[23];
  const float* cf_b1  = (const float*)d_in[24];
  const float* cf_w2  = (const float*)d_in[25];
  const float* cf_b2  = (const float*)d_in[26];
  float* out = (float*)d_out;
  char* ws = (char*)d_ws;

  const size_t MiB = 1024*1024;
  if (ws_size < 218*MiB) return;

  // Workspace layout
  float*          x     = (float*)(ws + 0*MiB);             // 8 MiB fp32
  unsigned short* hb    = (unsigned short*)(ws + 8*MiB);    // 4 MiB bf16
  unsigned short* qkvb  = (unsigned short*)(ws + 12*MiB);   // 12 MiB bf16
  unsigned short* ctx   = (unsigned short*)(ws + 24*MiB);   // 4 MiB bf16
  unsigned short* Vt    = (unsigned short*)(ws + 28*MiB);   // 4 MiB bf16
  unsigned short* mid   = (unsigned short*)(ws + 32*MiB);   // 32 MiB bf16
  float*          eout  = (float*)(ws + 64*MiB);            // 16 MiB fp32
  float*          fout  = (float*)(ws + 64*MiB);            //   (reuse, head)
  unsigned short* w1t   = (unsigned short*)(ws + 80*MiB);   // 64 MiB bf16
  unsigned short* w2t   = (unsigned short*)(ws + 144*MiB);  // 64 MiB bf16
  unsigned short* inwb  = (unsigned short*)(ws + 208*MiB);  // 6 MiB bf16
  unsigned short* outwb = (unsigned short*)(ws + 214*MiB);  // 2 MiB bf16
  char* misc = ws + 216*MiB;
  int*   counts  = (int*)(misc + 0);
  int*   offs    = (int*)(misc + 64);
  float* aux     = (float*)(misc + 128);
  int*   btab    = (int*)(misc + 256);       // 80 ints
  int*   btab64  = (int*)(misc + 1024);      // 144 ints
  float* pooled  = (float*)(misc + 4096);    // 64 KiB
  int*   tok_e   = (int*)(misc + 81920);
  float* tok_w   = (float*)(misc + 114688);
  int*   rowtok  = (int*)(misc + 147456);
  float* roww    = (float*)(misc + 180224);
  int*   rowof   = (int*)(misc + 212992);

  hipMemcpyAsync(x, emb, (size_t)T_*D_*4, hipMemcpyDeviceToDevice, stream);
  hipMemsetAsync(aux, 0, 4, stream);
  // weight prep
  cast_bf16_k<<<512, 256, 0, stream>>>(in_w, inwb, L_*3*D_*D_/8);
  cast_bf16_k<<<256, 256, 0, stream>>>(out_w, outwb, L_*D_*D_/8);
  transpose_cast_k<<<dim3(I_/64, D_/64, 4), 256, 0, stream>>>(e_w1, w1t, D_, I_, 8);
  transpose_cast_k<<<dim3(D_/64, I_/64, 4), 256, 0, stream>>>(e_w2, w2t, I_, D_, 8);

  for (int l=0; l<L_; l++){
    const float* inbl  = in_b  + (size_t)l*3*D_;
    const float* outbl = out_b + (size_t)l*D_;
    const float* gwl   = gate_w + (size_t)l*E_*D_;
    const float* eb1l  = e_b1 + (size_t)l*E_*I_;
    const float* eb2l  = e_b2 + (size_t)l*E_*D_;
    const unsigned short* inwbl  = inwb + (size_t)l*3*D_*D_;
    const unsigned short* outwbl = outwb + (size_t)l*D_*D_;
    const unsigned short* w1tl = w1t + (size_t)l*E_*I_*D_;
    const unsigned short* w2tl = w2t + (size_t)l*E_*D_*I_;

    // h = LN1(x) -> bf16
    ln_w_k<true><<<T_/4, 256, 0, stream>>>(x, ln1_w + (size_t)l*D_, ln1_b + (size_t)l*D_, hb);
    // qkv = h @ in_w^T + in_b -> bf16   (64x128: 768 blocks, nby=12)
    gemm_k<64,128,false,false,true,0,false><<<dim3(768,1,1), 512, 0, stream>>>(
      hb, inwbl, qkvb, inbl, nullptr, T_, 3*D_, D_, D_, D_, 3*D_,
      1, 0,0,0,0,0,0, 1.f, nullptr, nullptr, nullptr, nullptr, 0, 0, 12);
    vt_k<<<dim3(4,32), 256, 0, stream>>>(qkvb, Vt);
    // fused attention -> ctx (B,S,512) bf16
    flash_k<<<dim3(16,32), 256, 0, stream>>>(qkvb, Vt, ctx);
    // x = x + ctx @ out_w^T + out_b  (fp32)   (64x64: 512 blocks, nby=8)
    gemm_k<64,64,false,false,false,0,true><<<dim3(512,1,1), 512, 0, stream>>>(
      ctx, outwbl, x, outbl, x, T_, D_, D_, D_, D_, D_,
      1, 0,0,0,0,0,0, 1.f, nullptr, nullptr, nullptr, nullptr, 0, 0, 8);
    // h2 = LN2(x) -> bf16, + routing (no atomics)
    ln2route_k<<<T_/4, 256, 0, stream>>>(x, ln2_w + (size_t)l*D_, ln2_b + (size_t)l*D_,
                                         hb, gwl, tok_e, tok_w);
    // plan + scatter, single block, LDS atomics only
    plan_scatter_k<<<1, 1024, 0, stream>>>(tok_e, tok_w, offs, counts, aux, btab, btab64,
                                           rowtok, roww, rowof);
    // FFN1: mid = gelu(gather(h2) @ w1^T + b1) -> bf16   (BM=128, 1136 blocks, nby=16)
    gemm_k<128,128,true,true,true,1,false><<<dim3(1136,1,1), 512, 0, stream>>>(
      hb, w1tl, mid, eb1l, nullptr, 2*T_, I_, D_, D_, D_, I_,
      1, 0,0,0,0,0,0, 1.f, offs, counts, rowtok, btab, (long)I_*D_, I_, 16);
    // FFN2: eout = mid @ w2^T + b2 -> fp32   (BM=64, 544 blocks, nby=4)
    gemm_k<64,128,true,false,false,0,false><<<dim3(544,1,1), 512, 0, stream>>>(
      mid, w2tl, eout, eb2l, nullptr, 2*T_, D_, I_, I_, I_, D_,
      1, 0,0,0,0,0,0, 1.f, offs, counts, nullptr, btab64, (long)D_*I_, D_, 4);
    // x = LN(h2 + combine(eout))
    ln_moe_k<<<T_/4, 256, 0, stream>>>(eout, rowof, roww, mask, hb,
                                       mln_w + (size_t)l*D_, mln_b + (size_t)l*D_, x);
  }
  // head
  ln_w_k<false><<<T_/4, 256, 0, stream>>>(x, fln_w, fln_b, fout);
  pool2_k<<<dim3(4,8), 256, 0, stream>>>(fout, mask, pooled);
  head_final_k<<<4, 256, 0, stream>>>(pooled, mask, pool_w, pool_b, cls_w, cls_b,
                                      cf_w1, cf_b1, cf_w2, cf_b2, aux, out);
}

// Round 6
// 1293.700 us; speedup vs baseline: 1.1617x; 1.0253x over previous
//
#include <hip/hip_runtime.h>
#include <math.h>

// Problem constants
#define B_ 4
#define S_ 1024
#define D_ 512
#define H_ 8
#define DH_ 64
#define I_ 2048
#define E_ 8
#define L_ 4
#define T_ 4096   // B*S

using bf16x8 = __attribute__((ext_vector_type(8))) __bf16;
using f32x4  = __attribute__((ext_vector_type(4))) float;

typedef __attribute__((address_space(1))) const void gvoid;
typedef __attribute__((address_space(3))) void lvoid;
__device__ __forceinline__ void gl_lds16(const void* g, void* l){
  __builtin_amdgcn_global_load_lds((gvoid*)g, (lvoid*)l, 16, 0, 0);
}

__device__ __forceinline__ float wred_sum(float v){
#pragma unroll
  for(int m=32;m>0;m>>=1) v += __shfl_xor(v, m, 64);
  return v;
}
__device__ __forceinline__ unsigned short f2bf(float f){
  unsigned x = __float_as_uint(f);
  unsigned r = (x + 0x7FFFu + ((x>>16)&1u)) >> 16;
  return (unsigned short)r;
}
__device__ __forceinline__ float bf2f(unsigned short u){
  return __uint_as_float(((unsigned)u)<<16);
}
__device__ __forceinline__ unsigned pk2(float a, float b){
  return (unsigned)f2bf(a) | ((unsigned)f2bf(b)<<16);
}

// ---------------------------------------------------------------------------
// bf16 MFMA GEMM. NT: C[m,n] = sum_k A[m,k]*B[n,k].
// 512 threads = 8 waves in 2x4 (wy=wid>>2, wx=wid&3): per-wave tile WM=BM/2,
// WN=BN/4. Occupancy is the validated lever (R5: 4->8 waves = -9% total).
// FFN1 now BM=128,BN=64 -> 48KB LDS -> 3 blocks/CU (24 waves, was 16).
// BK=64, double-buffered LDS, phase-interleaved schedule:
//   per K-step: [vmcnt(0); s_barrier] then
//     phase0: issue stage A(t+1) | ds_read kk0 | setprio(1) MFMA kk0
//     phase1: issue stage B(t+1) | ds_read kk1 | setprio(1) MFMA kk1
// ONE barrier per K-step (top barrier protects both buffers).
// T2 bank-conflict fix (verified 6.78M->0): LDS dest linear, global SOURCE
// col unit ^= (row&7); fragment reads XOR the same involution.
// 1-D grid with XCD-chunked bijective swizzle (gridDim.x % 8 == 0).
// MOE: block table btab[bx] = (e<<8)|mblk, -1 = dead. Optional row gather.
// ---------------------------------------------------------------------------
template<int BM, int BN, bool MOE, bool GATHER, bool OUT_BF16, int ACT, bool ADD_IN>
__global__ __launch_bounds__(512)
void gemm_k(const unsigned short* __restrict__ A, const unsigned short* __restrict__ Bv,
            void* Cp, const float* __restrict__ bias, const float* addin,
            int M, int N, int K, int lda, int ldb, int ldc,
            int hdiv, long sAb, long sAh, long sBb, long sBh, long sCb, long sCh,
            float scale,
            const int* __restrict__ moff, const int* __restrict__ mcnt,
            const int* __restrict__ rowtok, const int* __restrict__ btab,
            long sBe, int biasStride, int nby)
{
  constexpr int BK = 64;
  constexpr int WM = BM/2, WN = BN/4, FM = WM/16, FNN = WN/16;
  constexpr int RPC = 64;            // rows covered per block-wide gl_lds16 call (512 thr / 8 per row)
  constexpr int SHPC = 4096;         // shorts per call (512 thr * 8)
  constexpr int NA = BM/RPC, NB = BN/RPC;
  __shared__ unsigned short As[2*BM*BK];
  __shared__ unsigned short Bs[2*BN*BK];

  const int tid = threadIdx.x, wid = tid>>6, lane = tid&63;
  const int wy = wid>>2, wx = wid&3, ln16 = lane&15;

  // XCD-chunked bijective swizzle: consecutive hw ids round-robin XCDs;
  // remap so each XCD owns a contiguous chunk of (bx,by) space, by innermost.
  const int nwg = gridDim.x, cpx = nwg >> 3;
  const int lin = blockIdx.x;
  const int wg  = (lin & 7)*cpx + (lin >> 3);
  const int bxi = wg / nby, byi = wg % nby;

  int m0 = bxi*BM;
  const int n0 = byi*BN;

  float* Cf = nullptr; unsigned short* Ch = nullptr;
  const float* biasp = bias;
  const unsigned short* Bp = Bv;
  int seg = 0, cnt = M;

  if constexpr (MOE){
    int tv = btab[bxi];
    if (tv < 0) return;
    int e = tv>>8;
    m0 = (tv&255)*BM;
    seg = moff[e]; cnt = mcnt[e];
    Bp = Bv + (long)e*sBe;
    if constexpr (OUT_BF16) Ch = (unsigned short*)Cp; else Cf = (float*)Cp;
    if (biasp) biasp += (long)e*biasStride;
  } else {
    int z = blockIdx.z, zb = z/hdiv, zh = z%hdiv;
    A  += (long)zb*sAb + (long)zh*sAh;
    Bp += (long)zb*sBb + (long)zh*sBh;
    long coff = (long)zb*sCb + (long)zh*sCh;
    if constexpr (OUT_BF16) Ch = (unsigned short*)Cp + coff; else Cf = ((float*)Cp) + coff;
    if constexpr (ADD_IN) addin += coff;
  }

  // staging geometry: call j covers rows j*RPC + tid/8, col-unit (tid&7) of 8x16B.
  // SOURCE-side XOR swizzle (T2): unit ^= (row&7); LDS dest stays linear so
  // gl_lds is legal; reads undo the same involution.
  const int srow = tid >> 3;          // 8 lanes per row
  const int scol = ((tid & 7) ^ (srow & 7)) * 8;
  long ga[NA], gb[NB];
#pragma unroll
  for (int j=0; j<NA; j++){
    int r = m0 + j*RPC + srow;
    if constexpr (MOE){
      r = min(r, cnt-1);
      long gr = GATHER ? (long)rowtok[seg+r] : (long)(seg+r);
      ga[j] = gr*lda + scol;
    } else {
      ga[j] = (long)min(r, M-1)*lda + scol;
    }
  }
#pragma unroll
  for (int j=0; j<NB; j++){
    int bn = min(n0 + j*RPC + srow, N-1);
    gb[j] = (long)bn*ldb + scol;
  }

  f32x4 acc[FM][FNN];
#pragma unroll
  for(int i=0;i<FM;i++)
#pragma unroll
    for(int j=0;j<FNN;j++){ f32x4 z = {0.f,0.f,0.f,0.f}; acc[i][j] = z; }

  const int nt = K/BK;
  // read-side swizzle: row&7 == ln16&7 for all fragment rows (WM,WN mult of 8/16)
  const int rsw = ln16 & 7;
  const int u0 = ((lane>>4)     ^ rsw) * 8;   // kk=0 unit offset (elements)
  const int u1 = ((4+(lane>>4)) ^ rsw) * 8;   // kk=1 unit offset

  // prologue: stage tile 0 into buffer 0
#pragma unroll
  for (int j=0; j<NA; j++) gl_lds16(A + ga[j], As + j*SHPC + wid*512);
#pragma unroll
  for (int j=0; j<NB; j++) gl_lds16(Bp + gb[j], Bs + j*SHPC + wid*512);

  for (int t = 0; t < nt; ++t){
    const int cb = t & 1;
    const unsigned short* Ab = As + cb*BM*BK;
    const unsigned short* Bb = Bs + cb*BN*BK;
    unsigned short* An = As + (cb^1)*BM*BK;
    unsigned short* Bn = Bs + (cb^1)*BN*BK;
    const bool pf = (t+1 < nt);
    const long k0n = (long)(t+1)*BK;

    asm volatile("s_waitcnt vmcnt(0)" ::: "memory");  // this tile's loads landed
    __builtin_amdgcn_s_barrier();                     // tile t ready; prev-tile reads done by all waves
    __builtin_amdgcn_sched_barrier(0);                // no ds_read/gl_lds hoists above

    // ---- phase 0: stage A(t+1) | ds_read kk0 | MFMA kk0
    if (pf){
#pragma unroll
      for (int j=0; j<NA; j++) gl_lds16(A + ga[j] + k0n, An + j*SHPC + wid*512);
    }
    {
      bf16x8 fa[FM], fb[FNN];
#pragma unroll
      for(int i=0;i<FM;i++) fa[i] = *(const bf16x8*)&Ab[(wy*WM + i*16 + ln16)*BK + u0];
#pragma unroll
      for(int j=0;j<FNN;j++) fb[j] = *(const bf16x8*)&Bb[(wx*WN + j*16 + ln16)*BK + u0];
      __builtin_amdgcn_s_setprio(1);
#pragma unroll
      for(int i=0;i<FM;i++)
#pragma unroll
        for(int j=0;j<FNN;j++)
          acc[i][j] = __builtin_amdgcn_mfma_f32_16x16x32_bf16(fa[i], fb[j], acc[i][j], 0, 0, 0);
      __builtin_amdgcn_s_setprio(0);
    }
    // ---- phase 1: stage B(t+1) | ds_read kk1 | MFMA kk1
    if (pf){
#pragma unroll
      for (int j=0; j<NB; j++) gl_lds16(Bp + gb[j] + k0n, Bn + j*SHPC + wid*512);
    }
    {
      bf16x8 fa[FM], fb[FNN];
#pragma unroll
      for(int i=0;i<FM;i++) fa[i] = *(const bf16x8*)&Ab[(wy*WM + i*16 + ln16)*BK + u1];
#pragma unroll
      for(int j=0;j<FNN;j++) fb[j] = *(const bf16x8*)&Bb[(wx*WN + j*16 + ln16)*BK + u1];
      __builtin_amdgcn_s_setprio(1);
#pragma unroll
      for(int i=0;i<FM;i++)
#pragma unroll
        for(int j=0;j<FNN;j++)
          acc[i][j] = __builtin_amdgcn_mfma_f32_16x16x32_bf16(fa[i], fb[j], acc[i][j], 0, 0, 0);
      __builtin_amdgcn_s_setprio(0);
    }
  }

  // epilogue: C[m = quad*4+r][n = lane&15]
#pragma unroll
  for(int i=0;i<FM;i++){
    int mbase = m0 + wy*WM + i*16 + (lane>>4)*4;
#pragma unroll
    for(int j=0;j<FNN;j++){
      int n = n0 + wx*WN + j*16 + ln16;
      float bv = biasp ? biasp[n] : 0.f;
      f32x4 v = acc[i][j];
#pragma unroll
      for(int r=0;r<4;r++){
        int m = mbase + r;
        if (m < cnt){
          float x = v[r]*scale + bv;
          if constexpr (ACT == 1) x = 0.5f*x*(1.f + erff(x*0.70710678118654752f));
          long ci = (long)(MOE ? seg + m : m)*ldc + n;
          if constexpr (ADD_IN) x += addin[ci];
          if constexpr (OUT_BF16) Ch[ci] = f2bf(x);
          else Cf[ci] = x;
        }
      }
    }
  }
}

// ---------------------------------------------------------------------------
// Fused flash attention. grid (S/64, B*H). 4 waves, each owns 16 Q-rows.
// ---------------------------------------------------------------------------
__global__ __launch_bounds__(256)
void flash_k(const unsigned short* __restrict__ qkvb, const unsigned short* __restrict__ Vt,
             unsigned short* __restrict__ ctx)
{
  __shared__ unsigned short Pl[4][16*72];
  const int qt = blockIdx.x, z = blockIdx.y, b = z>>3, h = z&7;
  const int wid = threadIdx.x>>6, lane = threadIdx.x&63;
  const int ln16 = lane&15, g = lane>>4;
  const int q0 = qt*64 + wid*16;
  unsigned short* Pw = &Pl[wid][0];

  const unsigned short* Qp = qkvb + (long)(b*1024 + q0 + ln16)*1536 + h*64 + g*8;
  bf16x8 qf0 = *(const bf16x8*)Qp;
  bf16x8 qf1 = *(const bf16x8*)(Qp + 32);
  const unsigned short* Kbase = qkvb + (long)b*1024*1536 + 512 + h*64 + g*8;
  const unsigned short* Vbase = Vt + (long)z*65536 + g*8;

  float m_s[4], l_s[4];
  f32x4 oacc[4];
#pragma unroll
  for(int r=0;r<4;r++){ m_s[r] = -1e30f; l_s[r] = 0.f; }
#pragma unroll
  for(int j=0;j<4;j++){ f32x4 zz = {0.f,0.f,0.f,0.f}; oacc[j] = zz; }

  for (int t = 0; t < 16; ++t){
    bf16x8 kf[4][2], vf[4][2];
#pragma unroll
    for(int j=0;j<4;j++){
      const unsigned short* kp = Kbase + (long)(t*64 + j*16 + ln16)*1536;
      kf[j][0] = *(const bf16x8*)kp;
      kf[j][1] = *(const bf16x8*)(kp + 32);
      const unsigned short* vp = Vbase + (long)(j*16 + ln16)*1024 + t*64;
      vf[j][0] = *(const bf16x8*)vp;
      vf[j][1] = *(const bf16x8*)(vp + 32);
    }
    f32x4 sacc[4];
#pragma unroll
    for(int j=0;j<4;j++){ f32x4 zz = {0.f,0.f,0.f,0.f}; sacc[j] = zz; }
#pragma unroll
    for(int j=0;j<4;j++){
      sacc[j] = __builtin_amdgcn_mfma_f32_16x16x32_bf16(qf0, kf[j][0], sacc[j], 0,0,0);
      sacc[j] = __builtin_amdgcn_mfma_f32_16x16x32_bf16(qf1, kf[j][1], sacc[j], 0,0,0);
    }
#pragma unroll
    for(int j=0;j<4;j++)
#pragma unroll
      for(int r=0;r<4;r++) sacc[j][r] *= 0.125f;
    float alpha[4];
#pragma unroll
    for(int r=0;r<4;r++){
      float mx = fmaxf(fmaxf(sacc[0][r], sacc[1][r]), fmaxf(sacc[2][r], sacc[3][r]));
#pragma unroll
      for(int m=1;m<16;m<<=1) mx = fmaxf(mx, __shfl_xor(mx, m, 64));
      float mn = fmaxf(m_s[r], mx);
      alpha[r] = __expf(m_s[r] - mn);
      m_s[r] = mn;
    }
#pragma unroll
    for(int j=0;j<4;j++)
#pragma unroll
      for(int r=0;r<4;r++) sacc[j][r] = __expf(sacc[j][r] - m_s[r]);
#pragma unroll
    for(int r=0;r<4;r++){
      float rs = sacc[0][r]+sacc[1][r]+sacc[2][r]+sacc[3][r];
#pragma unroll
      for(int m=1;m<16;m<<=1) rs += __shfl_xor(rs, m, 64);
      l_s[r] = l_s[r]*alpha[r] + rs;
    }
#pragma unroll
    for(int j=0;j<4;j++)
#pragma unroll
      for(int r=0;r<4;r++) oacc[j][r] *= alpha[r];
#pragma unroll
    for(int j=0;j<4;j++)
#pragma unroll
      for(int r=0;r<4;r++)
        Pw[(g*4+r)*72 + j*16 + ln16] = f2bf(sacc[j][r]);
    bf16x8 pf0 = *(const bf16x8*)&Pw[ln16*72 + g*8];
    bf16x8 pf1 = *(const bf16x8*)&Pw[ln16*72 + 32 + g*8];
#pragma unroll
    for(int j=0;j<4;j++){
      oacc[j] = __builtin_amdgcn_mfma_f32_16x16x32_bf16(pf0, vf[j][0], oacc[j], 0,0,0);
      oacc[j] = __builtin_amdgcn_mfma_f32_16x16x32_bf16(pf1, vf[j][1], oacc[j], 0,0,0);
    }
  }
#pragma unroll
  for(int r=0;r<4;r++){
    float inv = 1.f/l_s[r];
    long row = (long)(b*1024 + q0 + g*4 + r)*512 + h*64;
#pragma unroll
    for(int j=0;j<4;j++)
      ctx[row + j*16 + ln16] = f2bf(oacc[j][r]*inv);
  }
}

// ---------------------------------------------------------------------------
// Wave-per-row LayerNorm (D=512): 4 rows/block, no barriers. (layer-0 only)
// ---------------------------------------------------------------------------
template<bool OUT_BF16>
__global__ __launch_bounds__(256)
void ln_w_k(const float* __restrict__ in, const float* __restrict__ w,
            const float* __restrict__ bb, void* __restrict__ outp)
{
  int row = blockIdx.x*4 + (threadIdx.x>>6), lane = threadIdx.x&63;
  const float4* p = (const float4*)(in + (long)row*512 + lane*8);
  float4 a = p[0], c = p[1];
  float s = a.x+a.y+a.z+a.w + c.x+c.y+c.z+c.w;
  float q = a.x*a.x+a.y*a.y+a.z*a.z+a.w*a.w + c.x*c.x+c.y*c.y+c.z*c.z+c.w*c.w;
  s = wred_sum(s); q = wred_sum(q);
  float mean = s*(1.f/512.f);
  float var  = q*(1.f/512.f) - mean*mean;
  float inv  = rsqrtf(var + 1e-5f);
  const float4* wp = (const float4*)(w + lane*8);
  const float4* bp = (const float4*)(bb + lane*8);
  float4 w0 = wp[0], w1 = wp[1], b0 = bp[0], b1 = bp[1];
  float o0 = (a.x-mean)*inv*w0.x + b0.x, o1 = (a.y-mean)*inv*w0.y + b0.y;
  float o2 = (a.z-mean)*inv*w0.z + b0.z, o3 = (a.w-mean)*inv*w0.w + b0.w;
  float o4 = (c.x-mean)*inv*w1.x + b1.x, o5 = (c.y-mean)*inv*w1.y + b1.y;
  float o6 = (c.z-mean)*inv*w1.z + b1.z, o7 = (c.w-mean)*inv*w1.w + b1.w;
  if constexpr (OUT_BF16){
    *(uint4*)((unsigned short*)outp + (long)row*512 + lane*8) =
      make_uint4(pk2(o0,o1), pk2(o2,o3), pk2(o4,o5), pk2(o6,o7));
  } else {
    float4* op = (float4*)((float*)outp + (long)row*512 + lane*8);
    op[0] = make_float4(o0,o1,o2,o3);
    op[1] = make_float4(o4,o5,o6,o7);
  }
}

// LN2 + router fused: h2 = LN(x) (bf16 out) then top-2 gate; NO global atomics.
__global__ __launch_bounds__(256)
void ln2route_k(const float* __restrict__ in, const float* __restrict__ w,
                const float* __restrict__ bb, unsigned short* __restrict__ h2,
                const float* __restrict__ gw,
                int* __restrict__ tok_e, float* __restrict__ tok_w)
{
  int tok = blockIdx.x*4 + (threadIdx.x>>6), lane = threadIdx.x&63;
  const float4* p = (const float4*)(in + (long)tok*512 + lane*8);
  float4 a = p[0], c = p[1];
  float s = a.x+a.y+a.z+a.w + c.x+c.y+c.z+c.w;
  float q = a.x*a.x+a.y*a.y+a.z*a.z+a.w*a.w + c.x*c.x+c.y*c.y+c.z*c.z+c.w*c.w;
  s = wred_sum(s); q = wred_sum(q);
  float mean = s*(1.f/512.f);
  float var  = q*(1.f/512.f) - mean*mean;
  float inv  = rsqrtf(var + 1e-5f);
  const float4* wp = (const float4*)(w + lane*8);
  const float4* bp = (const float4*)(bb + lane*8);
  float4 w0 = wp[0], w1 = wp[1], b0 = bp[0], b1 = bp[1];
  float o[8];
  o[0] = (a.x-mean)*inv*w0.x + b0.x; o[1] = (a.y-mean)*inv*w0.y + b0.y;
  o[2] = (a.z-mean)*inv*w0.z + b0.z; o[3] = (a.w-mean)*inv*w0.w + b0.w;
  o[4] = (c.x-mean)*inv*w1.x + b1.x; o[5] = (c.y-mean)*inv*w1.y + b1.y;
  o[6] = (c.z-mean)*inv*w1.z + b1.z; o[7] = (c.w-mean)*inv*w1.w + b1.w;
  *(uint4*)(h2 + (long)tok*512 + lane*8) =
    make_uint4(pk2(o[0],o[1]), pk2(o[2],o[3]), pk2(o[4],o[5]), pk2(o[6],o[7]));
  float lg[8];
#pragma unroll
  for(int e=0;e<8;e++){
    const float4* gr = (const float4*)(gw + e*512 + lane*8);
    float4 g0 = gr[0], g1 = gr[1];
    float d = o[0]*g0.x + o[1]*g0.y + o[2]*g0.z + o[3]*g0.w
            + o[4]*g1.x + o[5]*g1.y + o[6]*g1.z + o[7]*g1.w;
    lg[e] = wred_sum(d);
  }
  if (lane == 0){
    float mx = lg[0];
#pragma unroll
    for(int e=1;e<8;e++) mx = fmaxf(mx, lg[e]);
    float pr[8];
#pragma unroll
    for(int e=0;e<8;e++) pr[e] = expf(lg[e]-mx);
    int e0 = 0; float p0 = pr[0];
#pragma unroll
    for(int e=1;e<8;e++) if (pr[e] > p0){ p0 = pr[e]; e0 = e; }
    int e1 = -1; float p1 = -1.f;
#pragma unroll
    for(int e=0;e<8;e++) if (e != e0 && pr[e] > p1){ p1 = pr[e]; e1 = e; }
    float invp = 1.f/(p0+p1);
    tok_e[2*tok] = e0; tok_e[2*tok+1] = e1;
    tok_w[2*tok] = p0*invp; tok_w[2*tok+1] = p1*invp;
  }
}

// ---------------------------------------------------------------------------
// Single-block planner + scatter: LDS-atomic histogram, offsets, two block
// tables (BM=128 for FFN1, BM=64 for FFN2), aux, and compaction scatter.
// ---------------------------------------------------------------------------
__global__ __launch_bounds__(1024)
void plan_scatter_k(const int* __restrict__ tok_e, const float* __restrict__ tok_w,
                    int* __restrict__ offs, int* __restrict__ cnts, float* __restrict__ aux,
                    int* __restrict__ btab, int* __restrict__ btab64,
                    int* __restrict__ rowtok, float* __restrict__ roww, int* __restrict__ rowof)
{
  __shared__ int hist[8];
  __shared__ int offsS[8];
  __shared__ int base[8];
  const int t = threadIdx.x;
  if (t < 8) hist[t] = 0;
  __syncthreads();
  int e[8]; float w[8];
#pragma unroll
  for (int i=0;i<8;i++){
    e[i] = tok_e[t + i*1024];
    w[i] = tok_w[t + i*1024];
    atomicAdd(&hist[e[i]], 1);
  }
  __syncthreads();
  if (t == 0){
    int o = 0, idx = 0, idx2 = 0; float a = 0.f;
    for (int ee=0; ee<8; ee++){
      offsS[ee] = o;
      int c = hist[ee];
      o += c;
      float u = (float)c*(1.f/4096.f) - 0.125f;
      a += u*u;
      int nb = (c + 127) >> 7;
      for (int j=0;j<nb;j++) btab[idx++] = (ee<<8)|j;
      int nb2 = (c + 63) >> 6;
      for (int j=0;j<nb2;j++) btab64[idx2++] = (ee<<8)|j;
    }
    while (idx < 80) btab[idx++] = -1;
    while (idx2 < 144) btab64[idx2++] = -1;
    *aux += a*(1.f/8.f);
  }
  __syncthreads();
  if (t < 8){
    cnts[t] = hist[t];
    offs[t] = offsS[t];
    base[t] = offsS[t];
  }
  __syncthreads();
#pragma unroll
  for (int i=0;i<8;i++){
    int pos = atomicAdd(&base[e[i]], 1);   // LDS atomic
    int gi = t + i*1024;
    rowtok[pos] = gi>>1;
    roww[pos] = w[i];
    rowof[gi] = pos;
  }
}

// Fused MoE combine + LN(mln) -> x, PLUS second LN (next layer's LN1, or the
// head's final LN) computed in-register from the just-built x. Eliminates the
// standalone ln_w launch + 12MB re-read per layer.
template<bool OUT2_BF16>
__global__ __launch_bounds__(256)
void ln_moe_k(const float* __restrict__ eout, const int* __restrict__ rowof,
              const float* __restrict__ roww, const float* __restrict__ mask,
              const unsigned short* __restrict__ h2,
              const float* __restrict__ w, const float* __restrict__ bb,
              float* __restrict__ outp,
              const float* __restrict__ w2, const float* __restrict__ b2,
              void* __restrict__ out2)
{
  int tok = blockIdx.x*4 + (threadIdx.x>>6), lane = threadIdx.x&63;
  int r0 = rowof[2*tok], r1 = rowof[2*tok+1];
  float w0w = roww[r0], w1w = roww[r1], mk = mask[tok];
  const float4* ap = (const float4*)(eout + (long)r0*512 + lane*8);
  const float4* bp2 = (const float4*)(eout + (long)r1*512 + lane*8);
  float4 a0 = ap[0], a1 = ap[1], c0 = bp2[0], c1 = bp2[1];
  uint4 hu = *(const uint4*)(h2 + (long)tok*512 + lane*8);
  const unsigned short* hh = (const unsigned short*)&hu;
  float v[8];
  v[0] = bf2f(hh[0]) + (a0.x*w0w + c0.x*w1w)*mk;
  v[1] = bf2f(hh[1]) + (a0.y*w0w + c0.y*w1w)*mk;
  v[2] = bf2f(hh[2]) + (a0.z*w0w + c0.z*w1w)*mk;
  v[3] = bf2f(hh[3]) + (a0.w*w0w + c0.w*w1w)*mk;
  v[4] = bf2f(hh[4]) + (a1.x*w0w + c1.x*w1w)*mk;
  v[5] = bf2f(hh[5]) + (a1.y*w0w + c1.y*w1w)*mk;
  v[6] = bf2f(hh[6]) + (a1.z*w0w + c1.z*w1w)*mk;
  v[7] = bf2f(hh[7]) + (a1.w*w0w + c1.w*w1w)*mk;
  float s = 0.f, q = 0.f;
#pragma unroll
  for(int i=0;i<8;i++){ s += v[i]; q += v[i]*v[i]; }
  s = wred_sum(s); q = wred_sum(q);
  float mean = s*(1.f/512.f);
  float var  = q*(1.f/512.f) - mean*mean;
  float inv  = rsqrtf(var + 1e-5f);
  const float4* wp = (const float4*)(w + lane*8);
  const float4* bpp = (const float4*)(bb + lane*8);
  float4 w0 = wp[0], w1 = wp[1], b0 = bpp[0], b1 = bpp[1];
  float wv[8] = {w0.x,w0.y,w0.z,w0.w,w1.x,w1.y,w1.z,w1.w};
  float bv[8] = {b0.x,b0.y,b0.z,b0.w,b1.x,b1.y,b1.z,b1.w};
  float o[8];
#pragma unroll
  for(int i=0;i<8;i++) o[i] = (v[i]-mean)*inv*wv[i]+bv[i];
  float4* op = (float4*)(outp + (long)tok*512 + lane*8);
  op[0] = make_float4(o[0], o[1], o[2], o[3]);
  op[1] = make_float4(o[4], o[5], o[6], o[7]);
  // second LN over o (the new x)
  float s2 = 0.f, q2 = 0.f;
#pragma unroll
  for(int i=0;i<8;i++){ s2 += o[i]; q2 += o[i]*o[i]; }
  s2 = wred_sum(s2); q2 = wred_sum(q2);
  float mean2 = s2*(1.f/512.f);
  float var2  = q2*(1.f/512.f) - mean2*mean2;
  float inv2  = rsqrtf(var2 + 1e-5f);
  const float4* wp2 = (const float4*)(w2 + lane*8);
  const float4* bp3 = (const float4*)(b2 + lane*8);
  float4 x0 = wp2[0], x1 = wp2[1], y0 = bp3[0], y1 = bp3[1];
  float wv2[8] = {x0.x,x0.y,x0.z,x0.w,x1.x,x1.y,x1.z,x1.w};
  float bv2[8] = {y0.x,y0.y,y0.z,y0.w,y1.x,y1.y,y1.z,y1.w};
  float o2[8];
#pragma unroll
  for(int i=0;i<8;i++) o2[i] = (o[i]-mean2)*inv2*wv2[i]+bv2[i];
  if constexpr (OUT2_BF16){
    *(uint4*)((unsigned short*)out2 + (long)tok*512 + lane*8) =
      make_uint4(pk2(o2[0],o2[1]), pk2(o2[2],o2[3]), pk2(o2[4],o2[5]), pk2(o2[6],o2[7]));
  } else {
    float4* op2 = (float4*)((float*)out2 + (long)tok*512 + lane*8);
    op2[0] = make_float4(o2[0], o2[1], o2[2], o2[3]);
    op2[1] = make_float4(o2[4], o2[5], o2[6], o2[7]);
  }
}

// Build Vt[bh][d][k] bf16 from qkv V slice; grid (4,32), 4 chunks per block
__global__ __launch_bounds__(256)
void vt_k(const unsigned short* __restrict__ qkvb, unsigned short* __restrict__ Vt)
{
  __shared__ unsigned short tile[64][80];
  int z = blockIdx.y, b = z>>3, h = z&7;
  int t = threadIdx.x;
  int kk = t>>2, dd = (t&3)*16;
  int dd2 = t>>2, kk2 = (t&3)*16;
  for (int c = 0; c < 4; ++c){
    int k0 = (blockIdx.x*4 + c)*64;
    const unsigned short* p = qkvb + ((long)(b*1024 + k0 + kk))*1536 + 1024 + h*64 + dd;
    uint4 u0 = *(const uint4*)p, u1 = *(const uint4*)(p+8);
    __syncthreads();
    *(uint4*)&tile[kk][dd] = u0;
    *(uint4*)&tile[kk][dd+8] = u1;
    __syncthreads();
    uint4 o0, o1;
    unsigned short* s0 = (unsigned short*)&o0;
    unsigned short* s1 = (unsigned short*)&o1;
#pragma unroll
    for(int j=0;j<8;j++){ s0[j] = tile[kk2+j][dd2]; s1[j] = tile[kk2+8+j][dd2]; }
    unsigned short* o = Vt + (long)z*65536 + (long)dd2*1024 + k0 + kk2;
    *(uint4*)o = o0; *(uint4*)(o+8) = o1;
  }
}

// fp32 (R,C) -> bf16 (C,R), z-loop of ZL
__global__ __launch_bounds__(256)
void transpose_cast_k(const float* __restrict__ in, unsigned short* __restrict__ outp,
                      int R, int C, int ZL)
{
  __shared__ float tile[64][65];
  int t = threadIdx.x;
  int rr = t>>2, cc = (t&3)*16;
  int cc2 = t>>2, rr2 = (t&3)*16;
  int c0 = blockIdx.x*64, r0 = blockIdx.y*64;
  for (int zi = 0; zi < ZL; ++zi){
    long zoff = (long)(blockIdx.z*ZL + zi) * R * C;
    const float* pin = in + zoff + (long)(r0+rr)*C + c0 + cc;
    float4 v0=*(const float4*)pin, v1=*(const float4*)(pin+4), v2=*(const float4*)(pin+8), v3=*(const float4*)(pin+12);
    __syncthreads();
    tile[rr][cc+0]=v0.x; tile[rr][cc+1]=v0.y; tile[rr][cc+2]=v0.z; tile[rr][cc+3]=v0.w;
    tile[rr][cc+4]=v1.x; tile[rr][cc+5]=v1.y; tile[rr][cc+6]=v1.z; tile[rr][cc+7]=v1.w;
    tile[rr][cc+8]=v2.x; tile[rr][cc+9]=v2.y; tile[rr][cc+10]=v2.z; tile[rr][cc+11]=v2.w;
    tile[rr][cc+12]=v3.x; tile[rr][cc+13]=v3.y; tile[rr][cc+14]=v3.z; tile[rr][cc+15]=v3.w;
    __syncthreads();
    unsigned tmp[8];
#pragma unroll
    for(int jj=0;jj<8;jj++)
      tmp[jj] = pk2(tile[rr2+2*jj][cc2], tile[rr2+2*jj+1][cc2]);
    uint4* dst = (uint4*)(outp + zoff + (long)(c0+cc2)*R + r0 + rr2);
    dst[0] = make_uint4(tmp[0],tmp[1],tmp[2],tmp[3]);
    dst[1] = make_uint4(tmp[4],tmp[5],tmp[6],tmp[7]);
  }
}

// fp32 -> bf16, grid-stride
__global__ __launch_bounds__(256)
void cast_bf16_k(const float* __restrict__ in, unsigned short* __restrict__ outp, int n8)
{
  for (int i = blockIdx.x*256 + threadIdx.x; i < n8; i += gridDim.x*256){
    const float4* p = (const float4*)(in + (long)i*8);
    float4 a = p[0], b = p[1];
    *(uint4*)(outp + (long)i*8) = make_uint4(pk2(a.x,a.y), pk2(a.z,a.w), pk2(b.x,b.y), pk2(b.z,b.w));
  }
}

// masked-sum partial pooling, NO atomics: grid (4,8) -> 8 partials per batch
__global__ __launch_bounds__(256)
void pool2_k(const float* __restrict__ h, const float* __restrict__ mask, float* __restrict__ pooled)
{
  int b = blockIdx.x, sc = blockIdx.y, t = threadIdx.x;
  float a0 = 0.f, a1 = 0.f;
  const float* mb = mask + b*1024 + sc*128;
  const float* hbase = h + ((long)b*1024 + sc*128)*512;
  for (int s = 0; s < 128; ++s){
    float mk = mb[s];
    const float* r = hbase + (long)s*512;
    a0 += r[t]*mk; a1 += r[t+256]*mk;
  }
  pooled[((b*8 + sc)*512) + t] = a0;
  pooled[((b*8 + sc)*512) + t + 256] = a1;
}

__global__ __launch_bounds__(256)
void head_final_k(const float* __restrict__ pooled, const float* __restrict__ mask,
                  const float* __restrict__ pool_w, const float* __restrict__ pool_b,
                  const float* __restrict__ cls_w, const float* __restrict__ cls_b,
                  const float* __restrict__ cf_w1, const float* __restrict__ cf_b1,
                  const float* __restrict__ cf_w2, const float* __restrict__ cf_b2,
                  const float* __restrict__ aux, float* __restrict__ out)
{
  int b = blockIdx.x, t = threadIdx.x, wid = t>>6, lane = t&63;
  __shared__ __align__(16) float pld[512];
  __shared__ __align__(16) float p2[512];
  __shared__ float red[4];
  float ds = 0.f;
  for(int s=t; s<1024; s+=256) ds += mask[b*1024 + s];
  ds = wred_sum(ds);
  if (lane==0) red[wid] = ds;
  __syncthreads();
  float denom = fmaxf(red[0]+red[1]+red[2]+red[3], 1e-9f);
  float s0 = 0.f, s1 = 0.f;
#pragma unroll
  for(int sc=0;sc<8;sc++){
    s0 += pooled[((b*8+sc)*512) + t];
    s1 += pooled[((b*8+sc)*512) + t + 256];
  }
  pld[t]     = s0/denom;
  pld[t+256] = s1/denom;
  __syncthreads();
#pragma unroll
  for(int jj=0;jj<2;jj++){
    int j = t + jj*256;
    const float4* wr = (const float4*)(pool_w + (long)j*512);
    float acc = 0.f;
    for(int i=0;i<128;i++){
      float4 w4 = wr[i]; float4 x4 = ((const float4*)pld)[i];
      acc += w4.x*x4.x + w4.y*x4.y + w4.z*x4.z + w4.w*x4.w;
    }
    p2[j] = tanhf(acc + pool_b[j]);
  }
  __syncthreads();
  if (t < 4){
    const float4* wr = (const float4*)(cls_w + (long)t*512);
    float acc = 0.f;
    for(int i=0;i<128;i++){
      float4 w4 = wr[i]; float4 x4 = ((const float4*)p2)[i];
      acc += w4.x*x4.x + w4.y*x4.y + w4.z*x4.z + w4.w*x4.w;
    }
    out[b*4 + t] = acc + cls_b[t];
  }
  {
    const float4* wr = (const float4*)(cf_w1 + (long)t*512);
    float acc = 0.f;
    for(int i=0;i<128;i++){
      float4 w4 = wr[i]; float4 x4 = ((const float4*)p2)[i];
      acc += w4.x*x4.x + w4.y*x4.y + w4.z*x4.z + w4.w*x4.w;
    }
    acc = fmaxf(acc + cf_b1[t], 0.f) * cf_w2[t];
    acc = wred_sum(acc);
    __syncthreads();
    if (lane==0) red[wid] = acc;
    __syncthreads();
    if (t == 0){
      float sum = red[0]+red[1]+red[2]+red[3];
      out[17 + b] = 1.f/(1.f + expf(-(sum + cf_b2[0])));
    }
  }
  if (b == 0 && t == 0) out[16] = aux[0]*0.25f;
}

// ---------------------------------------------------------------------------
extern "C" void kernel_launch(void* const* d_in, const int* in_sizes, int n_in,
                              void* d_out, int out_size, void* d_ws, size_t ws_size,
                              hipStream_t stream)
{
  (void)in_sizes; (void)n_in; (void)out_size;
  const float* emb    = (const float*)d_in[0];
  const float* mask   = (const float*)d_in[1];
  const float* in_w   = (const float*)d_in[2];
  const float* in_b   = (const float*)d_in[3];
  const float* out_w  = (const float*)d_in[4];
  const float* out_b  = (const float*)d_in[5];
  const float* ln1_w  = (const float*)d_in[6];
  const float* ln1_b  = (const float*)d_in[7];
  const float* ln2_w  = (const float*)d_in[8];
  const float* ln2_b  = (const float*)d_in[9];
  const float* gate_w = (const float*)d_in[10];
  const float* e_w1   = (const float*)d_in[11];
  const float* e_b1   = (const float*)d_in[12];
  const float* e_w2   = (const float*)d_in[13];
  const float* e_b2   = (const float*)d_in[14];
  const float* mln_w  = (const float*)d_in[15];
  const float* mln_b  = (const float*)d_in[16];
  const float* fln_w  = (const float*)d_in[17];
  const float* fln_b  = (const float*)d_in[18];
  const float* pool_w = (const float*)d_in[19];
  const float* pool_b = (const float*)d_in[20];
  const float* cls_w  = (const float*)d_in[21];
  const float* cls_b  = (const float*)d_in[22];
  const float* cf_w1  = (const float*)d_in[23];
  const float* cf_b1  = (const float*)d_in[24];
  const float* cf_w2  = (const float*)d_in[25];
  const float* cf_b2  = (const float*)d_in[26];
  float* out = (float*)d_out;
  char* ws = (char*)d_ws;

  const size_t MiB = 1024*1024;
  if (ws_size < 218*MiB) return;

  // Workspace layout
  float*          x     = (float*)(ws + 0*MiB);             // 8 MiB fp32
  unsigned short* hb    = (unsigned short*)(ws + 8*MiB);    // 4 MiB bf16
  unsigned short* qkvb  = (unsigned short*)(ws + 12*MiB);   // 12 MiB bf16
  unsigned short* ctx   = (unsigned short*)(ws + 24*MiB);   // 4 MiB bf16
  unsigned short* Vt    = (unsigned short*)(ws + 28*MiB);   // 4 MiB bf16
  unsigned short* mid   = (unsigned short*)(ws + 32*MiB);   // 32 MiB bf16
  float*          eout  = (float*)(ws + 64*MiB);            // 16 MiB fp32
  float*          fout  = (float*)(ws + 64*MiB);            //   (reuse, head)
  unsigned short* w1t   = (unsigned short*)(ws + 80*MiB);   // 64 MiB bf16
  unsigned short* w2t   = (unsigned short*)(ws + 144*MiB);  // 64 MiB bf16
  unsigned short* inwb  = (unsigned short*)(ws + 208*MiB);  // 6 MiB bf16
  unsigned short* outwb = (unsigned short*)(ws + 214*MiB);  // 2 MiB bf16
  char* misc = ws + 216*MiB;
  int*   counts  = (int*)(misc + 0);
  int*   offs    = (int*)(misc + 64);
  float* aux     = (float*)(misc + 128);
  int*   btab    = (int*)(misc + 256);       // 80 ints
  int*   btab64  = (int*)(misc + 1024);      // 144 ints
  float* pooled  = (float*)(misc + 4096);    // 64 KiB
  int*   tok_e   = (int*)(misc + 81920);
  float* tok_w   = (float*)(misc + 114688);
  int*   rowtok  = (int*)(misc + 147456);
  float* roww    = (float*)(misc + 180224);
  int*   rowof   = (int*)(misc + 212992);

  hipMemcpyAsync(x, emb, (size_t)T_*D_*4, hipMemcpyDeviceToDevice, stream);
  hipMemsetAsync(aux, 0, 4, stream);
  // weight prep
  cast_bf16_k<<<512, 256, 0, stream>>>(in_w, inwb, L_*3*D_*D_/8);
  cast_bf16_k<<<256, 256, 0, stream>>>(out_w, outwb, L_*D_*D_/8);
  transpose_cast_k<<<dim3(I_/64, D_/64, 4), 256, 0, stream>>>(e_w1, w1t, D_, I_, 8);
  transpose_cast_k<<<dim3(D_/64, I_/64, 4), 256, 0, stream>>>(e_w2, w2t, I_, D_, 8);

  // layer-0 LN1 (reads emb directly; x copy proceeds in parallel)
  ln_w_k<true><<<T_/4, 256, 0, stream>>>(emb, ln1_w, ln1_b, hb);

  for (int l=0; l<L_; l++){
    const float* inbl  = in_b  + (size_t)l*3*D_;
    const float* outbl = out_b + (size_t)l*D_;
    const float* gwl   = gate_w + (size_t)l*E_*D_;
    const float* eb1l  = e_b1 + (size_t)l*E_*I_;
    const float* eb2l  = e_b2 + (size_t)l*E_*D_;
    const unsigned short* inwbl  = inwb + (size_t)l*3*D_*D_;
    const unsigned short* outwbl = outwb + (size_t)l*D_*D_;
    const unsigned short* w1tl = w1t + (size_t)l*E_*I_*D_;
    const unsigned short* w2tl = w2t + (size_t)l*E_*D_*I_;

    // qkv = h @ in_w^T + in_b -> bf16   (64x128: 768 blocks, nby=12)
    gemm_k<64,128,false,false,true,0,false><<<dim3(768,1,1), 512, 0, stream>>>(
      hb, inwbl, qkvb, inbl, nullptr, T_, 3*D_, D_, D_, D_, 3*D_,
      1, 0,0,0,0,0,0, 1.f, nullptr, nullptr, nullptr, nullptr, 0, 0, 12);
    vt_k<<<dim3(4,32), 256, 0, stream>>>(qkvb, Vt);
    // fused attention -> ctx (B,S,512) bf16
    flash_k<<<dim3(16,32), 256, 0, stream>>>(qkvb, Vt, ctx);
    // x = x + ctx @ out_w^T + out_b  (fp32)   (64x64: 512 blocks, nby=8)
    gemm_k<64,64,false,false,false,0,true><<<dim3(512,1,1), 512, 0, stream>>>(
      ctx, outwbl, x, outbl, x, T_, D_, D_, D_, D_, D_,
      1, 0,0,0,0,0,0, 1.f, nullptr, nullptr, nullptr, nullptr, 0, 0, 8);
    // h2 = LN2(x) -> bf16, + routing (no atomics)
    ln2route_k<<<T_/4, 256, 0, stream>>>(x, ln2_w + (size_t)l*D_, ln2_b + (size_t)l*D_,
                                         hb, gwl, tok_e, tok_w);
    // plan + scatter, single block, LDS atomics only
    plan_scatter_k<<<1, 1024, 0, stream>>>(tok_e, tok_w, offs, counts, aux, btab, btab64,
                                           rowtok, roww, rowof);
    // FFN1: mid = gelu(gather(h2) @ w1^T + b1) -> bf16   (BM=128,BN=64: 2272 blocks, nby=32)
    gemm_k<128,64,true,true,true,1,false><<<dim3(2272,1,1), 512, 0, stream>>>(
      hb, w1tl, mid, eb1l, nullptr, 2*T_, I_, D_, D_, D_, I_,
      1, 0,0,0,0,0,0, 1.f, offs, counts, rowtok, btab, (long)I_*D_, I_, 32);
    // FFN2: eout = mid @ w2^T + b2 -> fp32   (BM=64, 544 blocks, nby=4)
    gemm_k<64,128,true,false,false,0,false><<<dim3(544,1,1), 512, 0, stream>>>(
      mid, w2tl, eout, eb2l, nullptr, 2*T_, D_, I_, I_, I_, D_,
      1, 0,0,0,0,0,0, 1.f, offs, counts, nullptr, btab64, (long)D_*I_, D_, 4);
    // x = LN(h2 + combine(eout)); fused second LN -> next LN1 (bf16 hb) or final LN (fp32 fout)
    if (l < 3){
      ln_moe_k<true><<<T_/4, 256, 0, stream>>>(eout, rowof, roww, mask, hb,
                                               mln_w + (size_t)l*D_, mln_b + (size_t)l*D_, x,
                                               ln1_w + (size_t)(l+1)*D_, ln1_b + (size_t)(l+1)*D_,
                                               (void*)hb);
    } else {
      ln_moe_k<false><<<T_/4, 256, 0, stream>>>(eout, rowof, roww, mask, hb,
                                                mln_w + (size_t)l*D_, mln_b + (size_t)l*D_, x,
                                                fln_w, fln_b, (void*)fout);
    }
  }
  // head
  pool2_k<<<dim3(4,8), 256, 0, stream>>>(fout, mask, pooled);
  head_final_k<<<4, 256, 0, stream>>>(pooled, mask, pool_w, pool_b, cls_w, cls_b,
                                      cf_w1, cf_b1, cf_w2, cf_b2, aux, out);
}

// Round 9
// 1257.382 us; speedup vs baseline: 1.1952x; 1.0289x over previous
//
#include <hip/hip_runtime.h>
#include <math.h>

// Problem constants
#define B_ 4
#define S_ 1024
#define D_ 512
#define H_ 8
#define DH_ 64
#define I_ 2048
#define E_ 8
#define L_ 4
#define T_ 4096   // B*S

using bf16x8 = __attribute__((ext_vector_type(8))) __bf16;
using f32x4  = __attribute__((ext_vector_type(4))) float;

typedef __attribute__((address_space(1))) const void gvoid;
typedef __attribute__((address_space(3))) void lvoid;
__device__ __forceinline__ void gl_lds16(const void* g, void* l){
  __builtin_amdgcn_global_load_lds((gvoid*)g, (lvoid*)l, 16, 0, 0);
}

__device__ __forceinline__ float wred_sum(float v){
#pragma unroll
  for(int m=32;m>0;m>>=1) v += __shfl_xor(v, m, 64);
  return v;
}
__device__ __forceinline__ unsigned short f2bf(float f){
  unsigned x = __float_as_uint(f);
  unsigned r = (x + 0x7FFFu + ((x>>16)&1u)) >> 16;
  return (unsigned short)r;
}
__device__ __forceinline__ float bf2f(unsigned short u){
  return __uint_as_float(((unsigned)u)<<16);
}
__device__ __forceinline__ unsigned pk2(float a, float b){
  return (unsigned)f2bf(a) | ((unsigned)f2bf(b)<<16);
}

// ---------------------------------------------------------------------------
// bf16 MFMA GEMM. NT: C[m,n] = sum_k A[m,k]*B[n,k].
// 512 threads = 8 waves in 2x4 (wy=wid>>2, wx=wid&3). Occupancy is the
// validated lever (R5: 4->8 waves = -9% total).
// BK=64, double-buffered LDS, phase-interleaved schedule:
//   per K-step: [vmcnt(0); s_barrier] then
//     phase0: issue stage A(t+1) | ds_read kk0 | setprio(1) MFMA kk0
//     phase1: issue stage B(t+1) | ds_read kk1 | setprio(1) MFMA kk1
// ONE barrier per K-step (top barrier protects both buffers).
// T2 bank-conflict fix (verified 6.78M->0): LDS dest linear, global SOURCE
// col unit ^= (row&7); fragment reads XOR the same involution.
// 1-D grid with XCD-chunked bijective swizzle (gridDim.x % 8 == 0).
// MOE: block table btab[bx] = (e<<8)|mblk, -1 = dead. Optional row gather.
// VT (QKV only): blocks with n0>=1024 hold the V slice -> write transposed
// directly to Vt[z=b*8+h][d][k] (replaces the vt_k copy kernel; bit-identical).
// ---------------------------------------------------------------------------
template<int BM, int BN, bool MOE, bool GATHER, bool OUT_BF16, int ACT, bool ADD_IN, bool VT>
__global__ __launch_bounds__(512)
void gemm_k(const unsigned short* __restrict__ A, const unsigned short* __restrict__ Bv,
            void* Cp, const float* __restrict__ bias, const float* addin,
            int M, int N, int K, int lda, int ldb, int ldc,
            int hdiv, long sAb, long sAh, long sBb, long sBh, long sCb, long sCh,
            float scale,
            const int* __restrict__ moff, const int* __restrict__ mcnt,
            const int* __restrict__ rowtok, const int* __restrict__ btab,
            long sBe, int biasStride, int nby, unsigned short* __restrict__ vtp)
{
  constexpr int BK = 64;
  constexpr int WM = BM/2, WN = BN/4, FM = WM/16, FNN = WN/16;
  constexpr int RPC = 64;            // rows covered per block-wide gl_lds16 call (512 thr / 8 per row)
  constexpr int SHPC = 4096;         // shorts per call (512 thr * 8)
  constexpr int NA = BM/RPC, NB = BN/RPC;
  __shared__ unsigned short As[2*BM*BK];
  __shared__ unsigned short Bs[2*BN*BK];

  const int tid = threadIdx.x, wid = tid>>6, lane = tid&63;
  const int wy = wid>>2, wx = wid&3, ln16 = lane&15;

  // XCD-chunked bijective swizzle: consecutive hw ids round-robin XCDs;
  // remap so each XCD owns a contiguous chunk of (bx,by) space, by innermost.
  const int nwg = gridDim.x, cpx = nwg >> 3;
  const int lin = blockIdx.x;
  const int wg  = (lin & 7)*cpx + (lin >> 3);
  const int bxi = wg / nby, byi = wg % nby;

  int m0 = bxi*BM;
  const int n0 = byi*BN;

  float* Cf = nullptr; unsigned short* Ch = nullptr;
  const float* biasp = bias;
  const unsigned short* Bp = Bv;
  int seg = 0, cnt = M;

  if constexpr (MOE){
    int tv = btab[bxi];
    if (tv < 0) return;
    int e = tv>>8;
    m0 = (tv&255)*BM;
    seg = moff[e]; cnt = mcnt[e];
    Bp = Bv + (long)e*sBe;
    if constexpr (OUT_BF16) Ch = (unsigned short*)Cp; else Cf = (float*)Cp;
    if (biasp) biasp += (long)e*biasStride;
  } else {
    int z = blockIdx.z, zb = z/hdiv, zh = z%hdiv;
    A  += (long)zb*sAb + (long)zh*sAh;
    Bp += (long)zb*sBb + (long)zh*sBh;
    long coff = (long)zb*sCb + (long)zh*sCh;
    if constexpr (OUT_BF16) Ch = (unsigned short*)Cp + coff; else Cf = ((float*)Cp) + coff;
    if constexpr (ADD_IN) addin += coff;
  }

  // staging geometry: call j covers rows j*RPC + tid/8, col-unit (tid&7) of 8x16B.
  // SOURCE-side XOR swizzle (T2): unit ^= (row&7); LDS dest stays linear so
  // gl_lds is legal; reads undo the same involution.
  const int srow = tid >> 3;          // 8 lanes per row
  const int scol = ((tid & 7) ^ (srow & 7)) * 8;
  long ga[NA], gb[NB];
#pragma unroll
  for (int j=0; j<NA; j++){
    int r = m0 + j*RPC + srow;
    if constexpr (MOE){
      r = min(r, cnt-1);
      long gr = GATHER ? (long)rowtok[seg+r] : (long)(seg+r);
      ga[j] = gr*lda + scol;
    } else {
      ga[j] = (long)min(r, M-1)*lda + scol;
    }
  }
#pragma unroll
  for (int j=0; j<NB; j++){
    int bn = min(n0 + j*RPC + srow, N-1);
    gb[j] = (long)bn*ldb + scol;
  }

  f32x4 acc[FM][FNN];
#pragma unroll
  for(int i=0;i<FM;i++)
#pragma unroll
    for(int j=0;j<FNN;j++){ f32x4 z = {0.f,0.f,0.f,0.f}; acc[i][j] = z; }

  const int nt = K/BK;
  // read-side swizzle: row&7 == ln16&7 for all fragment rows (WM,WN mult of 8/16)
  const int rsw = ln16 & 7;
  const int u0 = ((lane>>4)     ^ rsw) * 8;   // kk=0 unit offset (elements)
  const int u1 = ((4+(lane>>4)) ^ rsw) * 8;   // kk=1 unit offset

  // prologue: stage tile 0 into buffer 0
#pragma unroll
  for (int j=0; j<NA; j++) gl_lds16(A + ga[j], As + j*SHPC + wid*512);
#pragma unroll
  for (int j=0; j<NB; j++) gl_lds16(Bp + gb[j], Bs + j*SHPC + wid*512);

  for (int t = 0; t < nt; ++t){
    const int cb = t & 1;
    const unsigned short* Ab = As + cb*BM*BK;
    const unsigned short* Bb = Bs + cb*BN*BK;
    unsigned short* An = As + (cb^1)*BM*BK;
    unsigned short* Bn = Bs + (cb^1)*BN*BK;
    const bool pf = (t+1 < nt);
    const long k0n = (long)(t+1)*BK;

    asm volatile("s_waitcnt vmcnt(0)" ::: "memory");  // this tile's loads landed
    __builtin_amdgcn_s_barrier();                     // tile t ready; prev-tile reads done by all waves
    __builtin_amdgcn_sched_barrier(0);                // no ds_read/gl_lds hoists above

    // ---- phase 0: stage A(t+1) | ds_read kk0 | MFMA kk0
    if (pf){
#pragma unroll
      for (int j=0; j<NA; j++) gl_lds16(A + ga[j] + k0n, An + j*SHPC + wid*512);
    }
    {
      bf16x8 fa[FM], fb[FNN];
#pragma unroll
      for(int i=0;i<FM;i++) fa[i] = *(const bf16x8*)&Ab[(wy*WM + i*16 + ln16)*BK + u0];
#pragma unroll
      for(int j=0;j<FNN;j++) fb[j] = *(const bf16x8*)&Bb[(wx*WN + j*16 + ln16)*BK + u0];
      __builtin_amdgcn_s_setprio(1);
#pragma unroll
      for(int i=0;i<FM;i++)
#pragma unroll
        for(int j=0;j<FNN;j++)
          acc[i][j] = __builtin_amdgcn_mfma_f32_16x16x32_bf16(fa[i], fb[j], acc[i][j], 0, 0, 0);
      __builtin_amdgcn_s_setprio(0);
    }
    // ---- phase 1: stage B(t+1) | ds_read kk1 | MFMA kk1
    if (pf){
#pragma unroll
      for (int j=0; j<NB; j++) gl_lds16(Bp + gb[j] + k0n, Bn + j*SHPC + wid*512);
    }
    {
      bf16x8 fa[FM], fb[FNN];
#pragma unroll
      for(int i=0;i<FM;i++) fa[i] = *(const bf16x8*)&Ab[(wy*WM + i*16 + ln16)*BK + u1];
#pragma unroll
      for(int j=0;j<FNN;j++) fb[j] = *(const bf16x8*)&Bb[(wx*WN + j*16 + ln16)*BK + u1];
      __builtin_amdgcn_s_setprio(1);
#pragma unroll
      for(int i=0;i<FM;i++)
#pragma unroll
        for(int j=0;j<FNN;j++)
          acc[i][j] = __builtin_amdgcn_mfma_f32_16x16x32_bf16(fa[i], fb[j], acc[i][j], 0, 0, 0);
      __builtin_amdgcn_s_setprio(0);
    }
  }

  // V-split epilogue (QKV only): n0>=1024 is the V slice; write transposed
  // to Vt[(b*8+h)][d][k]. mbase is 4-aligned in k -> one 8B ushort4 store.
  if constexpr (VT){
    if (n0 >= 1024){
#pragma unroll
      for(int i=0;i<FM;i++){
        int mbase = m0 + wy*WM + i*16 + (lane>>4)*4;
        int bb = mbase >> 10;
        int k4 = mbase & 1023;
#pragma unroll
        for(int j=0;j<FNN;j++){
          int n = n0 + wx*WN + j*16 + ln16;
          float bv = biasp ? biasp[n] : 0.f;
          int hh = (n - 1024) >> 6, dd = (n - 1024) & 63;
          f32x4 v = acc[i][j];
          ushort4 pkv;
          pkv.x = f2bf(v[0]*scale + bv);
          pkv.y = f2bf(v[1]*scale + bv);
          pkv.z = f2bf(v[2]*scale + bv);
          pkv.w = f2bf(v[3]*scale + bv);
          *(ushort4*)(vtp + (long)(bb*8 + hh)*65536 + (long)dd*1024 + k4) = pkv;
        }
      }
      return;
    }
  }

  // epilogue: C[m = quad*4+r][n = lane&15]
#pragma unroll
  for(int i=0;i<FM;i++){
    int mbase = m0 + wy*WM + i*16 + (lane>>4)*4;
#pragma unroll
    for(int j=0;j<FNN;j++){
      int n = n0 + wx*WN + j*16 + ln16;
      float bv = biasp ? biasp[n] : 0.f;
      f32x4 v = acc[i][j];
#pragma unroll
      for(int r=0;r<4;r++){
        int m = mbase + r;
        if (m < cnt){
          float x = v[r]*scale + bv;
          if constexpr (ACT == 1) x = 0.5f*x*(1.f + erff(x*0.70710678118654752f));
          long ci = (long)(MOE ? seg + m : m)*ldc + n;
          if constexpr (ADD_IN) x += addin[ci];
          if constexpr (OUT_BF16) Ch[ci] = f2bf(x);
          else Cf[ci] = x;
        }
      }
    }
  }
}

// ---------------------------------------------------------------------------
// Fused flash attention. grid (S/64, B*H). 4 waves, each owns 16 Q-rows.
// ---------------------------------------------------------------------------
__global__ __launch_bounds__(256)
void flash_k(const unsigned short* __restrict__ qkvb, const unsigned short* __restrict__ Vt,
             unsigned short* __restrict__ ctx)
{
  __shared__ unsigned short Pl[4][16*72];
  const int qt = blockIdx.x, z = blockIdx.y, b = z>>3, h = z&7;
  const int wid = threadIdx.x>>6, lane = threadIdx.x&63;
  const int ln16 = lane&15, g = lane>>4;
  const int q0 = qt*64 + wid*16;
  unsigned short* Pw = &Pl[wid][0];

  const unsigned short* Qp = qkvb + (long)(b*1024 + q0 + ln16)*1536 + h*64 + g*8;
  bf16x8 qf0 = *(const bf16x8*)Qp;
  bf16x8 qf1 = *(const bf16x8*)(Qp + 32);
  const unsigned short* Kbase = qkvb + (long)b*1024*1536 + 512 + h*64 + g*8;
  const unsigned short* Vbase = Vt + (long)z*65536 + g*8;

  float m_s[4], l_s[4];
  f32x4 oacc[4];
#pragma unroll
  for(int r=0;r<4;r++){ m_s[r] = -1e30f; l_s[r] = 0.f; }
#pragma unroll
  for(int j=0;j<4;j++){ f32x4 zz = {0.f,0.f,0.f,0.f}; oacc[j] = zz; }

  for (int t = 0; t < 16; ++t){
    bf16x8 kf[4][2], vf[4][2];
#pragma unroll
    for(int j=0;j<4;j++){
      const unsigned short* kp = Kbase + (long)(t*64 + j*16 + ln16)*1536;
      kf[j][0] = *(const bf16x8*)kp;
      kf[j][1] = *(const bf16x8*)(kp + 32);
      const unsigned short* vp = Vbase + (long)(j*16 + ln16)*1024 + t*64;
      vf[j][0] = *(const bf16x8*)vp;
      vf[j][1] = *(const bf16x8*)(vp + 32);
    }
    f32x4 sacc[4];
#pragma unroll
    for(int j=0;j<4;j++){ f32x4 zz = {0.f,0.f,0.f,0.f}; sacc[j] = zz; }
#pragma unroll
    for(int j=0;j<4;j++){
      sacc[j] = __builtin_amdgcn_mfma_f32_16x16x32_bf16(qf0, kf[j][0], sacc[j], 0,0,0);
      sacc[j] = __builtin_amdgcn_mfma_f32_16x16x32_bf16(qf1, kf[j][1], sacc[j], 0,0,0);
    }
#pragma unroll
    for(int j=0;j<4;j++)
#pragma unroll
      for(int r=0;r<4;r++) sacc[j][r] *= 0.125f;
    float alpha[4];
#pragma unroll
    for(int r=0;r<4;r++){
      float mx = fmaxf(fmaxf(sacc[0][r], sacc[1][r]), fmaxf(sacc[2][r], sacc[3][r]));
#pragma unroll
      for(int m=1;m<16;m<<=1) mx = fmaxf(mx, __shfl_xor(mx, m, 64));
      float mn = fmaxf(m_s[r], mx);
      alpha[r] = __expf(m_s[r] - mn);
      m_s[r] = mn;
    }
#pragma unroll
    for(int j=0;j<4;j++)
#pragma unroll
      for(int r=0;r<4;r++) sacc[j][r] = __expf(sacc[j][r] - m_s[r]);
#pragma unroll
    for(int r=0;r<4;r++){
      float rs = sacc[0][r]+sacc[1][r]+sacc[2][r]+sacc[3][r];
#pragma unroll
      for(int m=1;m<16;m<<=1) rs += __shfl_xor(rs, m, 64);
      l_s[r] = l_s[r]*alpha[r] + rs;
    }
#pragma unroll
    for(int j=0;j<4;j++)
#pragma unroll
      for(int r=0;r<4;r++) oacc[j][r] *= alpha[r];
#pragma unroll
    for(int j=0;j<4;j++)
#pragma unroll
      for(int r=0;r<4;r++)
        Pw[(g*4+r)*72 + j*16 + ln16] = f2bf(sacc[j][r]);
    bf16x8 pf0 = *(const bf16x8*)&Pw[ln16*72 + g*8];
    bf16x8 pf1 = *(const bf16x8*)&Pw[ln16*72 + 32 + g*8];
#pragma unroll
    for(int j=0;j<4;j++){
      oacc[j] = __builtin_amdgcn_mfma_f32_16x16x32_bf16(pf0, vf[j][0], oacc[j], 0,0,0);
      oacc[j] = __builtin_amdgcn_mfma_f32_16x16x32_bf16(pf1, vf[j][1], oacc[j], 0,0,0);
    }
  }
#pragma unroll
  for(int r=0;r<4;r++){
    float inv = 1.f/l_s[r];
    long row = (long)(b*1024 + q0 + g*4 + r)*512 + h*64;
#pragma unroll
    for(int j=0;j<4;j++)
      ctx[row + j*16 + ln16] = f2bf(oacc[j][r]*inv);
  }
}

// ---------------------------------------------------------------------------
// Wave-per-row LayerNorm (D=512): 4 rows/block, no barriers. (layer-0 only)
// ---------------------------------------------------------------------------
template<bool OUT_BF16>
__global__ __launch_bounds__(256)
void ln_w_k(const float* __restrict__ in, const float* __restrict__ w,
            const float* __restrict__ bb, void* __restrict__ outp)
{
  int row = blockIdx.x*4 + (threadIdx.x>>6), lane = threadIdx.x&63;
  const float4* p = (const float4*)(in + (long)row*512 + lane*8);
  float4 a = p[0], c = p[1];
  float s = a.x+a.y+a.z+a.w + c.x+c.y+c.z+c.w;
  float q = a.x*a.x+a.y*a.y+a.z*a.z+a.w*a.w + c.x*c.x+c.y*c.y+c.z*c.z+c.w*c.w;
  s = wred_sum(s); q = wred_sum(q);
  float mean = s*(1.f/512.f);
  float var  = q*(1.f/512.f) - mean*mean;
  float inv  = rsqrtf(var + 1e-5f);
  const float4* wp = (const float4*)(w + lane*8);
  const float4* bp = (const float4*)(bb + lane*8);
  float4 w0 = wp[0], w1 = wp[1], b0 = bp[0], b1 = bp[1];
  float o0 = (a.x-mean)*inv*w0.x + b0.x, o1 = (a.y-mean)*inv*w0.y + b0.y;
  float o2 = (a.z-mean)*inv*w0.z + b0.z, o3 = (a.w-mean)*inv*w0.w + b0.w;
  float o4 = (c.x-mean)*inv*w1.x + b1.x, o5 = (c.y-mean)*inv*w1.y + b1.y;
  float o6 = (c.z-mean)*inv*w1.z + b1.z, o7 = (c.w-mean)*inv*w1.w + b1.w;
  if constexpr (OUT_BF16){
    *(uint4*)((unsigned short*)outp + (long)row*512 + lane*8) =
      make_uint4(pk2(o0,o1), pk2(o2,o3), pk2(o4,o5), pk2(o6,o7));
  } else {
    float4* op = (float4*)((float*)outp + (long)row*512 + lane*8);
    op[0] = make_float4(o0,o1,o2,o3);
    op[1] = make_float4(o4,o5,o6,o7);
  }
}

// LN2 + router fused: h2 = LN(x) (bf16 out) then top-2 gate; NO global atomics.
__global__ __launch_bounds__(256)
void ln2route_k(const float* __restrict__ in, const float* __restrict__ w,
                const float* __restrict__ bb, unsigned short* __restrict__ h2,
                const float* __restrict__ gw,
                int* __restrict__ tok_e, float* __restrict__ tok_w)
{
  int tok = blockIdx.x*4 + (threadIdx.x>>6), lane = threadIdx.x&63;
  const float4* p = (const float4*)(in + (long)tok*512 + lane*8);
  float4 a = p[0], c = p[1];
  float s = a.x+a.y+a.z+a.w + c.x+c.y+c.z+c.w;
  float q = a.x*a.x+a.y*a.y+a.z*a.z+a.w*a.w + c.x*c.x+c.y*c.y+c.z*c.z+c.w*c.w;
  s = wred_sum(s); q = wred_sum(q);
  float mean = s*(1.f/512.f);
  float var  = q*(1.f/512.f) - mean*mean;
  float inv  = rsqrtf(var + 1e-5f);
  const float4* wp = (const float4*)(w + lane*8);
  const float4* bp = (const float4*)(bb + lane*8);
  float4 w0 = wp[0], w1 = wp[1], b0 = bp[0], b1 = bp[1];
  float o[8];
  o[0] = (a.x-mean)*inv*w0.x + b0.x; o[1] = (a.y-mean)*inv*w0.y + b0.y;
  o[2] = (a.z-mean)*inv*w0.z + b0.z; o[3] = (a.w-mean)*inv*w0.w + b0.w;
  o[4] = (c.x-mean)*inv*w1.x + b1.x; o[5] = (c.y-mean)*inv*w1.y + b1.y;
  o[6] = (c.z-mean)*inv*w1.z + b1.z; o[7] = (c.w-mean)*inv*w1.w + b1.w;
  *(uint4*)(h2 + (long)tok*512 + lane*8) =
    make_uint4(pk2(o[0],o[1]), pk2(o[2],o[3]), pk2(o[4],o[5]), pk2(o[6],o[7]));
  float lg[8];
#pragma unroll
  for(int e=0;e<8;e++){
    const float4* gr = (const float4*)(gw + e*512 + lane*8);
    float4 g0 = gr[0], g1 = gr[1];
    float d = o[0]*g0.x + o[1]*g0.y + o[2]*g0.z + o[3]*g0.w
            + o[4]*g1.x + o[5]*g1.y + o[6]*g1.z + o[7]*g1.w;
    lg[e] = wred_sum(d);
  }
  if (lane == 0){
    float mx = lg[0];
#pragma unroll
    for(int e=1;e<8;e++) mx = fmaxf(mx, lg[e]);
    float pr[8];
#pragma unroll
    for(int e=0;e<8;e++) pr[e] = expf(lg[e]-mx);
    int e0 = 0; float p0 = pr[0];
#pragma unroll
    for(int e=1;e<8;e++) if (pr[e] > p0){ p0 = pr[e]; e0 = e; }
    int e1 = -1; float p1 = -1.f;
#pragma unroll
    for(int e=0;e<8;e++) if (e != e0 && pr[e] > p1){ p1 = pr[e]; e1 = e; }
    float invp = 1.f/(p0+p1);
    tok_e[2*tok] = e0; tok_e[2*tok+1] = e1;
    tok_w[2*tok] = p0*invp; tok_w[2*tok+1] = p1*invp;
  }
}

// ---------------------------------------------------------------------------
// Single-block planner + scatter: LDS-atomic histogram, offsets, two block
// tables (BM=128 for FFN1, BM=64 for FFN2), aux, and compaction scatter.
// ---------------------------------------------------------------------------
__global__ __launch_bounds__(1024)
void plan_scatter_k(const int* __restrict__ tok_e, const float* __restrict__ tok_w,
                    int* __restrict__ offs, int* __restrict__ cnts, float* __restrict__ aux,
                    int* __restrict__ btab, int* __restrict__ btab64,
                    int* __restrict__ rowtok, float* __restrict__ roww, int* __restrict__ rowof)
{
  __shared__ int hist[8];
  __shared__ int offsS[8];
  __shared__ int base[8];
  const int t = threadIdx.x;
  if (t < 8) hist[t] = 0;
  __syncthreads();
  int e[8]; float w[8];
#pragma unroll
  for (int i=0;i<8;i++){
    e[i] = tok_e[t + i*1024];
    w[i] = tok_w[t + i*1024];
    atomicAdd(&hist[e[i]], 1);
  }
  __syncthreads();
  if (t == 0){
    int o = 0, idx = 0, idx2 = 0; float a = 0.f;
    for (int ee=0; ee<8; ee++){
      offsS[ee] = o;
      int c = hist[ee];
      o += c;
      float u = (float)c*(1.f/4096.f) - 0.125f;
      a += u*u;
      int nb = (c + 127) >> 7;
      for (int j=0;j<nb;j++) btab[idx++] = (ee<<8)|j;
      int nb2 = (c + 63) >> 6;
      for (int j=0;j<nb2;j++) btab64[idx2++] = (ee<<8)|j;
    }
    while (idx < 80) btab[idx++] = -1;
    while (idx2 < 144) btab64[idx2++] = -1;
    *aux += a*(1.f/8.f);
  }
  __syncthreads();
  if (t < 8){
    cnts[t] = hist[t];
    offs[t] = offsS[t];
    base[t] = offsS[t];
  }
  __syncthreads();
#pragma unroll
  for (int i=0;i<8;i++){
    int pos = atomicAdd(&base[e[i]], 1);   // LDS atomic
    int gi = t + i*1024;
    rowtok[pos] = gi>>1;
    roww[pos] = w[i];
    rowof[gi] = pos;
  }
}

// Fused MoE combine + LN(mln) -> x, PLUS second LN (next layer's LN1, or the
// head's final LN) computed in-register from the just-built x. Eliminates the
// standalone ln_w launch + 12MB re-read per layer.
template<bool OUT2_BF16>
__global__ __launch_bounds__(256)
void ln_moe_k(const float* __restrict__ eout, const int* __restrict__ rowof,
              const float* __restrict__ roww, const float* __restrict__ mask,
              const unsigned short* __restrict__ h2,
              const float* __restrict__ w, const float* __restrict__ bb,
              float* __restrict__ outp,
              const float* __restrict__ w2, const float* __restrict__ b2,
              void* __restrict__ out2)
{
  int tok = blockIdx.x*4 + (threadIdx.x>>6), lane = threadIdx.x&63;
  int r0 = rowof[2*tok], r1 = rowof[2*tok+1];
  float w0w = roww[r0], w1w = roww[r1], mk = mask[tok];
  const float4* ap = (const float4*)(eout + (long)r0*512 + lane*8);
  const float4* bp2 = (const float4*)(eout + (long)r1*512 + lane*8);
  float4 a0 = ap[0], a1 = ap[1], c0 = bp2[0], c1 = bp2[1];
  uint4 hu = *(const uint4*)(h2 + (long)tok*512 + lane*8);
  const unsigned short* hh = (const unsigned short*)&hu;
  float v[8];
  v[0] = bf2f(hh[0]) + (a0.x*w0w + c0.x*w1w)*mk;
  v[1] = bf2f(hh[1]) + (a0.y*w0w + c0.y*w1w)*mk;
  v[2] = bf2f(hh[2]) + (a0.z*w0w + c0.z*w1w)*mk;
  v[3] = bf2f(hh[3]) + (a0.w*w0w + c0.w*w1w)*mk;
  v[4] = bf2f(hh[4]) + (a1.x*w0w + c1.x*w1w)*mk;
  v[5] = bf2f(hh[5]) + (a1.y*w0w + c1.y*w1w)*mk;
  v[6] = bf2f(hh[6]) + (a1.z*w0w + c1.z*w1w)*mk;
  v[7] = bf2f(hh[7]) + (a1.w*w0w + c1.w*w1w)*mk;
  float s = 0.f, q = 0.f;
#pragma unroll
  for(int i=0;i<8;i++){ s += v[i]; q += v[i]*v[i]; }
  s = wred_sum(s); q = wred_sum(q);
  float mean = s*(1.f/512.f);
  float var  = q*(1.f/512.f) - mean*mean;
  float inv  = rsqrtf(var + 1e-5f);
  const float4* wp = (const float4*)(w + lane*8);
  const float4* bpp = (const float4*)(bb + lane*8);
  float4 w0 = wp[0], w1 = wp[1], b0 = bpp[0], b1 = bpp[1];
  float wv[8] = {w0.x,w0.y,w0.z,w0.w,w1.x,w1.y,w1.z,w1.w};
  float bv[8] = {b0.x,b0.y,b0.z,b0.w,b1.x,b1.y,b1.z,b1.w};
  float o[8];
#pragma unroll
  for(int i=0;i<8;i++) o[i] = (v[i]-mean)*inv*wv[i]+bv[i];
  float4* op = (float4*)(outp + (long)tok*512 + lane*8);
  op[0] = make_float4(o[0], o[1], o[2], o[3]);
  op[1] = make_float4(o[4], o[5], o[6], o[7]);
  // second LN over o (the new x)
  float s2 = 0.f, q2 = 0.f;
#pragma unroll
  for(int i=0;i<8;i++){ s2 += o[i]; q2 += o[i]*o[i]; }
  s2 = wred_sum(s2); q2 = wred_sum(q2);
  float mean2 = s2*(1.f/512.f);
  float var2  = q2*(1.f/512.f) - mean2*mean2;
  float inv2  = rsqrtf(var2 + 1e-5f);
  const float4* wp2 = (const float4*)(w2 + lane*8);
  const float4* bp3 = (const float4*)(b2 + lane*8);
  float4 x0 = wp2[0], x1 = wp2[1], y0 = bp3[0], y1 = bp3[1];
  float wv2[8] = {x0.x,x0.y,x0.z,x0.w,x1.x,x1.y,x1.z,x1.w};
  float bv2[8] = {y0.x,y0.y,y0.z,y0.w,y1.x,y1.y,y1.z,y1.w};
  float o2[8];
#pragma unroll
  for(int i=0;i<8;i++) o2[i] = (o[i]-mean2)*inv2*wv2[i]+bv2[i];
  if constexpr (OUT2_BF16){
    *(uint4*)((unsigned short*)out2 + (long)tok*512 + lane*8) =
      make_uint4(pk2(o2[0],o2[1]), pk2(o2[2],o2[3]), pk2(o2[4],o2[5]), pk2(o2[6],o2[7]));
  } else {
    float4* op2 = (float4*)((float*)out2 + (long)tok*512 + lane*8);
    op2[0] = make_float4(o2[0], o2[1], o2[2], o2[3]);
    op2[1] = make_float4(o2[4], o2[5], o2[6], o2[7]);
  }
}

// fp32 (R,C) -> bf16 (C,R), z-loop of ZL
__global__ __launch_bounds__(256)
void transpose_cast_k(const float* __restrict__ in, unsigned short* __restrict__ outp,
                      int R, int C, int ZL)
{
  __shared__ float tile[64][65];
  int t = threadIdx.x;
  int rr = t>>2, cc = (t&3)*16;
  int cc2 = t>>2, rr2 = (t&3)*16;
  int c0 = blockIdx.x*64, r0 = blockIdx.y*64;
  for (int zi = 0; zi < ZL; ++zi){
    long zoff = (long)(blockIdx.z*ZL + zi) * R * C;
    const float* pin = in + zoff + (long)(r0+rr)*C + c0 + cc;
    float4 v0=*(const float4*)pin, v1=*(const float4*)(pin+4), v2=*(const float4*)(pin+8), v3=*(const float4*)(pin+12);
    __syncthreads();
    tile[rr][cc+0]=v0.x; tile[rr][cc+1]=v0.y; tile[rr][cc+2]=v0.z; tile[rr][cc+3]=v0.w;
    tile[rr][cc+4]=v1.x; tile[rr][cc+5]=v1.y; tile[rr][cc+6]=v1.z; tile[rr][cc+7]=v1.w;
    tile[rr][cc+8]=v2.x; tile[rr][cc+9]=v2.y; tile[rr][cc+10]=v2.z; tile[rr][cc+11]=v2.w;
    tile[rr][cc+12]=v3.x; tile[rr][cc+13]=v3.y; tile[rr][cc+14]=v3.z; tile[rr][cc+15]=v3.w;
    __syncthreads();
    unsigned tmp[8];
#pragma unroll
    for(int jj=0;jj<8;jj++)
      tmp[jj] = pk2(tile[rr2+2*jj][cc2], tile[rr2+2*jj+1][cc2]);
    uint4* dst = (uint4*)(outp + zoff + (long)(c0+cc2)*R + r0 + rr2);
    dst[0] = make_uint4(tmp[0],tmp[1],tmp[2],tmp[3]);
    dst[1] = make_uint4(tmp[4],tmp[5],tmp[6],tmp[7]);
  }
}

// fp32 -> bf16, grid-stride
__global__ __launch_bounds__(256)
void cast_bf16_k(const float* __restrict__ in, unsigned short* __restrict__ outp, int n8)
{
  for (int i = blockIdx.x*256 + threadIdx.x; i < n8; i += gridDim.x*256){
    const float4* p = (const float4*)(in + (long)i*8);
    float4 a = p[0], b = p[1];
    *(uint4*)(outp + (long)i*8) = make_uint4(pk2(a.x,a.y), pk2(a.z,a.w), pk2(b.x,b.y), pk2(b.z,b.w));
  }
}

// masked-sum partial pooling, NO atomics: grid (4,32) -> 32 partials per batch
__global__ __launch_bounds__(256)
void pool2_k(const float* __restrict__ h, const float* __restrict__ mask, float* __restrict__ pooled)
{
  int b = blockIdx.x, sc = blockIdx.y, t = threadIdx.x;
  float a0 = 0.f, a1 = 0.f;
  const float* mb = mask + b*1024 + sc*32;
  const float* hbase = h + ((long)b*1024 + sc*32)*512;
  for (int s = 0; s < 32; ++s){
    float mk = mb[s];
    const float* r = hbase + (long)s*512;
    a0 += r[t]*mk; a1 += r[t+256]*mk;
  }
  pooled[((b*32 + sc)*512) + t] = a0;
  pooled[((b*32 + sc)*512) + t + 256] = a1;
}

__global__ __launch_bounds__(256)
void head_final_k(const float* __restrict__ pooled, const float* __restrict__ mask,
                  const float* __restrict__ pool_w, const float* __restrict__ pool_b,
                  const float* __restrict__ cls_w, const float* __restrict__ cls_b,
                  const float* __restrict__ cf_w1, const float* __restrict__ cf_b1,
                  const float* __restrict__ cf_w2, const float* __restrict__ cf_b2,
                  const float* __restrict__ aux, float* __restrict__ out)
{
  int b = blockIdx.x, t = threadIdx.x, wid = t>>6, lane = t&63;
  __shared__ __align__(16) float pld[512];
  __shared__ __align__(16) float p2[512];
  __shared__ float red[4];
  float ds = 0.f;
  for(int s=t; s<1024; s+=256) ds += mask[b*1024 + s];
  ds = wred_sum(ds);
  if (lane==0) red[wid] = ds;
  __syncthreads();
  float denom = fmaxf(red[0]+red[1]+red[2]+red[3], 1e-9f);
  float s0 = 0.f, s1 = 0.f;
#pragma unroll
  for(int sc=0;sc<32;sc++){
    s0 += pooled[((b*32+sc)*512) + t];
    s1 += pooled[((b*32+sc)*512) + t + 256];
  }
  pld[t]     = s0/denom;
  pld[t+256] = s1/denom;
  __syncthreads();
#pragma unroll
  for(int jj=0;jj<2;jj++){
    int j = t + jj*256;
    const float4* wr = (const float4*)(pool_w + (long)j*512);
    float acc = 0.f;
    for(int i=0;i<128;i++){
      float4 w4 = wr[i]; float4 x4 = ((const float4*)pld)[i];
      acc += w4.x*x4.x + w4.y*x4.y + w4.z*x4.z + w4.w*x4.w;
    }
    p2[j] = tanhf(acc + pool_b[j]);
  }
  __syncthreads();
  if (t < 4){
    const float4* wr = (const float4*)(cls_w + (long)t*512);
    float acc = 0.f;
    for(int i=0;i<128;i++){
      float4 w4 = wr[i]; float4 x4 = ((const float4*)p2)[i];
      acc += w4.x*x4.x + w4.y*x4.y + w4.z*x4.z + w4.w*x4.w;
    }
    out[b*4 + t] = acc + cls_b[t];
  }
  {
    const float4* wr = (const float4*)(cf_w1 + (long)t*512);
    float acc = 0.f;
    for(int i=0;i<128;i++){
      float4 w4 = wr[i]; float4 x4 = ((const float4*)p2)[i];
      acc += w4.x*x4.x + w4.y*x4.y + w4.z*x4.z + w4.w*x4.w;
    }
    acc = fmaxf(acc + cf_b1[t], 0.f) * cf_w2[t];
    acc = wred_sum(acc);
    __syncthreads();
    if (lane==0) red[wid] = acc;
    __syncthreads();
    if (t == 0){
      float sum = red[0]+red[1]+red[2]+red[3];
      out[17 + b] = 1.f/(1.f + expf(-(sum + cf_b2[0])));
    }
  }
  if (b == 0 && t == 0) out[16] = aux[0]*0.25f;
}

// ---------------------------------------------------------------------------
extern "C" void kernel_launch(void* const* d_in, const int* in_sizes, int n_in,
                              void* d_out, int out_size, void* d_ws, size_t ws_size,
                              hipStream_t stream)
{
  (void)in_sizes; (void)n_in; (void)out_size;
  const float* emb    = (const float*)d_in[0];
  const float* mask   = (const float*)d_in[1];
  const float* in_w   = (const float*)d_in[2];
  const float* in_b   = (const float*)d_in[3];
  const float* out_w  = (const float*)d_in[4];
  const float* out_b  = (const float*)d_in[5];
  const float* ln1_w  = (const float*)d_in[6];
  const float* ln1_b  = (const float*)d_in[7];
  const float* ln2_w  = (const float*)d_in[8];
  const float* ln2_b  = (const float*)d_in[9];
  const float* gate_w = (const float*)d_in[10];
  const float* e_w1   = (const float*)d_in[11];
  const float* e_b1   = (const float*)d_in[12];
  const float* e_w2   = (const float*)d_in[13];
  const float* e_b2   = (const float*)d_in[14];
  const float* mln_w  = (const float*)d_in[15];
  const float* mln_b  = (const float*)d_in[16];
  const float* fln_w  = (const float*)d_in[17];
  const float* fln_b  = (const float*)d_in[18];
  const float* pool_w = (const float*)d_in[19];
  const float* pool_b = (const float*)d_in[20];
  const float* cls_w  = (const float*)d_in[21];
  const float* cls_b  = (const float*)d_in[22];
  const float* cf_w1  = (const float*)d_in[23];
  const float* cf_b1  = (const float*)d_in[24];
  const float* cf_w2  = (const float*)d_in[25];
  const float* cf_b2  = (const float*)d_in[26];
  float* out = (float*)d_out;
  char* ws = (char*)d_ws;

  const size_t MiB = 1024*1024;
  if (ws_size < 218*MiB) return;

  // Workspace layout
  float*          x     = (float*)(ws + 0*MiB);             // 8 MiB fp32
  unsigned short* hb    = (unsigned short*)(ws + 8*MiB);    // 4 MiB bf16
  unsigned short* qkvb  = (unsigned short*)(ws + 12*MiB);   // 12 MiB bf16
  unsigned short* ctx   = (unsigned short*)(ws + 24*MiB);   // 4 MiB bf16
  unsigned short* Vt    = (unsigned short*)(ws + 28*MiB);   // 4 MiB bf16
  unsigned short* mid   = (unsigned short*)(ws + 32*MiB);   // 32 MiB bf16
  float*          eout  = (float*)(ws + 64*MiB);            // 16 MiB fp32
  float*          fout  = (float*)(ws + 64*MiB);            //   (reuse, head)
  unsigned short* w1t   = (unsigned short*)(ws + 80*MiB);   // 64 MiB bf16
  unsigned short* w2t   = (unsigned short*)(ws + 144*MiB);  // 64 MiB bf16
  unsigned short* inwb  = (unsigned short*)(ws + 208*MiB);  // 6 MiB bf16
  unsigned short* outwb = (unsigned short*)(ws + 214*MiB);  // 2 MiB bf16
  char* misc = ws + 216*MiB;
  int*   counts  = (int*)(misc + 0);
  int*   offs    = (int*)(misc + 64);
  float* aux     = (float*)(misc + 128);
  int*   btab    = (int*)(misc + 256);       // 80 ints
  int*   btab64  = (int*)(misc + 1024);      // 144 ints
  int*   tok_e   = (int*)(misc + 81920);
  float* tok_w   = (float*)(misc + 114688);
  int*   rowtok  = (int*)(misc + 147456);
  float* roww    = (float*)(misc + 180224);
  int*   rowof   = (int*)(misc + 212992);    // 16 KiB
  float* pooled  = (float*)(misc + 262144);  // 256 KiB (4*32*512 fp32)

  hipMemsetAsync(aux, 0, 4, stream);
  // weight prep
  cast_bf16_k<<<512, 256, 0, stream>>>(in_w, inwb, L_*3*D_*D_/8);
  cast_bf16_k<<<256, 256, 0, stream>>>(out_w, outwb, L_*D_*D_/8);
  transpose_cast_k<<<dim3(I_/64, D_/64, 4), 256, 0, stream>>>(e_w1, w1t, D_, I_, 8);
  transpose_cast_k<<<dim3(D_/64, I_/64, 4), 256, 0, stream>>>(e_w2, w2t, I_, D_, 8);

  // layer-0 LN1 (reads emb directly)
  ln_w_k<true><<<T_/4, 256, 0, stream>>>(emb, ln1_w, ln1_b, hb);

  for (int l=0; l<L_; l++){
    const float* inbl  = in_b  + (size_t)l*3*D_;
    const float* outbl = out_b + (size_t)l*D_;
    const float* gwl   = gate_w + (size_t)l*E_*D_;
    const float* eb1l  = e_b1 + (size_t)l*E_*I_;
    const float* eb2l  = e_b2 + (size_t)l*E_*D_;
    const unsigned short* inwbl  = inwb + (size_t)l*3*D_*D_;
    const unsigned short* outwbl = outwb + (size_t)l*D_*D_;
    const unsigned short* w1tl = w1t + (size_t)l*E_*I_*D_;
    const unsigned short* w2tl = w2t + (size_t)l*E_*D_*I_;

    // qkv = h @ in_w^T + in_b; Q,K -> qkvb, V -> Vt transposed (fused vt_k)
    gemm_k<64,128,false,false,true,0,false,true><<<dim3(768,1,1), 512, 0, stream>>>(
      hb, inwbl, qkvb, inbl, nullptr, T_, 3*D_, D_, D_, D_, 3*D_,
      1, 0,0,0,0,0,0, 1.f, nullptr, nullptr, nullptr, nullptr, 0, 0, 12, Vt);
    // fused attention -> ctx (B,S,512) bf16
    flash_k<<<dim3(16,32), 256, 0, stream>>>(qkvb, Vt, ctx);
    // x = residual + ctx @ out_w^T + out_b  (fp32); layer 0 residual = emb
    gemm_k<64,64,false,false,false,0,true,false><<<dim3(512,1,1), 512, 0, stream>>>(
      ctx, outwbl, x, outbl, (l == 0 ? emb : x), T_, D_, D_, D_, D_, D_,
      1, 0,0,0,0,0,0, 1.f, nullptr, nullptr, nullptr, nullptr, 0, 0, 8, nullptr);
    // h2 = LN2(x) -> bf16, + routing (no atomics)
    ln2route_k<<<T_/4, 256, 0, stream>>>(x, ln2_w + (size_t)l*D_, ln2_b + (size_t)l*D_,
                                         hb, gwl, tok_e, tok_w);
    // plan + scatter, single block, LDS atomics only
    plan_scatter_k<<<1, 1024, 0, stream>>>(tok_e, tok_w, offs, counts, aux, btab, btab64,
                                           rowtok, roww, rowof);
    // FFN1: mid = gelu(gather(h2) @ w1^T + b1) -> bf16   (BM=128,BN=64: 2272 blocks, nby=32)
    gemm_k<128,64,true,true,true,1,false,false><<<dim3(2272,1,1), 512, 0, stream>>>(
      hb, w1tl, mid, eb1l, nullptr, 2*T_, I_, D_, D_, D_, I_,
      1, 0,0,0,0,0,0, 1.f, offs, counts, rowtok, btab, (long)I_*D_, I_, 32, nullptr);
    // FFN2: eout = mid @ w2^T + b2 -> fp32   (BM=64, 544 blocks, nby=4)
    gemm_k<64,128,true,false,false,0,false,false><<<dim3(544,1,1), 512, 0, stream>>>(
      mid, w2tl, eout, eb2l, nullptr, 2*T_, D_, I_, I_, I_, D_,
      1, 0,0,0,0,0,0, 1.f, offs, counts, nullptr, btab64, (long)D_*I_, D_, 4, nullptr);
    // x = LN(h2 + combine(eout)); fused second LN -> next LN1 (bf16 hb) or final LN (fp32 fout)
    if (l < 3){
      ln_moe_k<true><<<T_/4, 256, 0, stream>>>(eout, rowof, roww, mask, hb,
                                               mln_w + (size_t)l*D_, mln_b + (size_t)l*D_, x,
                                               ln1_w + (size_t)(l+1)*D_, ln1_b + (size_t)(l+1)*D_,
                                               (void*)hb);
    } else {
      ln_moe_k<false><<<T_/4, 256, 0, stream>>>(eout, rowof, roww, mask, hb,
                                                mln_w + (size_t)l*D_, mln_b + (size_t)l*D_, x,
                                                fln_w, fln_b, (void*)fout);
    }
  }
  // head
  pool2_k<<<dim3(4,32), 256, 0, stream>>>(fout, mask, pooled);
  head_final_k<<<4, 256, 0, stream>>>(pooled, mask, pool_w, pool_b, cls_w, cls_b,
                                      cf_w1, cf_b1, cf_w2, cf_b2, aux, out);
}

// Round 10
// 1251.398 us; speedup vs baseline: 1.2009x; 1.0048x over previous
//
#include <hip/hip_runtime.h>
#include <math.h>

// Problem constants
#define B_ 4
#define S_ 1024
#define D_ 512
#define H_ 8
#define DH_ 64
#define I_ 2048
#define E_ 8
#define L_ 4
#define T_ 4096   // B*S

using bf16x8 = __attribute__((ext_vector_type(8))) __bf16;
using f32x4  = __attribute__((ext_vector_type(4))) float;

typedef __attribute__((address_space(1))) const void gvoid;
typedef __attribute__((address_space(3))) void lvoid;
__device__ __forceinline__ void gl_lds16(const void* g, void* l){
  __builtin_amdgcn_global_load_lds((gvoid*)g, (lvoid*)l, 16, 0, 0);
}

__device__ __forceinline__ float wred_sum(float v){
#pragma unroll
  for(int m=32;m>0;m>>=1) v += __shfl_xor(v, m, 64);
  return v;
}
__device__ __forceinline__ unsigned short f2bf(float f){
  unsigned x = __float_as_uint(f);
  unsigned r = (x + 0x7FFFu + ((x>>16)&1u)) >> 16;
  return (unsigned short)r;
}
__device__ __forceinline__ float bf2f(unsigned short u){
  return __uint_as_float(((unsigned)u)<<16);
}
__device__ __forceinline__ unsigned pk2(float a, float b){
  return (unsigned)f2bf(a) | ((unsigned)f2bf(b)<<16);
}

// ---------------------------------------------------------------------------
// bf16 MFMA GEMM. NT: C[m,n] = sum_k A[m,k]*B[n,k].
// 512 threads = 8 waves in 2x4 (wy=wid>>2, wx=wid&3). Occupancy is the
// validated lever (R5: 4->8 waves = -9% total).
// BK=64, double-buffered LDS, phase-interleaved schedule:
//   per K-step: [vmcnt(0); s_barrier] then
//     phase0: issue stage A(t+1) | ds_read kk0 | setprio(1) MFMA kk0
//     phase1: issue stage B(t+1) | ds_read kk1 | setprio(1) MFMA kk1
// ONE barrier per K-step (top barrier protects both buffers).
// T2 bank-conflict fix (verified 6.78M->0): LDS dest linear, global SOURCE
// col unit ^= (row&7); fragment reads XOR the same involution.
// 1-D grid with XCD-chunked bijective swizzle (gridDim.x % 8 == 0).
// MOE: block table btab[bx] = (e<<8)|mblk, -1 = dead. Optional row gather.
// VT (QKV only): blocks with n0>=1024 hold the V slice -> write transposed
// directly to Vt[z=b*8+h][d][k] (replaces the vt_k copy kernel; bit-identical).
// ---------------------------------------------------------------------------
template<int BM, int BN, bool MOE, bool GATHER, bool OUT_BF16, int ACT, bool ADD_IN, bool VT>
__global__ __launch_bounds__(512)
void gemm_k(const unsigned short* __restrict__ A, const unsigned short* __restrict__ Bv,
            void* Cp, const float* __restrict__ bias, const float* addin,
            int M, int N, int K, int lda, int ldb, int ldc,
            int hdiv, long sAb, long sAh, long sBb, long sBh, long sCb, long sCh,
            float scale,
            const int* __restrict__ moff, const int* __restrict__ mcnt,
            const int* __restrict__ rowtok, const int* __restrict__ btab,
            long sBe, int biasStride, int nby, unsigned short* __restrict__ vtp)
{
  constexpr int BK = 64;
  constexpr int WM = BM/2, WN = BN/4, FM = WM/16, FNN = WN/16;
  constexpr int RPC = 64;            // rows covered per block-wide gl_lds16 call (512 thr / 8 per row)
  constexpr int SHPC = 4096;         // shorts per call (512 thr * 8)
  constexpr int NA = BM/RPC, NB = BN/RPC;
  __shared__ unsigned short As[2*BM*BK];
  __shared__ unsigned short Bs[2*BN*BK];

  const int tid = threadIdx.x, wid = tid>>6, lane = tid&63;
  const int wy = wid>>2, wx = wid&3, ln16 = lane&15;

  // XCD-chunked bijective swizzle: consecutive hw ids round-robin XCDs;
  // remap so each XCD owns a contiguous chunk of (bx,by) space, by innermost.
  const int nwg = gridDim.x, cpx = nwg >> 3;
  const int lin = blockIdx.x;
  const int wg  = (lin & 7)*cpx + (lin >> 3);
  const int bxi = wg / nby, byi = wg % nby;

  int m0 = bxi*BM;
  const int n0 = byi*BN;

  float* Cf = nullptr; unsigned short* Ch = nullptr;
  const float* biasp = bias;
  const unsigned short* Bp = Bv;
  int seg = 0, cnt = M;

  if constexpr (MOE){
    int tv = btab[bxi];
    if (tv < 0) return;
    int e = tv>>8;
    m0 = (tv&255)*BM;
    seg = moff[e]; cnt = mcnt[e];
    Bp = Bv + (long)e*sBe;
    if constexpr (OUT_BF16) Ch = (unsigned short*)Cp; else Cf = (float*)Cp;
    if (biasp) biasp += (long)e*biasStride;
  } else {
    int z = blockIdx.z, zb = z/hdiv, zh = z%hdiv;
    A  += (long)zb*sAb + (long)zh*sAh;
    Bp += (long)zb*sBb + (long)zh*sBh;
    long coff = (long)zb*sCb + (long)zh*sCh;
    if constexpr (OUT_BF16) Ch = (unsigned short*)Cp + coff; else Cf = ((float*)Cp) + coff;
    if constexpr (ADD_IN) addin += coff;
  }

  // staging geometry: call j covers rows j*RPC + tid/8, col-unit (tid&7) of 8x16B.
  // SOURCE-side XOR swizzle (T2): unit ^= (row&7); LDS dest stays linear so
  // gl_lds is legal; reads undo the same involution.
  const int srow = tid >> 3;          // 8 lanes per row
  const int scol = ((tid & 7) ^ (srow & 7)) * 8;
  long ga[NA], gb[NB];
#pragma unroll
  for (int j=0; j<NA; j++){
    int r = m0 + j*RPC + srow;
    if constexpr (MOE){
      r = min(r, cnt-1);
      long gr = GATHER ? (long)rowtok[seg+r] : (long)(seg+r);
      ga[j] = gr*lda + scol;
    } else {
      ga[j] = (long)min(r, M-1)*lda + scol;
    }
  }
#pragma unroll
  for (int j=0; j<NB; j++){
    int bn = min(n0 + j*RPC + srow, N-1);
    gb[j] = (long)bn*ldb + scol;
  }

  f32x4 acc[FM][FNN];
#pragma unroll
  for(int i=0;i<FM;i++)
#pragma unroll
    for(int j=0;j<FNN;j++){ f32x4 z = {0.f,0.f,0.f,0.f}; acc[i][j] = z; }

  const int nt = K/BK;
  // read-side swizzle: row&7 == ln16&7 for all fragment rows (WM,WN mult of 8/16)
  const int rsw = ln16 & 7;
  const int u0 = ((lane>>4)     ^ rsw) * 8;   // kk=0 unit offset (elements)
  const int u1 = ((4+(lane>>4)) ^ rsw) * 8;   // kk=1 unit offset

  // prologue: stage tile 0 into buffer 0
#pragma unroll
  for (int j=0; j<NA; j++) gl_lds16(A + ga[j], As + j*SHPC + wid*512);
#pragma unroll
  for (int j=0; j<NB; j++) gl_lds16(Bp + gb[j], Bs + j*SHPC + wid*512);

  for (int t = 0; t < nt; ++t){
    const int cb = t & 1;
    const unsigned short* Ab = As + cb*BM*BK;
    const unsigned short* Bb = Bs + cb*BN*BK;
    unsigned short* An = As + (cb^1)*BM*BK;
    unsigned short* Bn = Bs + (cb^1)*BN*BK;
    const bool pf = (t+1 < nt);
    const long k0n = (long)(t+1)*BK;

    asm volatile("s_waitcnt vmcnt(0)" ::: "memory");  // this tile's loads landed
    __builtin_amdgcn_s_barrier();                     // tile t ready; prev-tile reads done by all waves
    __builtin_amdgcn_sched_barrier(0);                // no ds_read/gl_lds hoists above

    // ---- phase 0: stage A(t+1) | ds_read kk0 | MFMA kk0
    if (pf){
#pragma unroll
      for (int j=0; j<NA; j++) gl_lds16(A + ga[j] + k0n, An + j*SHPC + wid*512);
    }
    {
      bf16x8 fa[FM], fb[FNN];
#pragma unroll
      for(int i=0;i<FM;i++) fa[i] = *(const bf16x8*)&Ab[(wy*WM + i*16 + ln16)*BK + u0];
#pragma unroll
      for(int j=0;j<FNN;j++) fb[j] = *(const bf16x8*)&Bb[(wx*WN + j*16 + ln16)*BK + u0];
      __builtin_amdgcn_s_setprio(1);
#pragma unroll
      for(int i=0;i<FM;i++)
#pragma unroll
        for(int j=0;j<FNN;j++)
          acc[i][j] = __builtin_amdgcn_mfma_f32_16x16x32_bf16(fa[i], fb[j], acc[i][j], 0, 0, 0);
      __builtin_amdgcn_s_setprio(0);
    }
    // ---- phase 1: stage B(t+1) | ds_read kk1 | MFMA kk1
    if (pf){
#pragma unroll
      for (int j=0; j<NB; j++) gl_lds16(Bp + gb[j] + k0n, Bn + j*SHPC + wid*512);
    }
    {
      bf16x8 fa[FM], fb[FNN];
#pragma unroll
      for(int i=0;i<FM;i++) fa[i] = *(const bf16x8*)&Ab[(wy*WM + i*16 + ln16)*BK + u1];
#pragma unroll
      for(int j=0;j<FNN;j++) fb[j] = *(const bf16x8*)&Bb[(wx*WN + j*16 + ln16)*BK + u1];
      __builtin_amdgcn_s_setprio(1);
#pragma unroll
      for(int i=0;i<FM;i++)
#pragma unroll
        for(int j=0;j<FNN;j++)
          acc[i][j] = __builtin_amdgcn_mfma_f32_16x16x32_bf16(fa[i], fb[j], acc[i][j], 0, 0, 0);
      __builtin_amdgcn_s_setprio(0);
    }
  }

  // V-split epilogue (QKV only): n0>=1024 is the V slice; write transposed
  // to Vt[(b*8+h)][d][k]. mbase is 4-aligned in k -> one 8B ushort4 store.
  if constexpr (VT){
    if (n0 >= 1024){
#pragma unroll
      for(int i=0;i<FM;i++){
        int mbase = m0 + wy*WM + i*16 + (lane>>4)*4;
        int bb = mbase >> 10;
        int k4 = mbase & 1023;
#pragma unroll
        for(int j=0;j<FNN;j++){
          int n = n0 + wx*WN + j*16 + ln16;
          float bv = biasp ? biasp[n] : 0.f;
          int hh = (n - 1024) >> 6, dd = (n - 1024) & 63;
          f32x4 v = acc[i][j];
          ushort4 pkv;
          pkv.x = f2bf(v[0]*scale + bv);
          pkv.y = f2bf(v[1]*scale + bv);
          pkv.z = f2bf(v[2]*scale + bv);
          pkv.w = f2bf(v[3]*scale + bv);
          *(ushort4*)(vtp + (long)(bb*8 + hh)*65536 + (long)dd*1024 + k4) = pkv;
        }
      }
      return;
    }
  }

  // epilogue: C[m = quad*4+r][n = lane&15]
#pragma unroll
  for(int i=0;i<FM;i++){
    int mbase = m0 + wy*WM + i*16 + (lane>>4)*4;
#pragma unroll
    for(int j=0;j<FNN;j++){
      int n = n0 + wx*WN + j*16 + ln16;
      float bv = biasp ? biasp[n] : 0.f;
      f32x4 v = acc[i][j];
#pragma unroll
      for(int r=0;r<4;r++){
        int m = mbase + r;
        if (m < cnt){
          float x = v[r]*scale + bv;
          if constexpr (ACT == 1) x = 0.5f*x*(1.f + erff(x*0.70710678118654752f));
          long ci = (long)(MOE ? seg + m : m)*ldc + n;
          if constexpr (ADD_IN) x += addin[ci];
          if constexpr (OUT_BF16) Ch[ci] = f2bf(x);
          else Cf[ci] = x;
        }
      }
    }
  }
}

// ---------------------------------------------------------------------------
// Fused flash attention. 1-D grid 512 blocks, XCD-chunked so the 16 qt-blocks
// sharing one z's K/V (256KB) land on ONE XCD's L2 (4 z per XCD = 1MB, fits).
// 4 waves, each owns 16 Q-rows; zero barriers (waves independent).
// 2-deep register double-buffer on K/V: load tile t+1 while computing t
// (hides HBM/L2 latency; grid-limited occupancy of 8 waves/CU can't).
// ---------------------------------------------------------------------------
__global__ __launch_bounds__(256, 2)
void flash_k(const unsigned short* __restrict__ qkvb, const unsigned short* __restrict__ Vt,
             unsigned short* __restrict__ ctx)
{
  __shared__ unsigned short Pl[4][16*72];
  const int lin = blockIdx.x;
  const int wg  = (lin & 7)*64 + (lin >> 3);   // bijective: 512 = 8 XCD x 64
  const int qt = wg & 15, z = wg >> 4, b = z>>3, h = z&7;
  const int wid = threadIdx.x>>6, lane = threadIdx.x&63;
  const int ln16 = lane&15, g = lane>>4;
  const int q0 = qt*64 + wid*16;
  unsigned short* Pw = &Pl[wid][0];

  const unsigned short* Qp = qkvb + (long)(b*1024 + q0 + ln16)*1536 + h*64 + g*8;
  bf16x8 qf0 = *(const bf16x8*)Qp;
  bf16x8 qf1 = *(const bf16x8*)(Qp + 32);
  const unsigned short* Kbase = qkvb + (long)b*1024*1536 + 512 + h*64 + g*8;
  const unsigned short* Vbase = Vt + (long)z*65536 + g*8;

  float m_s[4], l_s[4];
  f32x4 oacc[4];
#pragma unroll
  for(int r=0;r<4;r++){ m_s[r] = -1e30f; l_s[r] = 0.f; }
#pragma unroll
  for(int j=0;j<4;j++){ f32x4 zz = {0.f,0.f,0.f,0.f}; oacc[j] = zz; }

  bf16x8 ka[4][2], va[4][2], kb[4][2], vb[4][2];

#define LOADKV(T, KD, VD) do { \
  _Pragma("unroll") \
  for(int j=0;j<4;j++){ \
    const unsigned short* kp = Kbase + (long)((T)*64 + j*16 + ln16)*1536; \
    KD[j][0] = *(const bf16x8*)kp; \
    KD[j][1] = *(const bf16x8*)(kp + 32); \
    const unsigned short* vp = Vbase + (long)(j*16 + ln16)*1024 + (T)*64; \
    VD[j][0] = *(const bf16x8*)vp; \
    VD[j][1] = *(const bf16x8*)(vp + 32); \
  } } while(0)

  auto compute = [&](bf16x8 (&kf)[4][2], bf16x8 (&vf)[4][2]){
    f32x4 sacc[4];
#pragma unroll
    for(int j=0;j<4;j++){ f32x4 zz = {0.f,0.f,0.f,0.f}; sacc[j] = zz; }
    __builtin_amdgcn_s_setprio(1);
#pragma unroll
    for(int j=0;j<4;j++){
      sacc[j] = __builtin_amdgcn_mfma_f32_16x16x32_bf16(qf0, kf[j][0], sacc[j], 0,0,0);
      sacc[j] = __builtin_amdgcn_mfma_f32_16x16x32_bf16(qf1, kf[j][1], sacc[j], 0,0,0);
    }
    __builtin_amdgcn_s_setprio(0);
#pragma unroll
    for(int j=0;j<4;j++)
#pragma unroll
      for(int r=0;r<4;r++) sacc[j][r] *= 0.125f;
    float alpha[4];
#pragma unroll
    for(int r=0;r<4;r++){
      float mx = fmaxf(fmaxf(sacc[0][r], sacc[1][r]), fmaxf(sacc[2][r], sacc[3][r]));
#pragma unroll
      for(int m=1;m<16;m<<=1) mx = fmaxf(mx, __shfl_xor(mx, m, 64));
      float mn = fmaxf(m_s[r], mx);
      alpha[r] = __expf(m_s[r] - mn);
      m_s[r] = mn;
    }
#pragma unroll
    for(int j=0;j<4;j++)
#pragma unroll
      for(int r=0;r<4;r++) sacc[j][r] = __expf(sacc[j][r] - m_s[r]);
#pragma unroll
    for(int r=0;r<4;r++){
      float rs = sacc[0][r]+sacc[1][r]+sacc[2][r]+sacc[3][r];
#pragma unroll
      for(int m=1;m<16;m<<=1) rs += __shfl_xor(rs, m, 64);
      l_s[r] = l_s[r]*alpha[r] + rs;
    }
#pragma unroll
    for(int j=0;j<4;j++)
#pragma unroll
      for(int r=0;r<4;r++) oacc[j][r] *= alpha[r];
#pragma unroll
    for(int j=0;j<4;j++)
#pragma unroll
      for(int r=0;r<4;r++)
        Pw[(g*4+r)*72 + j*16 + ln16] = f2bf(sacc[j][r]);
    bf16x8 pf0 = *(const bf16x8*)&Pw[ln16*72 + g*8];
    bf16x8 pf1 = *(const bf16x8*)&Pw[ln16*72 + 32 + g*8];
    __builtin_amdgcn_s_setprio(1);
#pragma unroll
    for(int j=0;j<4;j++){
      oacc[j] = __builtin_amdgcn_mfma_f32_16x16x32_bf16(pf0, vf[j][0], oacc[j], 0,0,0);
      oacc[j] = __builtin_amdgcn_mfma_f32_16x16x32_bf16(pf1, vf[j][1], oacc[j], 0,0,0);
    }
    __builtin_amdgcn_s_setprio(0);
  };

  LOADKV(0, ka, va);
  for (int tt = 0; tt < 8; ++tt){
    LOADKV(2*tt+1, kb, vb);     // prefetch odd tile while computing even
    compute(ka, va);
    if (tt < 7) LOADKV(2*tt+2, ka, va);  // prefetch next even while computing odd
    compute(kb, vb);
  }
#undef LOADKV

#pragma unroll
  for(int r=0;r<4;r++){
    float inv = 1.f/l_s[r];
    long row = (long)(b*1024 + q0 + g*4 + r)*512 + h*64;
#pragma unroll
    for(int j=0;j<4;j++)
      ctx[row + j*16 + ln16] = f2bf(oacc[j][r]*inv);
  }
}

// ---------------------------------------------------------------------------
// Wave-per-row LayerNorm (D=512): 4 rows/block, no barriers. (layer-0 only)
// ---------------------------------------------------------------------------
template<bool OUT_BF16>
__global__ __launch_bounds__(256)
void ln_w_k(const float* __restrict__ in, const float* __restrict__ w,
            const float* __restrict__ bb, void* __restrict__ outp)
{
  int row = blockIdx.x*4 + (threadIdx.x>>6), lane = threadIdx.x&63;
  const float4* p = (const float4*)(in + (long)row*512 + lane*8);
  float4 a = p[0], c = p[1];
  float s = a.x+a.y+a.z+a.w + c.x+c.y+c.z+c.w;
  float q = a.x*a.x+a.y*a.y+a.z*a.z+a.w*a.w + c.x*c.x+c.y*c.y+c.z*c.z+c.w*c.w;
  s = wred_sum(s); q = wred_sum(q);
  float mean = s*(1.f/512.f);
  float var  = q*(1.f/512.f) - mean*mean;
  float inv  = rsqrtf(var + 1e-5f);
  const float4* wp = (const float4*)(w + lane*8);
  const float4* bp = (const float4*)(bb + lane*8);
  float4 w0 = wp[0], w1 = wp[1], b0 = bp[0], b1 = bp[1];
  float o0 = (a.x-mean)*inv*w0.x + b0.x, o1 = (a.y-mean)*inv*w0.y + b0.y;
  float o2 = (a.z-mean)*inv*w0.z + b0.z, o3 = (a.w-mean)*inv*w0.w + b0.w;
  float o4 = (c.x-mean)*inv*w1.x + b1.x, o5 = (c.y-mean)*inv*w1.y + b1.y;
  float o6 = (c.z-mean)*inv*w1.z + b1.z, o7 = (c.w-mean)*inv*w1.w + b1.w;
  if constexpr (OUT_BF16){
    *(uint4*)((unsigned short*)outp + (long)row*512 + lane*8) =
      make_uint4(pk2(o0,o1), pk2(o2,o3), pk2(o4,o5), pk2(o6,o7));
  } else {
    float4* op = (float4*)((float*)outp + (long)row*512 + lane*8);
    op[0] = make_float4(o0,o1,o2,o3);
    op[1] = make_float4(o4,o5,o6,o7);
  }
}

// LN2 + router fused: h2 = LN(x) (bf16 out) then top-2 gate; NO global atomics.
__global__ __launch_bounds__(256)
void ln2route_k(const float* __restrict__ in, const float* __restrict__ w,
                const float* __restrict__ bb, unsigned short* __restrict__ h2,
                const float* __restrict__ gw,
                int* __restrict__ tok_e, float* __restrict__ tok_w)
{
  int tok = blockIdx.x*4 + (threadIdx.x>>6), lane = threadIdx.x&63;
  const float4* p = (const float4*)(in + (long)tok*512 + lane*8);
  float4 a = p[0], c = p[1];
  float s = a.x+a.y+a.z+a.w + c.x+c.y+c.z+c.w;
  float q = a.x*a.x+a.y*a.y+a.z*a.z+a.w*a.w + c.x*c.x+c.y*c.y+c.z*c.z+c.w*c.w;
  s = wred_sum(s); q = wred_sum(q);
  float mean = s*(1.f/512.f);
  float var  = q*(1.f/512.f) - mean*mean;
  float inv  = rsqrtf(var + 1e-5f);
  const float4* wp = (const float4*)(w + lane*8);
  const float4* bp = (const float4*)(bb + lane*8);
  float4 w0 = wp[0], w1 = wp[1], b0 = bp[0], b1 = bp[1];
  float o[8];
  o[0] = (a.x-mean)*inv*w0.x + b0.x; o[1] = (a.y-mean)*inv*w0.y + b0.y;
  o[2] = (a.z-mean)*inv*w0.z + b0.z; o[3] = (a.w-mean)*inv*w0.w + b0.w;
  o[4] = (c.x-mean)*inv*w1.x + b1.x; o[5] = (c.y-mean)*inv*w1.y + b1.y;
  o[6] = (c.z-mean)*inv*w1.z + b1.z; o[7] = (c.w-mean)*inv*w1.w + b1.w;
  *(uint4*)(h2 + (long)tok*512 + lane*8) =
    make_uint4(pk2(o[0],o[1]), pk2(o[2],o[3]), pk2(o[4],o[5]), pk2(o[6],o[7]));
  float lg[8];
#pragma unroll
  for(int e=0;e<8;e++){
    const float4* gr = (const float4*)(gw + e*512 + lane*8);
    float4 g0 = gr[0], g1 = gr[1];
    float d = o[0]*g0.x + o[1]*g0.y + o[2]*g0.z + o[3]*g0.w
            + o[4]*g1.x + o[5]*g1.y + o[6]*g1.z + o[7]*g1.w;
    lg[e] = wred_sum(d);
  }
  if (lane == 0){
    float mx = lg[0];
#pragma unroll
    for(int e=1;e<8;e++) mx = fmaxf(mx, lg[e]);
    float pr[8];
#pragma unroll
    for(int e=0;e<8;e++) pr[e] = expf(lg[e]-mx);
    int e0 = 0; float p0 = pr[0];
#pragma unroll
    for(int e=1;e<8;e++) if (pr[e] > p0){ p0 = pr[e]; e0 = e; }
    int e1 = -1; float p1 = -1.f;
#pragma unroll
    for(int e=0;e<8;e++) if (e != e0 && pr[e] > p1){ p1 = pr[e]; e1 = e; }
    float invp = 1.f/(p0+p1);
    tok_e[2*tok] = e0; tok_e[2*tok+1] = e1;
    tok_w[2*tok] = p0*invp; tok_w[2*tok+1] = p1*invp;
  }
}

// ---------------------------------------------------------------------------
// Single-block planner + scatter: LDS-atomic histogram, offsets, two block
// tables (BM=128 for FFN1, BM=64 for FFN2), aux, and compaction scatter.
// ---------------------------------------------------------------------------
__global__ __launch_bounds__(1024)
void plan_scatter_k(const int* __restrict__ tok_e, const float* __restrict__ tok_w,
                    int* __restrict__ offs, int* __restrict__ cnts, float* __restrict__ aux,
                    int* __restrict__ btab, int* __restrict__ btab64,
                    int* __restrict__ rowtok, float* __restrict__ roww, int* __restrict__ rowof)
{
  __shared__ int hist[8];
  __shared__ int offsS[8];
  __shared__ int base[8];
  const int t = threadIdx.x;
  if (t < 8) hist[t] = 0;
  __syncthreads();
  int e[8]; float w[8];
#pragma unroll
  for (int i=0;i<8;i++){
    e[i] = tok_e[t + i*1024];
    w[i] = tok_w[t + i*1024];
    atomicAdd(&hist[e[i]], 1);
  }
  __syncthreads();
  if (t == 0){
    int o = 0, idx = 0, idx2 = 0; float a = 0.f;
    for (int ee=0; ee<8; ee++){
      offsS[ee] = o;
      int c = hist[ee];
      o += c;
      float u = (float)c*(1.f/4096.f) - 0.125f;
      a += u*u;
      int nb = (c + 127) >> 7;
      for (int j=0;j<nb;j++) btab[idx++] = (ee<<8)|j;
      int nb2 = (c + 63) >> 6;
      for (int j=0;j<nb2;j++) btab64[idx2++] = (ee<<8)|j;
    }
    while (idx < 80) btab[idx++] = -1;
    while (idx2 < 144) btab64[idx2++] = -1;
    *aux += a*(1.f/8.f);
  }
  __syncthreads();
  if (t < 8){
    cnts[t] = hist[t];
    offs[t] = offsS[t];
    base[t] = offsS[t];
  }
  __syncthreads();
#pragma unroll
  for (int i=0;i<8;i++){
    int pos = atomicAdd(&base[e[i]], 1);   // LDS atomic
    int gi = t + i*1024;
    rowtok[pos] = gi>>1;
    roww[pos] = w[i];
    rowof[gi] = pos;
  }
}

// Fused MoE combine + LN(mln) -> x, PLUS second LN (next layer's LN1, or the
// head's final LN) computed in-register from the just-built x. Eliminates the
// standalone ln_w launch + 12MB re-read per layer.
template<bool OUT2_BF16>
__global__ __launch_bounds__(256)
void ln_moe_k(const float* __restrict__ eout, const int* __restrict__ rowof,
              const float* __restrict__ roww, const float* __restrict__ mask,
              const unsigned short* __restrict__ h2,
              const float* __restrict__ w, const float* __restrict__ bb,
              float* __restrict__ outp,
              const float* __restrict__ w2, const float* __restrict__ b2,
              void* __restrict__ out2)
{
  int tok = blockIdx.x*4 + (threadIdx.x>>6), lane = threadIdx.x&63;
  int r0 = rowof[2*tok], r1 = rowof[2*tok+1];
  float w0w = roww[r0], w1w = roww[r1], mk = mask[tok];
  const float4* ap = (const float4*)(eout + (long)r0*512 + lane*8);
  const float4* bp2 = (const float4*)(eout + (long)r1*512 + lane*8);
  float4 a0 = ap[0], a1 = ap[1], c0 = bp2[0], c1 = bp2[1];
  uint4 hu = *(const uint4*)(h2 + (long)tok*512 + lane*8);
  const unsigned short* hh = (const unsigned short*)&hu;
  float v[8];
  v[0] = bf2f(hh[0]) + (a0.x*w0w + c0.x*w1w)*mk;
  v[1] = bf2f(hh[1]) + (a0.y*w0w + c0.y*w1w)*mk;
  v[2] = bf2f(hh[2]) + (a0.z*w0w + c0.z*w1w)*mk;
  v[3] = bf2f(hh[3]) + (a0.w*w0w + c0.w*w1w)*mk;
  v[4] = bf2f(hh[4]) + (a1.x*w0w + c1.x*w1w)*mk;
  v[5] = bf2f(hh[5]) + (a1.y*w0w + c1.y*w1w)*mk;
  v[6] = bf2f(hh[6]) + (a1.z*w0w + c1.z*w1w)*mk;
  v[7] = bf2f(hh[7]) + (a1.w*w0w + c1.w*w1w)*mk;
  float s = 0.f, q = 0.f;
#pragma unroll
  for(int i=0;i<8;i++){ s += v[i]; q += v[i]*v[i]; }
  s = wred_sum(s); q = wred_sum(q);
  float mean = s*(1.f/512.f);
  float var  = q*(1.f/512.f) - mean*mean;
  float inv  = rsqrtf(var + 1e-5f);
  const float4* wp = (const float4*)(w + lane*8);
  const float4* bpp = (const float4*)(bb + lane*8);
  float4 w0 = wp[0], w1 = wp[1], b0 = bpp[0], b1 = bpp[1];
  float wv[8] = {w0.x,w0.y,w0.z,w0.w,w1.x,w1.y,w1.z,w1.w};
  float bv[8] = {b0.x,b0.y,b0.z,b0.w,b1.x,b1.y,b1.z,b1.w};
  float o[8];
#pragma unroll
  for(int i=0;i<8;i++) o[i] = (v[i]-mean)*inv*wv[i]+bv[i];
  float4* op = (float4*)(outp + (long)tok*512 + lane*8);
  op[0] = make_float4(o[0], o[1], o[2], o[3]);
  op[1] = make_float4(o[4], o[5], o[6], o[7]);
  // second LN over o (the new x)
  float s2 = 0.f, q2 = 0.f;
#pragma unroll
  for(int i=0;i<8;i++){ s2 += o[i]; q2 += o[i]*o[i]; }
  s2 = wred_sum(s2); q2 = wred_sum(q2);
  float mean2 = s2*(1.f/512.f);
  float var2  = q2*(1.f/512.f) - mean2*mean2;
  float inv2  = rsqrtf(var2 + 1e-5f);
  const float4* wp2 = (const float4*)(w2 + lane*8);
  const float4* bp3 = (const float4*)(b2 + lane*8);
  float4 x0 = wp2[0], x1 = wp2[1], y0 = bp3[0], y1 = bp3[1];
  float wv2[8] = {x0.x,x0.y,x0.z,x0.w,x1.x,x1.y,x1.z,x1.w};
  float bv2[8] = {y0.x,y0.y,y0.z,y0.w,y1.x,y1.y,y1.z,y1.w};
  float o2[8];
#pragma unroll
  for(int i=0;i<8;i++) o2[i] = (o[i]-mean2)*inv2*wv2[i]+bv2[i];
  if constexpr (OUT2_BF16){
    *(uint4*)((unsigned short*)out2 + (long)tok*512 + lane*8) =
      make_uint4(pk2(o2[0],o2[1]), pk2(o2[2],o2[3]), pk2(o2[4],o2[5]), pk2(o2[6],o2[7]));
  } else {
    float4* op2 = (float4*)((float*)out2 + (long)tok*512 + lane*8);
    op2[0] = make_float4(o2[0], o2[1], o2[2], o2[3]);
    op2[1] = make_float4(o2[4], o2[5], o2[6], o2[7]);
  }
}

// fp32 (R,C) -> bf16 (C,R), z-loop of ZL
__global__ __launch_bounds__(256)
void transpose_cast_k(const float* __restrict__ in, unsigned short* __restrict__ outp,
                      int R, int C, int ZL)
{
  __shared__ float tile[64][65];
  int t = threadIdx.x;
  int rr = t>>2, cc = (t&3)*16;
  int cc2 = t>>2, rr2 = (t&3)*16;
  int c0 = blockIdx.x*64, r0 = blockIdx.y*64;
  for (int zi = 0; zi < ZL; ++zi){
    long zoff = (long)(blockIdx.z*ZL + zi) * R * C;
    const float* pin = in + zoff + (long)(r0+rr)*C + c0 + cc;
    float4 v0=*(const float4*)pin, v1=*(const float4*)(pin+4), v2=*(const float4*)(pin+8), v3=*(const float4*)(pin+12);
    __syncthreads();
    tile[rr][cc+0]=v0.x; tile[rr][cc+1]=v0.y; tile[rr][cc+2]=v0.z; tile[rr][cc+3]=v0.w;
    tile[rr][cc+4]=v1.x; tile[rr][cc+5]=v1.y; tile[rr][cc+6]=v1.z; tile[rr][cc+7]=v1.w;
    tile[rr][cc+8]=v2.x; tile[rr][cc+9]=v2.y; tile[rr][cc+10]=v2.z; tile[rr][cc+11]=v2.w;
    tile[rr][cc+12]=v3.x; tile[rr][cc+13]=v3.y; tile[rr][cc+14]=v3.z; tile[rr][cc+15]=v3.w;
    __syncthreads();
    unsigned tmp[8];
#pragma unroll
    for(int jj=0;jj<8;jj++)
      tmp[jj] = pk2(tile[rr2+2*jj][cc2], tile[rr2+2*jj+1][cc2]);
    uint4* dst = (uint4*)(outp + zoff + (long)(c0+cc2)*R + r0 + rr2);
    dst[0] = make_uint4(tmp[0],tmp[1],tmp[2],tmp[3]);
    dst[1] = make_uint4(tmp[4],tmp[5],tmp[6],tmp[7]);
  }
}

// fp32 -> bf16, grid-stride
__global__ __launch_bounds__(256)
void cast_bf16_k(const float* __restrict__ in, unsigned short* __restrict__ outp, int n8)
{
  for (int i = blockIdx.x*256 + threadIdx.x; i < n8; i += gridDim.x*256){
    const float4* p = (const float4*)(in + (long)i*8);
    float4 a = p[0], b = p[1];
    *(uint4*)(outp + (long)i*8) = make_uint4(pk2(a.x,a.y), pk2(a.z,a.w), pk2(b.x,b.y), pk2(b.z,b.w));
  }
}

// masked-sum partial pooling, NO atomics: grid (4,32) -> 32 partials per batch
__global__ __launch_bounds__(256)
void pool2_k(const float* __restrict__ h, const float* __restrict__ mask, float* __restrict__ pooled)
{
  int b = blockIdx.x, sc = blockIdx.y, t = threadIdx.x;
  float a0 = 0.f, a1 = 0.f;
  const float* mb = mask + b*1024 + sc*32;
  const float* hbase = h + ((long)b*1024 + sc*32)*512;
  for (int s = 0; s < 32; ++s){
    float mk = mb[s];
    const float* r = hbase + (long)s*512;
    a0 += r[t]*mk; a1 += r[t+256]*mk;
  }
  pooled[((b*32 + sc)*512) + t] = a0;
  pooled[((b*32 + sc)*512) + t + 256] = a1;
}

__global__ __launch_bounds__(256)
void head_final_k(const float* __restrict__ pooled, const float* __restrict__ mask,
                  const float* __restrict__ pool_w, const float* __restrict__ pool_b,
                  const float* __restrict__ cls_w, const float* __restrict__ cls_b,
                  const float* __restrict__ cf_w1, const float* __restrict__ cf_b1,
                  const float* __restrict__ cf_w2, const float* __restrict__ cf_b2,
                  const float* __restrict__ aux, float* __restrict__ out)
{
  int b = blockIdx.x, t = threadIdx.x, wid = t>>6, lane = t&63;
  __shared__ __align__(16) float pld[512];
  __shared__ __align__(16) float p2[512];
  __shared__ float red[4];
  float ds = 0.f;
  for(int s=t; s<1024; s+=256) ds += mask[b*1024 + s];
  ds = wred_sum(ds);
  if (lane==0) red[wid] = ds;
  __syncthreads();
  float denom = fmaxf(red[0]+red[1]+red[2]+red[3], 1e-9f);
  float s0 = 0.f, s1 = 0.f;
#pragma unroll
  for(int sc=0;sc<32;sc++){
    s0 += pooled[((b*32+sc)*512) + t];
    s1 += pooled[((b*32+sc)*512) + t + 256];
  }
  pld[t]     = s0/denom;
  pld[t+256] = s1/denom;
  __syncthreads();
#pragma unroll
  for(int jj=0;jj<2;jj++){
    int j = t + jj*256;
    const float4* wr = (const float4*)(pool_w + (long)j*512);
    float acc = 0.f;
    for(int i=0;i<128;i++){
      float4 w4 = wr[i]; float4 x4 = ((const float4*)pld)[i];
      acc += w4.x*x4.x + w4.y*x4.y + w4.z*x4.z + w4.w*x4.w;
    }
    p2[j] = tanhf(acc + pool_b[j]);
  }
  __syncthreads();
  if (t < 4){
    const float4* wr = (const float4*)(cls_w + (long)t*512);
    float acc = 0.f;
    for(int i=0;i<128;i++){
      float4 w4 = wr[i]; float4 x4 = ((const float4*)p2)[i];
      acc += w4.x*x4.x + w4.y*x4.y + w4.z*x4.z + w4.w*x4.w;
    }
    out[b*4 + t] = acc + cls_b[t];
  }
  {
    const float4* wr = (const float4*)(cf_w1 + (long)t*512);
    float acc = 0.f;
    for(int i=0;i<128;i++){
      float4 w4 = wr[i]; float4 x4 = ((const float4*)p2)[i];
      acc += w4.x*x4.x + w4.y*x4.y + w4.z*x4.z + w4.w*x4.w;
    }
    acc = fmaxf(acc + cf_b1[t], 0.f) * cf_w2[t];
    acc = wred_sum(acc);
    __syncthreads();
    if (lane==0) red[wid] = acc;
    __syncthreads();
    if (t == 0){
      float sum = red[0]+red[1]+red[2]+red[3];
      out[17 + b] = 1.f/(1.f + expf(-(sum + cf_b2[0])));
    }
  }
  if (b == 0 && t == 0) out[16] = aux[0]*0.25f;
}

// ---------------------------------------------------------------------------
extern "C" void kernel_launch(void* const* d_in, const int* in_sizes, int n_in,
                              void* d_out, int out_size, void* d_ws, size_t ws_size,
                              hipStream_t stream)
{
  (void)in_sizes; (void)n_in; (void)out_size;
  const float* emb    = (const float*)d_in[0];
  const float* mask   = (const float*)d_in[1];
  const float* in_w   = (const float*)d_in[2];
  const float* in_b   = (const float*)d_in[3];
  const float* out_w  = (const float*)d_in[4];
  const float* out_b  = (const float*)d_in[5];
  const float* ln1_w  = (const float*)d_in[6];
  const float* ln1_b  = (const float*)d_in[7];
  const float* ln2_w  = (const float*)d_in[8];
  const float* ln2_b  = (const float*)d_in[9];
  const float* gate_w = (const float*)d_in[10];
  const float* e_w1   = (const float*)d_in[11];
  const float* e_b1   = (const float*)d_in[12];
  const float* e_w2   = (const float*)d_in[13];
  const float* e_b2   = (const float*)d_in[14];
  const float* mln_w  = (const float*)d_in[15];
  const float* mln_b  = (const float*)d_in[16];
  const float* fln_w  = (const float*)d_in[17];
  const float* fln_b  = (const float*)d_in[18];
  const float* pool_w = (const float*)d_in[19];
  const float* pool_b = (const float*)d_in[20];
  const float* cls_w  = (const float*)d_in[21];
  const float* cls_b  = (const float*)d_in[22];
  const float* cf_w1  = (const float*)d_in[23];
  const float* cf_b1  = (const float*)d_in[24];
  const float* cf_w2  = (const float*)d_in[25];
  const float* cf_b2  = (const float*)d_in[26];
  float* out = (float*)d_out;
  char* ws = (char*)d_ws;

  const size_t MiB = 1024*1024;
  if (ws_size < 218*MiB) return;

  // Workspace layout
  float*          x     = (float*)(ws + 0*MiB);             // 8 MiB fp32
  unsigned short* hb    = (unsigned short*)(ws + 8*MiB);    // 4 MiB bf16
  unsigned short* qkvb  = (unsigned short*)(ws + 12*MiB);   // 12 MiB bf16
  unsigned short* ctx   = (unsigned short*)(ws + 24*MiB);   // 4 MiB bf16
  unsigned short* Vt    = (unsigned short*)(ws + 28*MiB);   // 4 MiB bf16
  unsigned short* mid   = (unsigned short*)(ws + 32*MiB);   // 32 MiB bf16
  float*          eout  = (float*)(ws + 64*MiB);            // 16 MiB fp32
  float*          fout  = (float*)(ws + 64*MiB);            //   (reuse, head)
  unsigned short* w1t   = (unsigned short*)(ws + 80*MiB);   // 64 MiB bf16
  unsigned short* w2t   = (unsigned short*)(ws + 144*MiB);  // 64 MiB bf16
  unsigned short* inwb  = (unsigned short*)(ws + 208*MiB);  // 6 MiB bf16
  unsigned short* outwb = (unsigned short*)(ws + 214*MiB);  // 2 MiB bf16
  char* misc = ws + 216*MiB;
  int*   counts  = (int*)(misc + 0);
  int*   offs    = (int*)(misc + 64);
  float* aux     = (float*)(misc + 128);
  int*   btab    = (int*)(misc + 256);       // 80 ints
  int*   btab64  = (int*)(misc + 1024);      // 144 ints
  int*   tok_e   = (int*)(misc + 81920);
  float* tok_w   = (float*)(misc + 114688);
  int*   rowtok  = (int*)(misc + 147456);
  float* roww    = (float*)(misc + 180224);
  int*   rowof   = (int*)(misc + 212992);    // 16 KiB
  float* pooled  = (float*)(misc + 262144);  // 256 KiB (4*32*512 fp32)

  hipMemsetAsync(aux, 0, 4, stream);
  // weight prep
  cast_bf16_k<<<512, 256, 0, stream>>>(in_w, inwb, L_*3*D_*D_/8);
  cast_bf16_k<<<256, 256, 0, stream>>>(out_w, outwb, L_*D_*D_/8);
  transpose_cast_k<<<dim3(I_/64, D_/64, 4), 256, 0, stream>>>(e_w1, w1t, D_, I_, 8);
  transpose_cast_k<<<dim3(D_/64, I_/64, 4), 256, 0, stream>>>(e_w2, w2t, I_, D_, 8);

  // layer-0 LN1 (reads emb directly)
  ln_w_k<true><<<T_/4, 256, 0, stream>>>(emb, ln1_w, ln1_b, hb);

  for (int l=0; l<L_; l++){
    const float* inbl  = in_b  + (size_t)l*3*D_;
    const float* outbl = out_b + (size_t)l*D_;
    const float* gwl   = gate_w + (size_t)l*E_*D_;
    const float* eb1l  = e_b1 + (size_t)l*E_*I_;
    const float* eb2l  = e_b2 + (size_t)l*E_*D_;
    const unsigned short* inwbl  = inwb + (size_t)l*3*D_*D_;
    const unsigned short* outwbl = outwb + (size_t)l*D_*D_;
    const unsigned short* w1tl = w1t + (size_t)l*E_*I_*D_;
    const unsigned short* w2tl = w2t + (size_t)l*E_*D_*I_;

    // qkv = h @ in_w^T + in_b; Q,K -> qkvb, V -> Vt transposed (fused vt_k)
    gemm_k<64,128,false,false,true,0,false,true><<<dim3(768,1,1), 512, 0, stream>>>(
      hb, inwbl, qkvb, inbl, nullptr, T_, 3*D_, D_, D_, D_, 3*D_,
      1, 0,0,0,0,0,0, 1.f, nullptr, nullptr, nullptr, nullptr, 0, 0, 12, Vt);
    // fused attention -> ctx (B,S,512) bf16  (1-D grid, XCD-chunked)
    flash_k<<<dim3(512,1,1), 256, 0, stream>>>(qkvb, Vt, ctx);
    // x = residual + ctx @ out_w^T + out_b  (fp32); layer 0 residual = emb
    gemm_k<64,64,false,false,false,0,true,false><<<dim3(512,1,1), 512, 0, stream>>>(
      ctx, outwbl, x, outbl, (l == 0 ? emb : x), T_, D_, D_, D_, D_, D_,
      1, 0,0,0,0,0,0, 1.f, nullptr, nullptr, nullptr, nullptr, 0, 0, 8, nullptr);
    // h2 = LN2(x) -> bf16, + routing (no atomics)
    ln2route_k<<<T_/4, 256, 0, stream>>>(x, ln2_w + (size_t)l*D_, ln2_b + (size_t)l*D_,
                                         hb, gwl, tok_e, tok_w);
    // plan + scatter, single block, LDS atomics only
    plan_scatter_k<<<1, 1024, 0, stream>>>(tok_e, tok_w, offs, counts, aux, btab, btab64,
                                           rowtok, roww, rowof);
    // FFN1: mid = gelu(gather(h2) @ w1^T + b1) -> bf16   (BM=128,BN=64: 2272 blocks, nby=32)
    gemm_k<128,64,true,true,true,1,false,false><<<dim3(2272,1,1), 512, 0, stream>>>(
      hb, w1tl, mid, eb1l, nullptr, 2*T_, I_, D_, D_, D_, I_,
      1, 0,0,0,0,0,0, 1.f, offs, counts, rowtok, btab, (long)I_*D_, I_, 32, nullptr);
    // FFN2: eout = mid @ w2^T + b2 -> fp32   (BM=64, 544 blocks, nby=4)
    gemm_k<64,128,true,false,false,0,false,false><<<dim3(544,1,1), 512, 0, stream>>>(
      mid, w2tl, eout, eb2l, nullptr, 2*T_, D_, I_, I_, I_, D_,
      1, 0,0,0,0,0,0, 1.f, offs, counts, nullptr, btab64, (long)D_*I_, D_, 4, nullptr);
    // x = LN(h2 + combine(eout)); fused second LN -> next LN1 (bf16 hb) or final LN (fp32 fout)
    if (l < 3){
      ln_moe_k<true><<<T_/4, 256, 0, stream>>>(eout, rowof, roww, mask, hb,
                                               mln_w + (size_t)l*D_, mln_b + (size_t)l*D_, x,
                                               ln1_w + (size_t)(l+1)*D_, ln1_b + (size_t)(l+1)*D_,
                                               (void*)hb);
    } else {
      ln_moe_k<false><<<T_/4, 256, 0, stream>>>(eout, rowof, roww, mask, hb,
                                                mln_w + (size_t)l*D_, mln_b + (size_t)l*D_, x,
                                                fln_w, fln_b, (void*)fout);
    }
  }
  // head
  pool2_k<<<dim3(4,32), 256, 0, stream>>>(fout, mask, pooled);
  head_final_k<<<4, 256, 0, stream>>>(pooled, mask, pool_w, pool_b, cls_w, cls_b,
                                      cf_w1, cf_b1, cf_w2, cf_b2, aux, out);
}

// Round 11
// 1227.085 us; speedup vs baseline: 1.2247x; 1.0198x over previous
//
#include <hip/hip_runtime.h>
#include <math.h>

// Problem constants
#define B_ 4
#define S_ 1024
#define D_ 512
#define H_ 8
#define DH_ 64
#define I_ 2048
#define E_ 8
#define L_ 4
#define T_ 4096   // B*S

using bf16x8 = __attribute__((ext_vector_type(8))) __bf16;
using f32x4  = __attribute__((ext_vector_type(4))) float;

typedef __attribute__((address_space(1))) const void gvoid;
typedef __attribute__((address_space(3))) void lvoid;
__device__ __forceinline__ void gl_lds16(const void* g, void* l){
  __builtin_amdgcn_global_load_lds((gvoid*)g, (lvoid*)l, 16, 0, 0);
}

__device__ __forceinline__ float wred_sum(float v){
#pragma unroll
  for(int m=32;m>0;m>>=1) v += __shfl_xor(v, m, 64);
  return v;
}
__device__ __forceinline__ unsigned short f2bf(float f){
  unsigned x = __float_as_uint(f);
  unsigned r = (x + 0x7FFFu + ((x>>16)&1u)) >> 16;
  return (unsigned short)r;
}
__device__ __forceinline__ float bf2f(unsigned short u){
  return __uint_as_float(((unsigned)u)<<16);
}
__device__ __forceinline__ unsigned pk2(float a, float b){
  return (unsigned)f2bf(a) | ((unsigned)f2bf(b)<<16);
}

// ---------------------------------------------------------------------------
// bf16 MFMA GEMM. NT: C[m,n] = sum_k A[m,k]*B[n,k].
// 512 threads = 8 waves in 2x4 (wy=wid>>2, wx=wid&3).
// BK=64, double-buffered LDS, T4 counted-vmcnt schedule (R10 reorder):
//   per K-step: s_barrier (frees buf[cb^1]) -> ISSUE tile t+1 into buf[cb^1]
//   -> s_waitcnt vmcnt(NLD) (waits tile t's loads = oldest NLD; t+1's NLD
//   stay in flight across the whole compute) -> phase0/phase1 ds_read+MFMA.
//   Never drains to 0 in steady state; memory side has 2 tiles in flight
//   during the wait window instead of 1. Buffer/barrier discipline identical
//   to the R4-verified template (one barrier per step; WAR protected by the
//   barrier, RAW by the counted wait; vmcnt retires in issue order).
// T2 bank-conflict fix (verified 6.78M->0): LDS dest linear, global SOURCE
// col unit ^= (row&7); fragment reads XOR the same involution.
// 1-D grid with XCD-chunked bijective swizzle (gridDim.x % 8 == 0).
// MOE: block table btab[bx] = (e<<8)|mblk, -1 = dead. Optional row gather.
// VT (QKV only): blocks with n0>=1024 hold the V slice -> write transposed
// directly to Vt[z=b*8+h][d][k] (replaces the vt_k copy kernel; bit-identical).
// ---------------------------------------------------------------------------
template<int BM, int BN, bool MOE, bool GATHER, bool OUT_BF16, int ACT, bool ADD_IN, bool VT>
__global__ __launch_bounds__(512)
void gemm_k(const unsigned short* __restrict__ A, const unsigned short* __restrict__ Bv,
            void* Cp, const float* __restrict__ bias, const float* addin,
            int M, int N, int K, int lda, int ldb, int ldc,
            int hdiv, long sAb, long sAh, long sBb, long sBh, long sCb, long sCh,
            float scale,
            const int* __restrict__ moff, const int* __restrict__ mcnt,
            const int* __restrict__ rowtok, const int* __restrict__ btab,
            long sBe, int biasStride, int nby, unsigned short* __restrict__ vtp)
{
  constexpr int BK = 64;
  constexpr int WM = BM/2, WN = BN/4, FM = WM/16, FNN = WN/16;
  constexpr int RPC = 64;            // rows covered per block-wide gl_lds16 call (512 thr / 8 per row)
  constexpr int SHPC = 4096;         // shorts per call (512 thr * 8)
  constexpr int NA = BM/RPC, NB = BN/RPC;
  constexpr int NLD = NA + NB;       // gl_lds calls per wave per K-step
  __shared__ unsigned short As[2*BM*BK];
  __shared__ unsigned short Bs[2*BN*BK];

  const int tid = threadIdx.x, wid = tid>>6, lane = tid&63;
  const int wy = wid>>2, wx = wid&3, ln16 = lane&15;

  // XCD-chunked bijective swizzle: consecutive hw ids round-robin XCDs;
  // remap so each XCD owns a contiguous chunk of (bx,by) space, by innermost.
  const int nwg = gridDim.x, cpx = nwg >> 3;
  const int lin = blockIdx.x;
  const int wg  = (lin & 7)*cpx + (lin >> 3);
  const int bxi = wg / nby, byi = wg % nby;

  int m0 = bxi*BM;
  const int n0 = byi*BN;

  float* Cf = nullptr; unsigned short* Ch = nullptr;
  const float* biasp = bias;
  const unsigned short* Bp = Bv;
  int seg = 0, cnt = M;

  if constexpr (MOE){
    int tv = btab[bxi];
    if (tv < 0) return;
    int e = tv>>8;
    m0 = (tv&255)*BM;
    seg = moff[e]; cnt = mcnt[e];
    Bp = Bv + (long)e*sBe;
    if constexpr (OUT_BF16) Ch = (unsigned short*)Cp; else Cf = (float*)Cp;
    if (biasp) biasp += (long)e*biasStride;
  } else {
    int z = blockIdx.z, zb = z/hdiv, zh = z%hdiv;
    A  += (long)zb*sAb + (long)zh*sAh;
    Bp += (long)zb*sBb + (long)zh*sBh;
    long coff = (long)zb*sCb + (long)zh*sCh;
    if constexpr (OUT_BF16) Ch = (unsigned short*)Cp + coff; else Cf = ((float*)Cp) + coff;
    if constexpr (ADD_IN) addin += coff;
  }

  // staging geometry: call j covers rows j*RPC + tid/8, col-unit (tid&7) of 8x16B.
  // SOURCE-side XOR swizzle (T2): unit ^= (row&7); LDS dest stays linear so
  // gl_lds is legal; reads undo the same involution.
  const int srow = tid >> 3;          // 8 lanes per row
  const int scol = ((tid & 7) ^ (srow & 7)) * 8;
  long ga[NA], gb[NB];
#pragma unroll
  for (int j=0; j<NA; j++){
    int r = m0 + j*RPC + srow;
    if constexpr (MOE){
      r = min(r, cnt-1);
      long gr = GATHER ? (long)rowtok[seg+r] : (long)(seg+r);
      ga[j] = gr*lda + scol;
    } else {
      ga[j] = (long)min(r, M-1)*lda + scol;
    }
  }
#pragma unroll
  for (int j=0; j<NB; j++){
    int bn = min(n0 + j*RPC + srow, N-1);
    gb[j] = (long)bn*ldb + scol;
  }

  f32x4 acc[FM][FNN];
#pragma unroll
  for(int i=0;i<FM;i++)
#pragma unroll
    for(int j=0;j<FNN;j++){ f32x4 z = {0.f,0.f,0.f,0.f}; acc[i][j] = z; }

  const int nt = K/BK;
  // read-side swizzle: row&7 == ln16&7 for all fragment rows (WM,WN mult of 8/16)
  const int rsw = ln16 & 7;
  const int u0 = ((lane>>4)     ^ rsw) * 8;   // kk=0 unit offset (elements)
  const int u1 = ((4+(lane>>4)) ^ rsw) * 8;   // kk=1 unit offset

  // prologue: stage tile 0 into buffer 0
#pragma unroll
  for (int j=0; j<NA; j++) gl_lds16(A + ga[j], As + j*SHPC + wid*512);
#pragma unroll
  for (int j=0; j<NB; j++) gl_lds16(Bp + gb[j], Bs + j*SHPC + wid*512);

  for (int t = 0; t < nt; ++t){
    const int cb = t & 1;
    const unsigned short* Ab = As + cb*BM*BK;
    const unsigned short* Bb = Bs + cb*BN*BK;
    unsigned short* An = As + (cb^1)*BM*BK;
    unsigned short* Bn = Bs + (cb^1)*BN*BK;
    const bool pf = (t+1 < nt);
    const long k0n = (long)(t+1)*BK;

    __builtin_amdgcn_s_barrier();      // all waves done reading buf[cb^1] (step t-1)
    if (pf){
      // issue tile t+1 BEFORE the wait: its loads stream while we wait on tile t
#pragma unroll
      for (int j=0; j<NA; j++) gl_lds16(A + ga[j] + k0n, An + j*SHPC + wid*512);
#pragma unroll
      for (int j=0; j<NB; j++) gl_lds16(Bp + gb[j] + k0n, Bn + j*SHPC + wid*512);
      asm volatile("s_waitcnt vmcnt(%0)" :: "n"(NLD) : "memory");  // tile t done; t+1 in flight
    } else {
      asm volatile("s_waitcnt vmcnt(0)" ::: "memory");             // last tile: drain
    }
    __builtin_amdgcn_sched_barrier(0); // no ds_read hoists above the wait

    // ---- phase 0: ds_read kk0 | MFMA kk0
    {
      bf16x8 fa[FM], fb[FNN];
#pragma unroll
      for(int i=0;i<FM;i++) fa[i] = *(const bf16x8*)&Ab[(wy*WM + i*16 + ln16)*BK + u0];
#pragma unroll
      for(int j=0;j<FNN;j++) fb[j] = *(const bf16x8*)&Bb[(wx*WN + j*16 + ln16)*BK + u0];
      __builtin_amdgcn_s_setprio(1);
#pragma unroll
      for(int i=0;i<FM;i++)
#pragma unroll
        for(int j=0;j<FNN;j++)
          acc[i][j] = __builtin_amdgcn_mfma_f32_16x16x32_bf16(fa[i], fb[j], acc[i][j], 0, 0, 0);
      __builtin_amdgcn_s_setprio(0);
    }
    // ---- phase 1: ds_read kk1 | MFMA kk1
    {
      bf16x8 fa[FM], fb[FNN];
#pragma unroll
      for(int i=0;i<FM;i++) fa[i] = *(const bf16x8*)&Ab[(wy*WM + i*16 + ln16)*BK + u1];
#pragma unroll
      for(int j=0;j<FNN;j++) fb[j] = *(const bf16x8*)&Bb[(wx*WN + j*16 + ln16)*BK + u1];
      __builtin_amdgcn_s_setprio(1);
#pragma unroll
      for(int i=0;i<FM;i++)
#pragma unroll
        for(int j=0;j<FNN;j++)
          acc[i][j] = __builtin_amdgcn_mfma_f32_16x16x32_bf16(fa[i], fb[j], acc[i][j], 0, 0, 0);
      __builtin_amdgcn_s_setprio(0);
    }
  }

  // V-split epilogue (QKV only): n0>=1024 is the V slice; write transposed
  // to Vt[(b*8+h)][d][k]. mbase is 4-aligned in k -> one 8B ushort4 store.
  if constexpr (VT){
    if (n0 >= 1024){
#pragma unroll
      for(int i=0;i<FM;i++){
        int mbase = m0 + wy*WM + i*16 + (lane>>4)*4;
        int bb = mbase >> 10;
        int k4 = mbase & 1023;
#pragma unroll
        for(int j=0;j<FNN;j++){
          int n = n0 + wx*WN + j*16 + ln16;
          float bv = biasp ? biasp[n] : 0.f;
          int hh = (n - 1024) >> 6, dd = (n - 1024) & 63;
          f32x4 v = acc[i][j];
          ushort4 pkv;
          pkv.x = f2bf(v[0]*scale + bv);
          pkv.y = f2bf(v[1]*scale + bv);
          pkv.z = f2bf(v[2]*scale + bv);
          pkv.w = f2bf(v[3]*scale + bv);
          *(ushort4*)(vtp + (long)(bb*8 + hh)*65536 + (long)dd*1024 + k4) = pkv;
        }
      }
      return;
    }
  }

  // epilogue: C[m = quad*4+r][n = lane&15]
#pragma unroll
  for(int i=0;i<FM;i++){
    int mbase = m0 + wy*WM + i*16 + (lane>>4)*4;
#pragma unroll
    for(int j=0;j<FNN;j++){
      int n = n0 + wx*WN + j*16 + ln16;
      float bv = biasp ? biasp[n] : 0.f;
      f32x4 v = acc[i][j];
#pragma unroll
      for(int r=0;r<4;r++){
        int m = mbase + r;
        if (m < cnt){
          float x = v[r]*scale + bv;
          if constexpr (ACT == 1) x = 0.5f*x*(1.f + erff(x*0.70710678118654752f));
          long ci = (long)(MOE ? seg + m : m)*ldc + n;
          if constexpr (ADD_IN) x += addin[ci];
          if constexpr (OUT_BF16) Ch[ci] = f2bf(x);
          else Cf[ci] = x;
        }
      }
    }
  }
}

// ---------------------------------------------------------------------------
// Fused flash attention. 1-D grid 512 blocks, XCD-chunked so the 16 qt-blocks
// sharing one z's K/V (256KB) land on ONE XCD's L2 (4 z per XCD = 1MB, fits).
// 4 waves, each owns 16 Q-rows; zero barriers (waves independent).
// 2-deep register double-buffer on K/V: load tile t+1 while computing t.
// ---------------------------------------------------------------------------
__global__ __launch_bounds__(256, 2)
void flash_k(const unsigned short* __restrict__ qkvb, const unsigned short* __restrict__ Vt,
             unsigned short* __restrict__ ctx)
{
  __shared__ unsigned short Pl[4][16*72];
  const int lin = blockIdx.x;
  const int wg  = (lin & 7)*64 + (lin >> 3);   // bijective: 512 = 8 XCD x 64
  const int qt = wg & 15, z = wg >> 4, b = z>>3, h = z&7;
  const int wid = threadIdx.x>>6, lane = threadIdx.x&63;
  const int ln16 = lane&15, g = lane>>4;
  const int q0 = qt*64 + wid*16;
  unsigned short* Pw = &Pl[wid][0];

  const unsigned short* Qp = qkvb + (long)(b*1024 + q0 + ln16)*1536 + h*64 + g*8;
  bf16x8 qf0 = *(const bf16x8*)Qp;
  bf16x8 qf1 = *(const bf16x8*)(Qp + 32);
  const unsigned short* Kbase = qkvb + (long)b*1024*1536 + 512 + h*64 + g*8;
  const unsigned short* Vbase = Vt + (long)z*65536 + g*8;

  float m_s[4], l_s[4];
  f32x4 oacc[4];
#pragma unroll
  for(int r=0;r<4;r++){ m_s[r] = -1e30f; l_s[r] = 0.f; }
#pragma unroll
  for(int j=0;j<4;j++){ f32x4 zz = {0.f,0.f,0.f,0.f}; oacc[j] = zz; }

  bf16x8 ka[4][2], va[4][2], kb[4][2], vb[4][2];

#define LOADKV(T, KD, VD) do { \
  _Pragma("unroll") \
  for(int j=0;j<4;j++){ \
    const unsigned short* kp = Kbase + (long)((T)*64 + j*16 + ln16)*1536; \
    KD[j][0] = *(const bf16x8*)kp; \
    KD[j][1] = *(const bf16x8*)(kp + 32); \
    const unsigned short* vp = Vbase + (long)(j*16 + ln16)*1024 + (T)*64; \
    VD[j][0] = *(const bf16x8*)vp; \
    VD[j][1] = *(const bf16x8*)(vp + 32); \
  } } while(0)

  auto compute = [&](bf16x8 (&kf)[4][2], bf16x8 (&vf)[4][2]){
    f32x4 sacc[4];
#pragma unroll
    for(int j=0;j<4;j++){ f32x4 zz = {0.f,0.f,0.f,0.f}; sacc[j] = zz; }
    __builtin_amdgcn_s_setprio(1);
#pragma unroll
    for(int j=0;j<4;j++){
      sacc[j] = __builtin_amdgcn_mfma_f32_16x16x32_bf16(qf0, kf[j][0], sacc[j], 0,0,0);
      sacc[j] = __builtin_amdgcn_mfma_f32_16x16x32_bf16(qf1, kf[j][1], sacc[j], 0,0,0);
    }
    __builtin_amdgcn_s_setprio(0);
#pragma unroll
    for(int j=0;j<4;j++)
#pragma unroll
      for(int r=0;r<4;r++) sacc[j][r] *= 0.125f;
    float alpha[4];
#pragma unroll
    for(int r=0;r<4;r++){
      float mx = fmaxf(fmaxf(sacc[0][r], sacc[1][r]), fmaxf(sacc[2][r], sacc[3][r]));
#pragma unroll
      for(int m=1;m<16;m<<=1) mx = fmaxf(mx, __shfl_xor(mx, m, 64));
      float mn = fmaxf(m_s[r], mx);
      alpha[r] = __expf(m_s[r] - mn);
      m_s[r] = mn;
    }
#pragma unroll
    for(int j=0;j<4;j++)
#pragma unroll
      for(int r=0;r<4;r++) sacc[j][r] = __expf(sacc[j][r] - m_s[r]);
#pragma unroll
    for(int r=0;r<4;r++){
      float rs = sacc[0][r]+sacc[1][r]+sacc[2][r]+sacc[3][r];
#pragma unroll
      for(int m=1;m<16;m<<=1) rs += __shfl_xor(rs, m, 64);
      l_s[r] = l_s[r]*alpha[r] + rs;
    }
#pragma unroll
    for(int j=0;j<4;j++)
#pragma unroll
      for(int r=0;r<4;r++) oacc[j][r] *= alpha[r];
#pragma unroll
    for(int j=0;j<4;j++)
#pragma unroll
      for(int r=0;r<4;r++)
        Pw[(g*4+r)*72 + j*16 + ln16] = f2bf(sacc[j][r]);
    bf16x8 pf0 = *(const bf16x8*)&Pw[ln16*72 + g*8];
    bf16x8 pf1 = *(const bf16x8*)&Pw[ln16*72 + 32 + g*8];
    __builtin_amdgcn_s_setprio(1);
#pragma unroll
    for(int j=0;j<4;j++){
      oacc[j] = __builtin_amdgcn_mfma_f32_16x16x32_bf16(pf0, vf[j][0], oacc[j], 0,0,0);
      oacc[j] = __builtin_amdgcn_mfma_f32_16x16x32_bf16(pf1, vf[j][1], oacc[j], 0,0,0);
    }
    __builtin_amdgcn_s_setprio(0);
  };

  LOADKV(0, ka, va);
  for (int tt = 0; tt < 8; ++tt){
    LOADKV(2*tt+1, kb, vb);     // prefetch odd tile while computing even
    compute(ka, va);
    if (tt < 7) LOADKV(2*tt+2, ka, va);  // prefetch next even while computing odd
    compute(kb, vb);
  }
#undef LOADKV

#pragma unroll
  for(int r=0;r<4;r++){
    float inv = 1.f/l_s[r];
    long row = (long)(b*1024 + q0 + g*4 + r)*512 + h*64;
#pragma unroll
    for(int j=0;j<4;j++)
      ctx[row + j*16 + ln16] = f2bf(oacc[j][r]*inv);
  }
}

// ---------------------------------------------------------------------------
// Wave-per-row LayerNorm (D=512): 4 rows/block, no barriers. (layer-0 only)
// ---------------------------------------------------------------------------
template<bool OUT_BF16>
__global__ __launch_bounds__(256)
void ln_w_k(const float* __restrict__ in, const float* __restrict__ w,
            const float* __restrict__ bb, void* __restrict__ outp)
{
  int row = blockIdx.x*4 + (threadIdx.x>>6), lane = threadIdx.x&63;
  const float4* p = (const float4*)(in + (long)row*512 + lane*8);
  float4 a = p[0], c = p[1];
  float s = a.x+a.y+a.z+a.w + c.x+c.y+c.z+c.w;
  float q = a.x*a.x+a.y*a.y+a.z*a.z+a.w*a.w + c.x*c.x+c.y*c.y+c.z*c.z+c.w*c.w;
  s = wred_sum(s); q = wred_sum(q);
  float mean = s*(1.f/512.f);
  float var  = q*(1.f/512.f) - mean*mean;
  float inv  = rsqrtf(var + 1e-5f);
  const float4* wp = (const float4*)(w + lane*8);
  const float4* bp = (const float4*)(bb + lane*8);
  float4 w0 = wp[0], w1 = wp[1], b0 = bp[0], b1 = bp[1];
  float o0 = (a.x-mean)*inv*w0.x + b0.x, o1 = (a.y-mean)*inv*w0.y + b0.y;
  float o2 = (a.z-mean)*inv*w0.z + b0.z, o3 = (a.w-mean)*inv*w0.w + b0.w;
  float o4 = (c.x-mean)*inv*w1.x + b1.x, o5 = (c.y-mean)*inv*w1.y + b1.y;
  float o6 = (c.z-mean)*inv*w1.z + b1.z, o7 = (c.w-mean)*inv*w1.w + b1.w;
  if constexpr (OUT_BF16){
    *(uint4*)((unsigned short*)outp + (long)row*512 + lane*8) =
      make_uint4(pk2(o0,o1), pk2(o2,o3), pk2(o4,o5), pk2(o6,o7));
  } else {
    float4* op = (float4*)((float*)outp + (long)row*512 + lane*8);
    op[0] = make_float4(o0,o1,o2,o3);
    op[1] = make_float4(o4,o5,o6,o7);
  }
}

// LN2 + router fused: h2 = LN(x) (bf16 out) then top-2 gate; NO global atomics.
__global__ __launch_bounds__(256)
void ln2route_k(const float* __restrict__ in, const float* __restrict__ w,
                const float* __restrict__ bb, unsigned short* __restrict__ h2,
                const float* __restrict__ gw,
                int* __restrict__ tok_e, float* __restrict__ tok_w)
{
  int tok = blockIdx.x*4 + (threadIdx.x>>6), lane = threadIdx.x&63;
  const float4* p = (const float4*)(in + (long)tok*512 + lane*8);
  float4 a = p[0], c = p[1];
  float s = a.x+a.y+a.z+a.w + c.x+c.y+c.z+c.w;
  float q = a.x*a.x+a.y*a.y+a.z*a.z+a.w*a.w + c.x*c.x+c.y*c.y+c.z*c.z+c.w*c.w;
  s = wred_sum(s); q = wred_sum(q);
  float mean = s*(1.f/512.f);
  float var  = q*(1.f/512.f) - mean*mean;
  float inv  = rsqrtf(var + 1e-5f);
  const float4* wp = (const float4*)(w + lane*8);
  const float4* bp = (const float4*)(bb + lane*8);
  float4 w0 = wp[0], w1 = wp[1], b0 = bp[0], b1 = bp[1];
  float o[8];
  o[0] = (a.x-mean)*inv*w0.x + b0.x; o[1] = (a.y-mean)*inv*w0.y + b0.y;
  o[2] = (a.z-mean)*inv*w0.z + b0.z; o[3] = (a.w-mean)*inv*w0.w + b0.w;
  o[4] = (c.x-mean)*inv*w1.x + b1.x; o[5] = (c.y-mean)*inv*w1.y + b1.y;
  o[6] = (c.z-mean)*inv*w1.z + b1.z; o[7] = (c.w-mean)*inv*w1.w + b1.w;
  *(uint4*)(h2 + (long)tok*512 + lane*8) =
    make_uint4(pk2(o[0],o[1]), pk2(o[2],o[3]), pk2(o[4],o[5]), pk2(o[6],o[7]));
  float lg[8];
#pragma unroll
  for(int e=0;e<8;e++){
    const float4* gr = (const float4*)(gw + e*512 + lane*8);
    float4 g0 = gr[0], g1 = gr[1];
    float d = o[0]*g0.x + o[1]*g0.y + o[2]*g0.z + o[3]*g0.w
            + o[4]*g1.x + o[5]*g1.y + o[6]*g1.z + o[7]*g1.w;
    lg[e] = wred_sum(d);
  }
  if (lane == 0){
    float mx = lg[0];
#pragma unroll
    for(int e=1;e<8;e++) mx = fmaxf(mx, lg[e]);
    float pr[8];
#pragma unroll
    for(int e=0;e<8;e++) pr[e] = expf(lg[e]-mx);
    int e0 = 0; float p0 = pr[0];
#pragma unroll
    for(int e=1;e<8;e++) if (pr[e] > p0){ p0 = pr[e]; e0 = e; }
    int e1 = -1; float p1 = -1.f;
#pragma unroll
    for(int e=0;e<8;e++) if (e != e0 && pr[e] > p1){ p1 = pr[e]; e1 = e; }
    float invp = 1.f/(p0+p1);
    tok_e[2*tok] = e0; tok_e[2*tok+1] = e1;
    tok_w[2*tok] = p0*invp; tok_w[2*tok+1] = p1*invp;
  }
}

// ---------------------------------------------------------------------------
// Single-block planner + scatter: LDS-atomic histogram, offsets, two block
// tables (BM=128 for FFN1, BM=64 for FFN2), aux, and compaction scatter.
// ---------------------------------------------------------------------------
__global__ __launch_bounds__(1024)
void plan_scatter_k(const int* __restrict__ tok_e, const float* __restrict__ tok_w,
                    int* __restrict__ offs, int* __restrict__ cnts, float* __restrict__ aux,
                    int* __restrict__ btab, int* __restrict__ btab64,
                    int* __restrict__ rowtok, float* __restrict__ roww, int* __restrict__ rowof)
{
  __shared__ int hist[8];
  __shared__ int offsS[8];
  __shared__ int base[8];
  const int t = threadIdx.x;
  if (t < 8) hist[t] = 0;
  __syncthreads();
  int e[8]; float w[8];
#pragma unroll
  for (int i=0;i<8;i++){
    e[i] = tok_e[t + i*1024];
    w[i] = tok_w[t + i*1024];
    atomicAdd(&hist[e[i]], 1);
  }
  __syncthreads();
  if (t == 0){
    int o = 0, idx = 0, idx2 = 0; float a = 0.f;
    for (int ee=0; ee<8; ee++){
      offsS[ee] = o;
      int c = hist[ee];
      o += c;
      float u = (float)c*(1.f/4096.f) - 0.125f;
      a += u*u;
      int nb = (c + 127) >> 7;
      for (int j=0;j<nb;j++) btab[idx++] = (ee<<8)|j;
      int nb2 = (c + 63) >> 6;
      for (int j=0;j<nb2;j++) btab64[idx2++] = (ee<<8)|j;
    }
    while (idx < 80) btab[idx++] = -1;
    while (idx2 < 144) btab64[idx2++] = -1;
    *aux += a*(1.f/8.f);
  }
  __syncthreads();
  if (t < 8){
    cnts[t] = hist[t];
    offs[t] = offsS[t];
    base[t] = offsS[t];
  }
  __syncthreads();
#pragma unroll
  for (int i=0;i<8;i++){
    int pos = atomicAdd(&base[e[i]], 1);   // LDS atomic
    int gi = t + i*1024;
    rowtok[pos] = gi>>1;
    roww[pos] = w[i];
    rowof[gi] = pos;
  }
}

// Fused MoE combine + LN(mln) -> x, PLUS second LN (next layer's LN1, or the
// head's final LN) computed in-register from the just-built x.
template<bool OUT2_BF16>
__global__ __launch_bounds__(256)
void ln_moe_k(const float* __restrict__ eout, const int* __restrict__ rowof,
              const float* __restrict__ roww, const float* __restrict__ mask,
              const unsigned short* __restrict__ h2,
              const float* __restrict__ w, const float* __restrict__ bb,
              float* __restrict__ outp,
              const float* __restrict__ w2, const float* __restrict__ b2,
              void* __restrict__ out2)
{
  int tok = blockIdx.x*4 + (threadIdx.x>>6), lane = threadIdx.x&63;
  int r0 = rowof[2*tok], r1 = rowof[2*tok+1];
  float w0w = roww[r0], w1w = roww[r1], mk = mask[tok];
  const float4* ap = (const float4*)(eout + (long)r0*512 + lane*8);
  const float4* bp2 = (const float4*)(eout + (long)r1*512 + lane*8);
  float4 a0 = ap[0], a1 = ap[1], c0 = bp2[0], c1 = bp2[1];
  uint4 hu = *(const uint4*)(h2 + (long)tok*512 + lane*8);
  const unsigned short* hh = (const unsigned short*)&hu;
  float v[8];
  v[0] = bf2f(hh[0]) + (a0.x*w0w + c0.x*w1w)*mk;
  v[1] = bf2f(hh[1]) + (a0.y*w0w + c0.y*w1w)*mk;
  v[2] = bf2f(hh[2]) + (a0.z*w0w + c0.z*w1w)*mk;
  v[3] = bf2f(hh[3]) + (a0.w*w0w + c0.w*w1w)*mk;
  v[4] = bf2f(hh[4]) + (a1.x*w0w + c1.x*w1w)*mk;
  v[5] = bf2f(hh[5]) + (a1.y*w0w + c1.y*w1w)*mk;
  v[6] = bf2f(hh[6]) + (a1.z*w0w + c1.z*w1w)*mk;
  v[7] = bf2f(hh[7]) + (a1.w*w0w + c1.w*w1w)*mk;
  float s = 0.f, q = 0.f;
#pragma unroll
  for(int i=0;i<8;i++){ s += v[i]; q += v[i]*v[i]; }
  s = wred_sum(s); q = wred_sum(q);
  float mean = s*(1.f/512.f);
  float var  = q*(1.f/512.f) - mean*mean;
  float inv  = rsqrtf(var + 1e-5f);
  const float4* wp = (const float4*)(w + lane*8);
  const float4* bpp = (const float4*)(bb + lane*8);
  float4 w0 = wp[0], w1 = wp[1], b0 = bpp[0], b1 = bpp[1];
  float wv[8] = {w0.x,w0.y,w0.z,w0.w,w1.x,w1.y,w1.z,w1.w};
  float bv[8] = {b0.x,b0.y,b0.z,b0.w,b1.x,b1.y,b1.z,b1.w};
  float o[8];
#pragma unroll
  for(int i=0;i<8;i++) o[i] = (v[i]-mean)*inv*wv[i]+bv[i];
  float4* op = (float4*)(outp + (long)tok*512 + lane*8);
  op[0] = make_float4(o[0], o[1], o[2], o[3]);
  op[1] = make_float4(o[4], o[5], o[6], o[7]);
  // second LN over o (the new x)
  float s2 = 0.f, q2 = 0.f;
#pragma unroll
  for(int i=0;i<8;i++){ s2 += o[i]; q2 += o[i]*o[i]; }
  s2 = wred_sum(s2); q2 = wred_sum(q2);
  float mean2 = s2*(1.f/512.f);
  float var2  = q2*(1.f/512.f) - mean2*mean2;
  float inv2  = rsqrtf(var2 + 1e-5f);
  const float4* wp2 = (const float4*)(w2 + lane*8);
  const float4* bp3 = (const float4*)(b2 + lane*8);
  float4 x0 = wp2[0], x1 = wp2[1], y0 = bp3[0], y1 = bp3[1];
  float wv2[8] = {x0.x,x0.y,x0.z,x0.w,x1.x,x1.y,x1.z,x1.w};
  float bv2[8] = {y0.x,y0.y,y0.z,y0.w,y1.x,y1.y,y1.z,y1.w};
  float o2[8];
#pragma unroll
  for(int i=0;i<8;i++) o2[i] = (o[i]-mean2)*inv2*wv2[i]+bv2[i];
  if constexpr (OUT2_BF16){
    *(uint4*)((unsigned short*)out2 + (long)tok*512 + lane*8) =
      make_uint4(pk2(o2[0],o2[1]), pk2(o2[2],o2[3]), pk2(o2[4],o2[5]), pk2(o2[6],o2[7]));
  } else {
    float4* op2 = (float4*)((float*)out2 + (long)tok*512 + lane*8);
    op2[0] = make_float4(o2[0], o2[1], o2[2], o2[3]);
    op2[1] = make_float4(o2[4], o2[5], o2[6], o2[7]);
  }
}

// fp32 (R,C) -> bf16 (C,R), z-loop of ZL
__global__ __launch_bounds__(256)
void transpose_cast_k(const float* __restrict__ in, unsigned short* __restrict__ outp,
                      int R, int C, int ZL)
{
  __shared__ float tile[64][65];
  int t = threadIdx.x;
  int rr = t>>2, cc = (t&3)*16;
  int cc2 = t>>2, rr2 = (t&3)*16;
  int c0 = blockIdx.x*64, r0 = blockIdx.y*64;
  for (int zi = 0; zi < ZL; ++zi){
    long zoff = (long)(blockIdx.z*ZL + zi) * R * C;
    const float* pin = in + zoff + (long)(r0+rr)*C + c0 + cc;
    float4 v0=*(const float4*)pin, v1=*(const float4*)(pin+4), v2=*(const float4*)(pin+8), v3=*(const float4*)(pin+12);
    __syncthreads();
    tile[rr][cc+0]=v0.x; tile[rr][cc+1]=v0.y; tile[rr][cc+2]=v0.z; tile[rr][cc+3]=v0.w;
    tile[rr][cc+4]=v1.x; tile[rr][cc+5]=v1.y; tile[rr][cc+6]=v1.z; tile[rr][cc+7]=v1.w;
    tile[rr][cc+8]=v2.x; tile[rr][cc+9]=v2.y; tile[rr][cc+10]=v2.z; tile[rr][cc+11]=v2.w;
    tile[rr][cc+12]=v3.x; tile[rr][cc+13]=v3.y; tile[rr][cc+14]=v3.z; tile[rr][cc+15]=v3.w;
    __syncthreads();
    unsigned tmp[8];
#pragma unroll
    for(int jj=0;jj<8;jj++)
      tmp[jj] = pk2(tile[rr2+2*jj][cc2], tile[rr2+2*jj+1][cc2]);
    uint4* dst = (uint4*)(outp + zoff + (long)(c0+cc2)*R + r0 + rr2);
    dst[0] = make_uint4(tmp[0],tmp[1],tmp[2],tmp[3]);
    dst[1] = make_uint4(tmp[4],tmp[5],tmp[6],tmp[7]);
  }
}

// fp32 -> bf16, grid-stride
__global__ __launch_bounds__(256)
void cast_bf16_k(const float* __restrict__ in, unsigned short* __restrict__ outp, int n8)
{
  for (int i = blockIdx.x*256 + threadIdx.x; i < n8; i += gridDim.x*256){
    const float4* p = (const float4*)(in + (long)i*8);
    float4 a = p[0], b = p[1];
    *(uint4*)(outp + (long)i*8) = make_uint4(pk2(a.x,a.y), pk2(a.z,a.w), pk2(b.x,b.y), pk2(b.z,b.w));
  }
}

// masked-sum partial pooling, NO atomics: grid (4,32) -> 32 partials per batch
__global__ __launch_bounds__(256)
void pool2_k(const float* __restrict__ h, const float* __restrict__ mask, float* __restrict__ pooled)
{
  int b = blockIdx.x, sc = blockIdx.y, t = threadIdx.x;
  float a0 = 0.f, a1 = 0.f;
  const float* mb = mask + b*1024 + sc*32;
  const float* hbase = h + ((long)b*1024 + sc*32)*512;
  for (int s = 0; s < 32; ++s){
    float mk = mb[s];
    const float* r = hbase + (long)s*512;
    a0 += r[t]*mk; a1 += r[t+256]*mk;
  }
  pooled[((b*32 + sc)*512) + t] = a0;
  pooled[((b*32 + sc)*512) + t + 256] = a1;
}

__global__ __launch_bounds__(256)
void head_final_k(const float* __restrict__ pooled, const float* __restrict__ mask,
                  const float* __restrict__ pool_w, const float* __restrict__ pool_b,
                  const float* __restrict__ cls_w, const float* __restrict__ cls_b,
                  const float* __restrict__ cf_w1, const float* __restrict__ cf_b1,
                  const float* __restrict__ cf_w2, const float* __restrict__ cf_b2,
                  const float* __restrict__ aux, float* __restrict__ out)
{
  int b = blockIdx.x, t = threadIdx.x, wid = t>>6, lane = t&63;
  __shared__ __align__(16) float pld[512];
  __shared__ __align__(16) float p2[512];
  __shared__ float red[4];
  float ds = 0.f;
  for(int s=t; s<1024; s+=256) ds += mask[b*1024 + s];
  ds = wred_sum(ds);
  if (lane==0) red[wid] = ds;
  __syncthreads();
  float denom = fmaxf(red[0]+red[1]+red[2]+red[3], 1e-9f);
  float s0 = 0.f, s1 = 0.f;
#pragma unroll
  for(int sc=0;sc<32;sc++){
    s0 += pooled[((b*32+sc)*512) + t];
    s1 += pooled[((b*32+sc)*512) + t + 256];
  }
  pld[t]     = s0/denom;
  pld[t+256] = s1/denom;
  __syncthreads();
#pragma unroll
  for(int jj=0;jj<2;jj++){
    int j = t + jj*256;
    const float4* wr = (const float4*)(pool_w + (long)j*512);
    float acc = 0.f;
    for(int i=0;i<128;i++){
      float4 w4 = wr[i]; float4 x4 = ((const float4*)pld)[i];
      acc += w4.x*x4.x + w4.y*x4.y + w4.z*x4.z + w4.w*x4.w;
    }
    p2[j] = tanhf(acc + pool_b[j]);
  }
  __syncthreads();
  if (t < 4){
    const float4* wr = (const float4*)(cls_w + (long)t*512);
    float acc = 0.f;
    for(int i=0;i<128;i++){
      float4 w4 = wr[i]; float4 x4 = ((const float4*)p2)[i];
      acc += w4.x*x4.x + w4.y*x4.y + w4.z*x4.z + w4.w*x4.w;
    }
    out[b*4 + t] = acc + cls_b[t];
  }
  {
    const float4* wr = (const float4*)(cf_w1 + (long)t*512);
    float acc = 0.f;
    for(int i=0;i<128;i++){
      float4 w4 = wr[i]; float4 x4 = ((const float4*)p2)[i];
      acc += w4.x*x4.x + w4.y*x4.y + w4.z*x4.z + w4.w*x4.w;
    }
    acc = fmaxf(acc + cf_b1[t], 0.f) * cf_w2[t];
    acc = wred_sum(acc);
    __syncthreads();
    if (lane==0) red[wid] = acc;
    __syncthreads();
    if (t == 0){
      float sum = red[0]+red[1]+red[2]+red[3];
      out[17 + b] = 1.f/(1.f + expf(-(sum + cf_b2[0])));
    }
  }
  if (b == 0 && t == 0) out[16] = aux[0]*0.25f;
}

// ---------------------------------------------------------------------------
extern "C" void kernel_launch(void* const* d_in, const int* in_sizes, int n_in,
                              void* d_out, int out_size, void* d_ws, size_t ws_size,
                              hipStream_t stream)
{
  (void)in_sizes; (void)n_in; (void)out_size;
  const float* emb    = (const float*)d_in[0];
  const float* mask   = (const float*)d_in[1];
  const float* in_w   = (const float*)d_in[2];
  const float* in_b   = (const float*)d_in[3];
  const float* out_w  = (const float*)d_in[4];
  const float* out_b  = (const float*)d_in[5];
  const float* ln1_w  = (const float*)d_in[6];
  const float* ln1_b  = (const float*)d_in[7];
  const float* ln2_w  = (const float*)d_in[8];
  const float* ln2_b  = (const float*)d_in[9];
  const float* gate_w = (const float*)d_in[10];
  const float* e_w1   = (const float*)d_in[11];
  const float* e_b1   = (const float*)d_in[12];
  const float* e_w2   = (const float*)d_in[13];
  const float* e_b2   = (const float*)d_in[14];
  const float* mln_w  = (const float*)d_in[15];
  const float* mln_b  = (const float*)d_in[16];
  const float* fln_w  = (const float*)d_in[17];
  const float* fln_b  = (const float*)d_in[18];
  const float* pool_w = (const float*)d_in[19];
  const float* pool_b = (const float*)d_in[20];
  const float* cls_w  = (const float*)d_in[21];
  const float* cls_b  = (const float*)d_in[22];
  const float* cf_w1  = (const float*)d_in[23];
  const float* cf_b1  = (const float*)d_in[24];
  const float* cf_w2  = (const float*)d_in[25];
  const float* cf_b2  = (const float*)d_in[26];
  float* out = (float*)d_out;
  char* ws = (char*)d_ws;

  const size_t MiB = 1024*1024;
  if (ws_size < 218*MiB) return;

  // Workspace layout
  float*          x     = (float*)(ws + 0*MiB);             // 8 MiB fp32
  unsigned short* hb    = (unsigned short*)(ws + 8*MiB);    // 4 MiB bf16
  unsigned short* qkvb  = (unsigned short*)(ws + 12*MiB);   // 12 MiB bf16
  unsigned short* ctx   = (unsigned short*)(ws + 24*MiB);   // 4 MiB bf16
  unsigned short* Vt    = (unsigned short*)(ws + 28*MiB);   // 4 MiB bf16
  unsigned short* mid   = (unsigned short*)(ws + 32*MiB);   // 32 MiB bf16
  float*          eout  = (float*)(ws + 64*MiB);            // 16 MiB fp32
  float*          fout  = (float*)(ws + 64*MiB);            //   (reuse, head)
  unsigned short* w1t   = (unsigned short*)(ws + 80*MiB);   // 64 MiB bf16
  unsigned short* w2t   = (unsigned short*)(ws + 144*MiB);  // 64 MiB bf16
  unsigned short* inwb  = (unsigned short*)(ws + 208*MiB);  // 6 MiB bf16
  unsigned short* outwb = (unsigned short*)(ws + 214*MiB);  // 2 MiB bf16
  char* misc = ws + 216*MiB;
  int*   counts  = (int*)(misc + 0);
  int*   offs    = (int*)(misc + 64);
  float* aux     = (float*)(misc + 128);
  int*   btab    = (int*)(misc + 256);       // 80 ints
  int*   btab64  = (int*)(misc + 1024);      // 144 ints
  int*   tok_e   = (int*)(misc + 81920);
  float* tok_w   = (float*)(misc + 114688);
  int*   rowtok  = (int*)(misc + 147456);
  float* roww    = (float*)(misc + 180224);
  int*   rowof   = (int*)(misc + 212992);    // 16 KiB
  float* pooled  = (float*)(misc + 262144);  // 256 KiB (4*32*512 fp32)

  hipMemsetAsync(aux, 0, 4, stream);
  // weight prep
  cast_bf16_k<<<512, 256, 0, stream>>>(in_w, inwb, L_*3*D_*D_/8);
  cast_bf16_k<<<256, 256, 0, stream>>>(out_w, outwb, L_*D_*D_/8);
  transpose_cast_k<<<dim3(I_/64, D_/64, 4), 256, 0, stream>>>(e_w1, w1t, D_, I_, 8);
  transpose_cast_k<<<dim3(D_/64, I_/64, 4), 256, 0, stream>>>(e_w2, w2t, I_, D_, 8);

  // layer-0 LN1 (reads emb directly)
  ln_w_k<true><<<T_/4, 256, 0, stream>>>(emb, ln1_w, ln1_b, hb);

  for (int l=0; l<L_; l++){
    const float* inbl  = in_b  + (size_t)l*3*D_;
    const float* outbl = out_b + (size_t)l*D_;
    const float* gwl   = gate_w + (size_t)l*E_*D_;
    const float* eb1l  = e_b1 + (size_t)l*E_*I_;
    const float* eb2l  = e_b2 + (size_t)l*E_*D_;
    const unsigned short* inwbl  = inwb + (size_t)l*3*D_*D_;
    const unsigned short* outwbl = outwb + (size_t)l*D_*D_;
    const unsigned short* w1tl = w1t + (size_t)l*E_*I_*D_;
    const unsigned short* w2tl = w2t + (size_t)l*E_*D_*I_;

    // qkv = h @ in_w^T + in_b; Q,K -> qkvb, V -> Vt transposed (fused vt_k)
    gemm_k<64,128,false,false,true,0,false,true><<<dim3(768,1,1), 512, 0, stream>>>(
      hb, inwbl, qkvb, inbl, nullptr, T_, 3*D_, D_, D_, D_, 3*D_,
      1, 0,0,0,0,0,0, 1.f, nullptr, nullptr, nullptr, nullptr, 0, 0, 12, Vt);
    // fused attention -> ctx (B,S,512) bf16  (1-D grid, XCD-chunked)
    flash_k<<<dim3(512,1,1), 256, 0, stream>>>(qkvb, Vt, ctx);
    // x = residual + ctx @ out_w^T + out_b  (fp32); layer 0 residual = emb
    gemm_k<64,64,false,false,false,0,true,false><<<dim3(512,1,1), 512, 0, stream>>>(
      ctx, outwbl, x, outbl, (l == 0 ? emb : x), T_, D_, D_, D_, D_, D_,
      1, 0,0,0,0,0,0, 1.f, nullptr, nullptr, nullptr, nullptr, 0, 0, 8, nullptr);
    // h2 = LN2(x) -> bf16, + routing (no atomics)
    ln2route_k<<<T_/4, 256, 0, stream>>>(x, ln2_w + (size_t)l*D_, ln2_b + (size_t)l*D_,
                                         hb, gwl, tok_e, tok_w);
    // plan + scatter, single block, LDS atomics only
    plan_scatter_k<<<1, 1024, 0, stream>>>(tok_e, tok_w, offs, counts, aux, btab, btab64,
                                           rowtok, roww, rowof);
    // FFN1: mid = gelu(gather(h2) @ w1^T + b1) -> bf16   (BM=128,BN=64: 2272 blocks, nby=32)
    gemm_k<128,64,true,true,true,1,false,false><<<dim3(2272,1,1), 512, 0, stream>>>(
      hb, w1tl, mid, eb1l, nullptr, 2*T_, I_, D_, D_, D_, I_,
      1, 0,0,0,0,0,0, 1.f, offs, counts, rowtok, btab, (long)I_*D_, I_, 32, nullptr);
    // FFN2: eout = mid @ w2^T + b2 -> fp32   (BM=64, 544 blocks, nby=4)
    gemm_k<64,128,true,false,false,0,false,false><<<dim3(544,1,1), 512, 0, stream>>>(
      mid, w2tl, eout, eb2l, nullptr, 2*T_, D_, I_, I_, I_, D_,
      1, 0,0,0,0,0,0, 1.f, offs, counts, nullptr, btab64, (long)D_*I_, D_, 4, nullptr);
    // x = LN(h2 + combine(eout)); fused second LN -> next LN1 (bf16 hb) or final LN (fp32 fout)
    if (l < 3){
      ln_moe_k<true><<<T_/4, 256, 0, stream>>>(eout, rowof, roww, mask, hb,
                                               mln_w + (size_t)l*D_, mln_b + (size_t)l*D_, x,
                                               ln1_w + (size_t)(l+1)*D_, ln1_b + (size_t)(l+1)*D_,
                                               (void*)hb);
    } else {
      ln_moe_k<false><<<T_/4, 256, 0, stream>>>(eout, rowof, roww, mask, hb,
                                                mln_w + (size_t)l*D_, mln_b + (size_t)l*D_, x,
                                                fln_w, fln_b, (void*)fout);
    }
  }
  // head
  pool2_k<<<dim3(4,32), 256, 0, stream>>>(fout, mask, pooled);
  head_final_k<<<4, 256, 0, stream>>>(pooled, mask, pool_w, pool_b, cls_w, cls_b,
                                      cf_w1, cf_b1, cf_w2, cf_b2, aux, out);
}